// Round 1
// baseline (3138.674 us; speedup 1.0000x reference)
//
#include <hip/hip_runtime.h>
#include <hip/hip_bf16.h>
#include <math.h>

#define B_ 4
#define L_ 2048
#define E_ 1024
#define H_ 16
#define D_ 64
#define NFFT 8192
#define LOG2N 13

// ---------------- 8192-point complex FFT in LDS (radix-2, iterative DIT) -----
// dir = -1.0f forward, +1.0f inverse (unscaled; 1/N folded into Khat).
__device__ inline void fft_lds(float2* a, int tid, float dir) {
    __syncthreads();
    // bit reverse permutation
    for (int i = tid; i < NFFT; i += 256) {
        int j = __brev(i) >> (32 - LOG2N);
        if (i < j) { float2 t = a[i]; a[i] = a[j]; a[j] = t; }
    }
    __syncthreads();
    for (int s = 1; s <= LOG2N; ++s) {
        int half = 1 << (s - 1);
        for (int k = tid; k < NFFT / 2; k += 256) {
            int pos = k & (half - 1);
            int grp = k >> (s - 1);
            int i0 = (grp << s) + pos;
            int i1 = i0 + half;
            float ang = dir * 6.28318530717958647692f * (float)pos / (float)(1 << s);
            float sn, cs;
            __sincosf(ang, &sn, &cs);
            float2 u = a[i0], v = a[i1];
            float tr = v.x * cs - v.y * sn;
            float ti = v.x * sn + v.y * cs;
            a[i0] = make_float2(u.x + tr, u.y + ti);
            a[i1] = make_float2(u.x - tr, u.y - ti);
        }
        __syncthreads();
    }
}

// ---------------- PSF softmax + K8192 construction + forward FFT -------------
// K[dlt] = psf[dlt mod 4095]; layout in 8192: [0..2047]=causal softmax weights,
// [2048..6144]=0, [6145..8191]=uniform anticausal weight exp(-M)/Z.
// Output Khat[h][u][f], scaled by 1/NFFT (folds IFFT normalization).
__global__ __launch_bounds__(256) void k_build_khat(const float* __restrict__ psfs,
                                                    float2* __restrict__ Khat) {
    __shared__ float2 lds[NFFT];
    float* scratch = (float*)lds;
    int u = blockIdx.x, h = blockIdx.y, tid = threadIdx.x;
    const float* col = psfs + (size_t)h * (2 * L_ - 1) * D_ + u;

    // max over causal taps (masked taps contribute logit 0)
    float lm = -1e30f;
    for (int t = tid; t < L_; t += 256) lm = fmaxf(lm, col[(size_t)t * D_]);
    scratch[tid] = lm; __syncthreads();
    for (int off = 128; off > 0; off >>= 1) {
        if (tid < off) scratch[tid] = fmaxf(scratch[tid], scratch[tid + off]);
        __syncthreads();
    }
    float M = fmaxf(scratch[0], 0.0f);
    __syncthreads();

    float ls = 0.0f;
    for (int t = tid; t < L_; t += 256) ls += expf(col[(size_t)t * D_] - M);
    scratch[tid] = ls; __syncthreads();
    for (int off = 128; off > 0; off >>= 1) {
        if (tid < off) scratch[tid] += scratch[tid + off];
        __syncthreads();
    }
    float Z = scratch[0] + (float)(L_ - 1) * expf(-M);
    __syncthreads();

    float invZ = 1.0f / Z;
    float cval = expf(-M) * invZ;
    for (int i = tid; i < NFFT; i += 256) {
        float re;
        if (i < L_)                     re = expf(col[(size_t)i * D_] - M) * invZ;
        else if (i >= NFFT - (L_ - 1))  re = cval;
        else                            re = 0.0f;
        lds[i] = make_float2(re, 0.0f);
    }
    fft_lds(lds, tid, -1.0f);
    float sc = 1.0f / (float)NFFT;
    float2* outp = Khat + ((size_t)h * D_ + u) * NFFT;
    for (int i = tid; i < NFFT; i += 256) {
        float2 v = lds[i];
        outp[i] = make_float2(v.x * sc, v.y * sc);
    }
}

// ---------------- forward FFT of one (b) slice of pre, per (h,v) column ------
__global__ __launch_bounds__(256) void k_fft_fwd(const float* __restrict__ preb,
                                                 float2* __restrict__ Xbuf) {
    __shared__ float2 lds[NFFT];
    int v = blockIdx.x, h = blockIdx.y, tid = threadIdx.x;
    const float* col = preb + (size_t)(h * D_ + v);
    for (int i = tid; i < NFFT; i += 256) {
        float re = (i < L_) ? col[(size_t)i * E_] : 0.0f;
        lds[i] = make_float2(re, 0.0f);
    }
    fft_lds(lds, tid, -1.0f);
    float2* outp = Xbuf + ((size_t)h * D_ + v) * NFFT;
    for (int i = tid; i < NFFT; i += 256) outp[i] = lds[i];
}

// ---------------- per-frequency 64-tap circular conv over d (in place) -------
__global__ __launch_bounds__(256) void k_dconv(float2* __restrict__ Xbuf,
                                               const float2* __restrict__ Khat) {
    __shared__ float2 Xs[D_][64];
    __shared__ float2 Ks[D_][64];
    int f0 = blockIdx.x * 64, h = blockIdx.y, tid = threadIdx.x;
    float2* xb = Xbuf + (size_t)h * D_ * NFFT;
    const float2* kb = Khat + (size_t)h * D_ * NFFT;
    for (int i = tid; i < D_ * 64; i += 256) {
        int vv = i >> 6, fc = i & 63;
        Xs[vv][fc] = xb[(size_t)vv * NFFT + f0 + fc];
        Ks[vv][fc] = kb[(size_t)vv * NFFT + f0 + fc];
    }
    __syncthreads();
    for (int o = tid; o < D_ * 64; o += 256) {
        int m = o >> 6, fc = o & 63;
        float yr = 0.0f, yi = 0.0f;
        for (int u = 0; u < D_; ++u) {
            float2 kk = Ks[u][fc];
            float2 xx = Xs[(m - u) & 63][fc];
            yr += kk.x * xx.x - kk.y * xx.y;
            yi += kk.x * xx.y + kk.y * xx.x;
        }
        xb[(size_t)m * NFFT + f0 + fc] = make_float2(yr, yi);  // LDS holds inputs; safe
    }
}

// ---------------- inverse FFT + GELU + scatter to conv[b][n][h*64+m] ---------
__global__ __launch_bounds__(256) void k_fft_inv(const float2* __restrict__ Xbuf,
                                                 float* __restrict__ convb) {
    __shared__ float2 lds[NFFT];
    int m = blockIdx.x, h = blockIdx.y, tid = threadIdx.x;
    const float2* in = Xbuf + ((size_t)h * D_ + m) * NFFT;
    for (int i = tid; i < NFFT; i += 256) lds[i] = in[i];
    fft_lds(lds, tid, +1.0f);
    float* outp = convb + (h * D_ + m);
    for (int n = tid; n < L_; n += 256) {
        float x = lds[n].x;
        float g = 0.5f * x * (1.0f + erff(x * 0.70710678118654752f));
        outp[(size_t)n * E_] = g;
    }
}

// ---------------- fp32 NT GEMM: C[i,o] = sum_k A[i,k]*W[o,k] + bias[o] -------
__global__ __launch_bounds__(256) void k_gemm_nt(const float* __restrict__ A,
                                                 const float* __restrict__ W,
                                                 const float* __restrict__ bias,
                                                 float* __restrict__ C,
                                                 int M, int N, int K) {
    __shared__ float As[128][9];
    __shared__ float Bs[128][9];
    int bx = blockIdx.x * 128, by = blockIdx.y * 128;
    int tid = threadIdx.x;
    int tx = tid & 15, ty = tid >> 4;
    float acc[8][8];
#pragma unroll
    for (int i = 0; i < 8; ++i)
#pragma unroll
        for (int j = 0; j < 8; ++j) acc[i][j] = 0.0f;

    int lr = tid >> 1, lc = (tid & 1) * 4;
    for (int k0 = 0; k0 < K; k0 += 8) {
        float4 a4 = *(const float4*)(A + (size_t)(by + lr) * K + k0 + lc);
        float4 b4 = *(const float4*)(W + (size_t)(bx + lr) * K + k0 + lc);
        As[lr][lc + 0] = a4.x; As[lr][lc + 1] = a4.y; As[lr][lc + 2] = a4.z; As[lr][lc + 3] = a4.w;
        Bs[lr][lc + 0] = b4.x; Bs[lr][lc + 1] = b4.y; Bs[lr][lc + 2] = b4.z; Bs[lr][lc + 3] = b4.w;
        __syncthreads();
#pragma unroll
        for (int kk = 0; kk < 8; ++kk) {
            float af[8], bf[8];
#pragma unroll
            for (int i = 0; i < 8; ++i) af[i] = As[ty * 8 + i][kk];
#pragma unroll
            for (int j = 0; j < 8; ++j) bf[j] = Bs[tx * 8 + j][kk];
#pragma unroll
            for (int i = 0; i < 8; ++i)
#pragma unroll
                for (int j = 0; j < 8; ++j) acc[i][j] += af[i] * bf[j];
        }
        __syncthreads();
    }
#pragma unroll
    for (int i = 0; i < 8; ++i) {
        int row = by + ty * 8 + i;
#pragma unroll
        for (int j = 0; j < 8; ++j) {
            int col = bx + tx * 8 + j;
            C[(size_t)row * N + col] = acc[i][j] + bias[col];
        }
    }
}

// --------- fp32 NN GEMM accumulate: C[b][l][o] += sum_s tril(S)[l][s]*P[b][s][o]
__global__ __launch_bounds__(256) void k_gemm_nn_acc(const float* __restrict__ Sp,
                                                     const float* __restrict__ P,
                                                     float* __restrict__ C) {
    __shared__ float As[64][17];
    __shared__ float Bs[16][65];
    int o0 = blockIdx.x * 64, l0 = blockIdx.y * 64, b = blockIdx.z;
    int tid = threadIdx.x;
    int tx = tid & 15, ty = tid >> 4;
    const float* Pb = P + (size_t)b * L_ * E_;
    float acc[4][4];
#pragma unroll
    for (int i = 0; i < 4; ++i)
#pragma unroll
        for (int j = 0; j < 4; ++j) acc[i][j] = 0.0f;

    int ar = tid >> 2, ac = (tid & 3) * 4;   // A tile: 64 l-rows x 16 s-cols
    int br = tid >> 4, bc = (tid & 15) * 4;  // B tile: 16 s-rows x 64 o-cols
    for (int s0 = 0; s0 < L_; s0 += 16) {
        int l = l0 + ar;
        float4 a4 = *(const float4*)(Sp + (size_t)l * L_ + s0 + ac);
        As[ar][ac + 0] = (s0 + ac + 0 <= l) ? a4.x : 0.0f;
        As[ar][ac + 1] = (s0 + ac + 1 <= l) ? a4.y : 0.0f;
        As[ar][ac + 2] = (s0 + ac + 2 <= l) ? a4.z : 0.0f;
        As[ar][ac + 3] = (s0 + ac + 3 <= l) ? a4.w : 0.0f;
        float4 b4 = *(const float4*)(Pb + (size_t)(s0 + br) * E_ + o0 + bc);
        Bs[br][bc + 0] = b4.x; Bs[br][bc + 1] = b4.y; Bs[br][bc + 2] = b4.z; Bs[br][bc + 3] = b4.w;
        __syncthreads();
#pragma unroll
        for (int kk = 0; kk < 16; ++kk) {
            float af[4], bf[4];
#pragma unroll
            for (int i = 0; i < 4; ++i) af[i] = As[ty * 4 + i][kk];
#pragma unroll
            for (int j = 0; j < 4; ++j) bf[j] = Bs[kk][tx * 4 + j];
#pragma unroll
            for (int i = 0; i < 4; ++i)
#pragma unroll
                for (int j = 0; j < 4; ++j) acc[i][j] += af[i] * bf[j];
        }
        __syncthreads();
    }
#pragma unroll
    for (int i = 0; i < 4; ++i)
#pragma unroll
        for (int j = 0; j < 4; ++j) {
            size_t idx = (size_t)(b * L_ + l0 + ty * 4 + i) * E_ + o0 + tx * 4 + j;
            C[idx] += acc[i][j];
        }
}

// ---------------- residual + LayerNorm ---------------------------------------
__global__ __launch_bounds__(256) void k_layernorm(const float* __restrict__ accb,
                                                   const float* __restrict__ emb,
                                                   const float* __restrict__ gamma,
                                                   const float* __restrict__ beta,
                                                   float* __restrict__ outp) {
    __shared__ float xs[E_];
    __shared__ float red[256];
    size_t row = blockIdx.x;
    int tid = threadIdx.x;
    const float* a = accb + row * E_;
    const float* e = emb + row * E_;
    float lsum = 0.0f;
    for (int i = tid; i < E_; i += 256) {
        float x = a[i] + e[i];
        xs[i] = x;
        lsum += x;
    }
    red[tid] = lsum; __syncthreads();
    for (int off = 128; off > 0; off >>= 1) {
        if (tid < off) red[tid] += red[tid + off];
        __syncthreads();
    }
    float mu = red[0] * (1.0f / E_);
    __syncthreads();
    float lv = 0.0f;
    for (int i = tid; i < E_; i += 256) { float d = xs[i] - mu; lv += d * d; }
    red[tid] = lv; __syncthreads();
    for (int off = 128; off > 0; off >>= 1) {
        if (tid < off) red[tid] += red[tid + off];
        __syncthreads();
    }
    float inv = rsqrtf(red[0] * (1.0f / E_) + 1e-12f);
    for (int i = tid; i < E_; i += 256)
        outp[row * E_ + i] = (xs[i] - mu) * inv * gamma[i] + beta[i];
}

extern "C" void kernel_launch(void* const* d_in, const int* in_sizes, int n_in,
                              void* d_out, int out_size, void* d_ws, size_t ws_size,
                              hipStream_t stream) {
    const float* emb    = (const float*)d_in[0];
    const float* W1     = (const float*)d_in[1];
    const float* b1     = (const float*)d_in[2];
    const float* W2     = (const float*)d_in[3];
    const float* b2     = (const float*)d_in[4];
    const float* psfs   = (const float*)d_in[5];
    const float* W3     = (const float*)d_in[6];
    const float* b3     = (const float*)d_in[7];
    const float* sparse = (const float*)d_in[8];
    const float* gamma  = (const float*)d_in[9];
    const float* beta   = (const float*)d_in[10];
    float* outp = (float*)d_out;

    const size_t BLE = (size_t)B_ * L_ * E_;
    float*  pre        = (float*)d_ws;
    float*  pre_sparse = pre + BLE;
    float*  conv       = pre_sparse + BLE;
    float*  accb       = conv + BLE;
    float2* Khat       = (float2*)(accb + BLE);
    float2* Xbuf       = Khat + (size_t)H_ * D_ * NFFT;
    // total ws use: 4*33.55MB + 2*67.1MB = 268.4 MB

    // pre = emb @ W1^T + b1 ; pre_sparse = pre @ W2^T + b2
    k_gemm_nt<<<dim3(E_ / 128, (B_ * L_) / 128), 256, 0, stream>>>(emb, W1, b1, pre, B_ * L_, E_, E_);
    k_gemm_nt<<<dim3(E_ / 128, (B_ * L_) / 128), 256, 0, stream>>>(pre, W2, b2, pre_sparse, B_ * L_, E_, E_);

    // PSF softmax + seq-FFT of kernel
    k_build_khat<<<dim3(D_, H_), 256, 0, stream>>>(psfs, Khat);

    // per-batch FFT conv: seq-FFT -> per-frequency d-conv -> inverse seq-FFT (+GELU)
    for (int b = 0; b < B_; ++b) {
        k_fft_fwd<<<dim3(D_, H_), 256, 0, stream>>>(pre + (size_t)b * L_ * E_, Xbuf);
        k_dconv<<<dim3(NFFT / 64, H_), 256, 0, stream>>>(Xbuf, Khat);
        k_fft_inv<<<dim3(D_, H_), 256, 0, stream>>>(Xbuf, conv + (size_t)b * L_ * E_);
    }

    // acc = conv @ W3^T + b3 ; acc += tril(sparse) @ pre_sparse
    k_gemm_nt<<<dim3(E_ / 128, (B_ * L_) / 128), 256, 0, stream>>>(conv, W3, b3, accb, B_ * L_, E_, E_);
    k_gemm_nn_acc<<<dim3(E_ / 64, L_ / 64, B_), 256, 0, stream>>>(sparse, pre_sparse, accb);

    // out = LayerNorm(acc + emb) * gamma + beta
    k_layernorm<<<B_ * L_, 256, 0, stream>>>(accb, emb, gamma, beta, outp);
}

// Round 2
// 2531.074 us; speedup vs baseline: 1.2401x; 1.2401x over previous
//
#include <hip/hip_runtime.h>
#include <hip/hip_bf16.h>
#include <math.h>

#define B_ 4
#define L_ 2048
#define E_ 1024
#define H_ 16
#define D_ 64
#define NFFT 8192
#define LOG2N 13
#define CAP 128  // max nonzeros per row kept (expected ~10, Poisson tail << 128)

// ---------------- 8192-point complex FFT in LDS (radix-2, iterative DIT) -----
__device__ inline void fft_lds(float2* a, int tid, float dir) {
    __syncthreads();
    for (int i = tid; i < NFFT; i += 256) {
        int j = __brev(i) >> (32 - LOG2N);
        if (i < j) { float2 t = a[i]; a[i] = a[j]; a[j] = t; }
    }
    __syncthreads();
    for (int s = 1; s <= LOG2N; ++s) {
        int half = 1 << (s - 1);
        for (int k = tid; k < NFFT / 2; k += 256) {
            int pos = k & (half - 1);
            int grp = k >> (s - 1);
            int i0 = (grp << s) + pos;
            int i1 = i0 + half;
            float ang = dir * 6.28318530717958647692f * (float)pos / (float)(1 << s);
            float sn, cs;
            __sincosf(ang, &sn, &cs);
            float2 u = a[i0], v = a[i1];
            float tr = v.x * cs - v.y * sn;
            float ti = v.x * sn + v.y * cs;
            a[i0] = make_float2(u.x + tr, u.y + ti);
            a[i1] = make_float2(u.x - tr, u.y - ti);
        }
        __syncthreads();
    }
}

// ---------------- PSF softmax + K8192 construction + forward FFT -------------
__global__ __launch_bounds__(256) void k_build_khat(const float* __restrict__ psfs,
                                                    float2* __restrict__ Khat) {
    __shared__ float2 lds[NFFT];
    float* scratch = (float*)lds;
    int u = blockIdx.x, h = blockIdx.y, tid = threadIdx.x;
    const float* col = psfs + (size_t)h * (2 * L_ - 1) * D_ + u;

    float lm = -1e30f;
    for (int t = tid; t < L_; t += 256) lm = fmaxf(lm, col[(size_t)t * D_]);
    scratch[tid] = lm; __syncthreads();
    for (int off = 128; off > 0; off >>= 1) {
        if (tid < off) scratch[tid] = fmaxf(scratch[tid], scratch[tid + off]);
        __syncthreads();
    }
    float M = fmaxf(scratch[0], 0.0f);
    __syncthreads();

    float ls = 0.0f;
    for (int t = tid; t < L_; t += 256) ls += expf(col[(size_t)t * D_] - M);
    scratch[tid] = ls; __syncthreads();
    for (int off = 128; off > 0; off >>= 1) {
        if (tid < off) scratch[tid] += scratch[tid + off];
        __syncthreads();
    }
    float Z = scratch[0] + (float)(L_ - 1) * expf(-M);
    __syncthreads();

    float invZ = 1.0f / Z;
    float cval = expf(-M) * invZ;
    for (int i = tid; i < NFFT; i += 256) {
        float re;
        if (i < L_)                     re = expf(col[(size_t)i * D_] - M) * invZ;
        else if (i >= NFFT - (L_ - 1))  re = cval;
        else                            re = 0.0f;
        lds[i] = make_float2(re, 0.0f);
    }
    fft_lds(lds, tid, -1.0f);
    float sc = 1.0f / (float)NFFT;
    float2* outp = Khat + ((size_t)h * D_ + u) * NFFT;
    for (int i = tid; i < NFFT; i += 256) {
        float2 v = lds[i];
        outp[i] = make_float2(v.x * sc, v.y * sc);
    }
}

// ---------------- forward FFT of one (b) slice of pre, per (h,v) column ------
__global__ __launch_bounds__(256) void k_fft_fwd(const float* __restrict__ preb,
                                                 float2* __restrict__ Xbuf) {
    __shared__ float2 lds[NFFT];
    int v = blockIdx.x, h = blockIdx.y, tid = threadIdx.x;
    const float* col = preb + (size_t)(h * D_ + v);
    for (int i = tid; i < NFFT; i += 256) {
        float re = (i < L_) ? col[(size_t)i * E_] : 0.0f;
        lds[i] = make_float2(re, 0.0f);
    }
    fft_lds(lds, tid, -1.0f);
    float2* outp = Xbuf + ((size_t)h * D_ + v) * NFFT;
    for (int i = tid; i < NFFT; i += 256) outp[i] = lds[i];
}

// ---------------- per-frequency 64-tap circular conv over d (in place) -------
__global__ __launch_bounds__(256) void k_dconv(float2* __restrict__ Xbuf,
                                               const float2* __restrict__ Khat) {
    __shared__ float2 Xs[D_][64];
    __shared__ float2 Ks[D_][64];
    int f0 = blockIdx.x * 64, h = blockIdx.y, tid = threadIdx.x;
    float2* xb = Xbuf + (size_t)h * D_ * NFFT;
    const float2* kb = Khat + (size_t)h * D_ * NFFT;
    for (int i = tid; i < D_ * 64; i += 256) {
        int vv = i >> 6, fc = i & 63;
        Xs[vv][fc] = xb[(size_t)vv * NFFT + f0 + fc];
        Ks[vv][fc] = kb[(size_t)vv * NFFT + f0 + fc];
    }
    __syncthreads();
    for (int o = tid; o < D_ * 64; o += 256) {
        int m = o >> 6, fc = o & 63;
        float yr = 0.0f, yi = 0.0f;
        for (int u = 0; u < D_; ++u) {
            float2 kk = Ks[u][fc];
            float2 xx = Xs[(m - u) & 63][fc];
            yr += kk.x * xx.x - kk.y * xx.y;
            yi += kk.x * xx.y + kk.y * xx.x;
        }
        xb[(size_t)m * NFFT + f0 + fc] = make_float2(yr, yi);
    }
}

// ---------------- inverse FFT + GELU + scatter to conv[b][n][h*64+m] ---------
__global__ __launch_bounds__(256) void k_fft_inv(const float2* __restrict__ Xbuf,
                                                 float* __restrict__ convb) {
    __shared__ float2 lds[NFFT];
    int m = blockIdx.x, h = blockIdx.y, tid = threadIdx.x;
    const float2* in = Xbuf + ((size_t)h * D_ + m) * NFFT;
    for (int i = tid; i < NFFT; i += 256) lds[i] = in[i];
    fft_lds(lds, tid, +1.0f);
    float* outp = convb + (h * D_ + m);
    for (int n = tid; n < L_; n += 256) {
        float x = lds[n].x;
        float g = 0.5f * x * (1.0f + erff(x * 0.70710678118654752f));
        outp[(size_t)n * E_] = g;
    }
}

// ---------------- fp32 NT GEMM: C[i,o] = sum_k A[i,k]*W[o,k] + bias[o] -------
__global__ __launch_bounds__(256) void k_gemm_nt(const float* __restrict__ A,
                                                 const float* __restrict__ W,
                                                 const float* __restrict__ bias,
                                                 float* __restrict__ C,
                                                 int M, int N, int K) {
    __shared__ float As[128][9];
    __shared__ float Bs[128][9];
    int bx = blockIdx.x * 128, by = blockIdx.y * 128;
    int tid = threadIdx.x;
    int tx = tid & 15, ty = tid >> 4;
    float acc[8][8];
#pragma unroll
    for (int i = 0; i < 8; ++i)
#pragma unroll
        for (int j = 0; j < 8; ++j) acc[i][j] = 0.0f;

    int lr = tid >> 1, lc = (tid & 1) * 4;
    for (int k0 = 0; k0 < K; k0 += 8) {
        float4 a4 = *(const float4*)(A + (size_t)(by + lr) * K + k0 + lc);
        float4 b4 = *(const float4*)(W + (size_t)(bx + lr) * K + k0 + lc);
        As[lr][lc + 0] = a4.x; As[lr][lc + 1] = a4.y; As[lr][lc + 2] = a4.z; As[lr][lc + 3] = a4.w;
        Bs[lr][lc + 0] = b4.x; Bs[lr][lc + 1] = b4.y; Bs[lr][lc + 2] = b4.z; Bs[lr][lc + 3] = b4.w;
        __syncthreads();
#pragma unroll
        for (int kk = 0; kk < 8; ++kk) {
            float af[8], bf[8];
#pragma unroll
            for (int i = 0; i < 8; ++i) af[i] = As[ty * 8 + i][kk];
#pragma unroll
            for (int j = 0; j < 8; ++j) bf[j] = Bs[tx * 8 + j][kk];
#pragma unroll
            for (int i = 0; i < 8; ++i)
#pragma unroll
                for (int j = 0; j < 8; ++j) acc[i][j] += af[i] * bf[j];
        }
        __syncthreads();
    }
#pragma unroll
    for (int i = 0; i < 8; ++i) {
        int row = by + ty * 8 + i;
#pragma unroll
        for (int j = 0; j < 8; ++j) {
            int col = bx + tx * 8 + j;
            C[(size_t)row * N + col] = acc[i][j] + bias[col];
        }
    }
}

// ---------------- sparse seq-mix: build per-row (col,val) lists --------------
// One block per row l; keeps only s<=l (tril mask), nonzero values.
__global__ __launch_bounds__(256) void k_sparse_build(const float* __restrict__ Sp,
                                                      int* __restrict__ nnz,
                                                      int* __restrict__ idxs,
                                                      float* __restrict__ vals) {
    __shared__ int cnt;
    int l = blockIdx.x, tid = threadIdx.x;
    if (tid == 0) cnt = 0;
    __syncthreads();
    const float* row = Sp + (size_t)l * L_;
    for (int s = tid; s <= l; s += 256) {
        float v = row[s];
        if (v != 0.0f) {
            int slot = atomicAdd(&cnt, 1);
            if (slot < CAP) { idxs[l * CAP + slot] = s; vals[l * CAP + slot] = v; }
        }
    }
    __syncthreads();
    if (tid == 0) nnz[l] = min(cnt, CAP);
}

// ---------------- gather-SpMM accumulate: C[b][l][:] += sum_j val_j*P[b][s_j][:]
__global__ __launch_bounds__(256) void k_spmm_acc(const int* __restrict__ nnz,
                                                  const int* __restrict__ idxs,
                                                  const float* __restrict__ vals,
                                                  const float* __restrict__ P,
                                                  float* __restrict__ C) {
    __shared__ int sidx[CAP];
    __shared__ float sval[CAP];
    int l = blockIdx.x, b = blockIdx.y, tid = threadIdx.x;
    int n = nnz[l];
    for (int j = tid; j < n; j += 256) {
        sidx[j] = idxs[l * CAP + j];
        sval[j] = vals[l * CAP + j];
    }
    __syncthreads();
    const float* Pb = P + (size_t)b * L_ * E_;
    size_t off = (size_t)tid * 4;
    float* cp = C + ((size_t)(b * L_ + l)) * E_ + off;
    float4 acc = *(float4*)cp;
    for (int j = 0; j < n; ++j) {
        float v = sval[j];
        float4 p = *(const float4*)(Pb + (size_t)sidx[j] * E_ + off);
        acc.x += v * p.x; acc.y += v * p.y; acc.z += v * p.z; acc.w += v * p.w;
    }
    *(float4*)cp = acc;
}

// ---------------- residual + LayerNorm ---------------------------------------
__global__ __launch_bounds__(256) void k_layernorm(const float* __restrict__ accb,
                                                   const float* __restrict__ emb,
                                                   const float* __restrict__ gamma,
                                                   const float* __restrict__ beta,
                                                   float* __restrict__ outp) {
    __shared__ float xs[E_];
    __shared__ float red[256];
    size_t row = blockIdx.x;
    int tid = threadIdx.x;
    const float* a = accb + row * E_;
    const float* e = emb + row * E_;
    float lsum = 0.0f;
    for (int i = tid; i < E_; i += 256) {
        float x = a[i] + e[i];
        xs[i] = x;
        lsum += x;
    }
    red[tid] = lsum; __syncthreads();
    for (int off = 128; off > 0; off >>= 1) {
        if (tid < off) red[tid] += red[tid + off];
        __syncthreads();
    }
    float mu = red[0] * (1.0f / E_);
    __syncthreads();
    float lv = 0.0f;
    for (int i = tid; i < E_; i += 256) { float d = xs[i] - mu; lv += d * d; }
    red[tid] = lv; __syncthreads();
    for (int off = 128; off > 0; off >>= 1) {
        if (tid < off) red[tid] += red[tid + off];
        __syncthreads();
    }
    float inv = rsqrtf(red[0] * (1.0f / E_) + 1e-12f);
    for (int i = tid; i < E_; i += 256)
        outp[row * E_ + i] = (xs[i] - mu) * inv * gamma[i] + beta[i];
}

extern "C" void kernel_launch(void* const* d_in, const int* in_sizes, int n_in,
                              void* d_out, int out_size, void* d_ws, size_t ws_size,
                              hipStream_t stream) {
    const float* emb    = (const float*)d_in[0];
    const float* W1     = (const float*)d_in[1];
    const float* b1     = (const float*)d_in[2];
    const float* W2     = (const float*)d_in[3];
    const float* b2     = (const float*)d_in[4];
    const float* psfs   = (const float*)d_in[5];
    const float* W3     = (const float*)d_in[6];
    const float* b3     = (const float*)d_in[7];
    const float* sparse = (const float*)d_in[8];
    const float* gamma  = (const float*)d_in[9];
    const float* beta   = (const float*)d_in[10];
    float* outp = (float*)d_out;

    const size_t BLE = (size_t)B_ * L_ * E_;
    float*  pre        = (float*)d_ws;
    float*  pre_sparse = pre + BLE;
    float*  conv       = pre_sparse + BLE;
    float*  accb       = conv + BLE;
    float2* Khat       = (float2*)(accb + BLE);
    float2* Xbuf       = Khat + (size_t)H_ * D_ * NFFT;
    // sparse lists live in Xbuf's space (Xbuf is dead by the time they're used)
    int*    s_nnz      = (int*)Xbuf;
    int*    s_idx      = s_nnz + L_;
    float*  s_val      = (float*)(s_idx + (size_t)L_ * CAP);
    // total ws use: 4*33.55MB + 2*67.1MB = 268.4 MB

    // pre = emb @ W1^T + b1 ; pre_sparse = pre @ W2^T + b2
    k_gemm_nt<<<dim3(E_ / 128, (B_ * L_) / 128), 256, 0, stream>>>(emb, W1, b1, pre, B_ * L_, E_, E_);
    k_gemm_nt<<<dim3(E_ / 128, (B_ * L_) / 128), 256, 0, stream>>>(pre, W2, b2, pre_sparse, B_ * L_, E_, E_);

    // PSF softmax + seq-FFT of kernel
    k_build_khat<<<dim3(D_, H_), 256, 0, stream>>>(psfs, Khat);

    // per-batch FFT conv: seq-FFT -> per-frequency d-conv -> inverse seq-FFT (+GELU)
    for (int b = 0; b < B_; ++b) {
        k_fft_fwd<<<dim3(D_, H_), 256, 0, stream>>>(pre + (size_t)b * L_ * E_, Xbuf);
        k_dconv<<<dim3(NFFT / 64, H_), 256, 0, stream>>>(Xbuf, Khat);
        k_fft_inv<<<dim3(D_, H_), 256, 0, stream>>>(Xbuf, conv + (size_t)b * L_ * E_);
    }

    // acc = conv @ W3^T + b3
    k_gemm_nt<<<dim3(E_ / 128, (B_ * L_) / 128), 256, 0, stream>>>(conv, W3, b3, accb, B_ * L_, E_, E_);

    // acc += tril(sparse) @ pre_sparse  (sparse path: ~21K nonzeros total)
    k_sparse_build<<<L_, 256, 0, stream>>>(sparse, s_nnz, s_idx, s_val);
    k_spmm_acc<<<dim3(L_, B_), 256, 0, stream>>>(s_nnz, s_idx, s_val, pre_sparse, accb);

    // out = LayerNorm(acc + emb) * gamma + beta
    k_layernorm<<<B_ * L_, 256, 0, stream>>>(accb, emb, gamma, beta, outp);
}

// Round 3
// 1522.664 us; speedup vs baseline: 2.0613x; 1.6623x over previous
//
#include <hip/hip_runtime.h>
#include <hip/hip_bf16.h>
#include <math.h>

#define B_ 4
#define L_ 2048
#define E_ 1024
#define H_ 16
#define D_ 64
#define NFFT 8192
#define LOG2N 13
#define CAP 128

typedef __hip_bfloat16 bf16;
typedef __attribute__((ext_vector_type(8))) short bf16x8;
typedef __attribute__((ext_vector_type(4))) float f32x4;

typedef __attribute__((address_space(1))) const unsigned int gas_u32;
typedef __attribute__((address_space(3))) unsigned int las_u32;

__device__ __forceinline__ void gload_lds16(const void* g, void* l) {
    __builtin_amdgcn_global_load_lds((gas_u32*)g, (las_u32*)l, 16, 0, 0);
}

// ---------------- fp32 -> bf16 convert (vectorized) --------------------------
__global__ __launch_bounds__(256) void k_cvt(const float* __restrict__ in,
                                             bf16* __restrict__ out, int n) {
    int i = (blockIdx.x * 256 + threadIdx.x) * 4;
    if (i >= n) return;
    float4 v = *(const float4*)(in + i);
    bf16 tmp[4];
    tmp[0] = __float2bfloat16(v.x);
    tmp[1] = __float2bfloat16(v.y);
    tmp[2] = __float2bfloat16(v.z);
    tmp[3] = __float2bfloat16(v.w);
    *(ushort4*)(out + i) = *(ushort4*)tmp;
}

// ---------------- bf16 MFMA GEMM (m97 structure): C = A @ Wt^T + bias --------
// A: [M][K] bf16, Wt: [N][K] bf16 (NT). OUTB=0 -> C fp32; OUTB=1 -> Cb bf16.
template <int OUTB>
__global__ __launch_bounds__(256) void k_gemm_mfma(const bf16* __restrict__ A,
                                                   const bf16* __restrict__ Wt,
                                                   const float* __restrict__ bias,
                                                   float* __restrict__ C,
                                                   bf16* __restrict__ Cb,
                                                   int M, int N, int K) {
    __shared__ bf16 As[128 * 32];
    __shared__ bf16 Bs[128 * 32];
    int tid = threadIdx.x;
    int lane = tid & 63, w = tid >> 6;
    int wr = w >> 1, wc = w & 1;
    int by = blockIdx.y * 128;  // M
    int bx = blockIdx.x * 128;  // N

    f32x4 zz = {0.0f, 0.0f, 0.0f, 0.0f};
    f32x4 acc[4][4];
#pragma unroll
    for (int m = 0; m < 4; ++m)
#pragma unroll
        for (int n = 0; n < 4; ++n) acc[m][n] = zz;

    int koff = (lane >> 4) * 8;
    int rsub = lane & 15;

    for (int k0 = 0; k0 < K; k0 += 32) {
        // stage 128x32 A and B tiles: each thread 2 x 16B chunks per tile
#pragma unroll
        for (int i = 0; i < 2; ++i) {
            int c = tid + i * 256;  // 0..511
            int row = c >> 2;
            int kb = (c & 3) * 8;
            gload_lds16(A + (size_t)(by + row) * K + k0 + kb, &As[c * 8]);
            gload_lds16(Wt + (size_t)(bx + row) * K + k0 + kb, &Bs[c * 8]);
        }
        __syncthreads();
        bf16x8 af[4], bfv[4];
#pragma unroll
        for (int m = 0; m < 4; ++m)
            af[m] = *(const bf16x8*)&As[(wr * 64 + m * 16 + rsub) * 32 + koff];
#pragma unroll
        for (int n = 0; n < 4; ++n)
            bfv[n] = *(const bf16x8*)&Bs[(wc * 64 + n * 16 + rsub) * 32 + koff];
#pragma unroll
        for (int m = 0; m < 4; ++m)
#pragma unroll
            for (int n = 0; n < 4; ++n)
                acc[m][n] = __builtin_amdgcn_mfma_f32_16x16x32_bf16(af[m], bfv[n], acc[m][n], 0, 0, 0);
        __syncthreads();
    }

    // epilogue: C/D layout col=lane&15, row=(lane>>4)*4+j  (m89-verified)
    int cq = (lane >> 4) * 4;
    int cr = lane & 15;
#pragma unroll
    for (int m = 0; m < 4; ++m) {
        int row0 = by + wr * 64 + m * 16 + cq;
#pragma unroll
        for (int n = 0; n < 4; ++n) {
            int col = bx + wc * 64 + n * 16 + cr;
            float bv = bias[col];
#pragma unroll
            for (int j = 0; j < 4; ++j) {
                float v = acc[m][n][j] + bv;
                if constexpr (OUTB)
                    Cb[(size_t)(row0 + j) * N + col] = __float2bfloat16(v);
                else
                    C[(size_t)(row0 + j) * N + col] = v;
            }
        }
    }
}

// ---------------- 8192-point complex FFT in LDS (radix-2, iterative DIT) -----
__device__ inline void fft_lds(float2* a, int tid, float dir) {
    __syncthreads();
    for (int i = tid; i < NFFT; i += 256) {
        int j = __brev(i) >> (32 - LOG2N);
        if (i < j) { float2 t = a[i]; a[i] = a[j]; a[j] = t; }
    }
    __syncthreads();
    for (int s = 1; s <= LOG2N; ++s) {
        int half = 1 << (s - 1);
        for (int k = tid; k < NFFT / 2; k += 256) {
            int pos = k & (half - 1);
            int grp = k >> (s - 1);
            int i0 = (grp << s) + pos;
            int i1 = i0 + half;
            float ang = dir * 6.28318530717958647692f * (float)pos / (float)(1 << s);
            float sn, cs;
            __sincosf(ang, &sn, &cs);
            float2 u = a[i0], v = a[i1];
            float tr = v.x * cs - v.y * sn;
            float ti = v.x * sn + v.y * cs;
            a[i0] = make_float2(u.x + tr, u.y + ti);
            a[i1] = make_float2(u.x - tr, u.y - ti);
        }
        __syncthreads();
    }
}

// ---------------- PSF softmax + K8192 construction + forward FFT -------------
__global__ __launch_bounds__(256) void k_build_khat(const float* __restrict__ psfs,
                                                    float2* __restrict__ Khat) {
    __shared__ float2 lds[NFFT];
    float* scratch = (float*)lds;
    int u = blockIdx.x, h = blockIdx.y, tid = threadIdx.x;
    const float* col = psfs + (size_t)h * (2 * L_ - 1) * D_ + u;

    float lm = -1e30f;
    for (int t = tid; t < L_; t += 256) lm = fmaxf(lm, col[(size_t)t * D_]);
    scratch[tid] = lm; __syncthreads();
    for (int off = 128; off > 0; off >>= 1) {
        if (tid < off) scratch[tid] = fmaxf(scratch[tid], scratch[tid + off]);
        __syncthreads();
    }
    float M = fmaxf(scratch[0], 0.0f);
    __syncthreads();

    float ls = 0.0f;
    for (int t = tid; t < L_; t += 256) ls += expf(col[(size_t)t * D_] - M);
    scratch[tid] = ls; __syncthreads();
    for (int off = 128; off > 0; off >>= 1) {
        if (tid < off) scratch[tid] += scratch[tid + off];
        __syncthreads();
    }
    float Z = scratch[0] + (float)(L_ - 1) * expf(-M);
    __syncthreads();

    float invZ = 1.0f / Z;
    float cval = expf(-M) * invZ;
    for (int i = tid; i < NFFT; i += 256) {
        float re;
        if (i < L_)                     re = expf(col[(size_t)i * D_] - M) * invZ;
        else if (i >= NFFT - (L_ - 1))  re = cval;
        else                            re = 0.0f;
        lds[i] = make_float2(re, 0.0f);
    }
    fft_lds(lds, tid, -1.0f);
    float sc = 1.0f / (float)NFFT;
    float2* outp = Khat + ((size_t)h * D_ + u) * NFFT;
    for (int i = tid; i < NFFT; i += 256) {
        float2 v = lds[i];
        outp[i] = make_float2(v.x * sc, v.y * sc);
    }
}

// ---------------- forward FFT of one (b) slice of preb (bf16), per (h,v) -----
__global__ __launch_bounds__(256) void k_fft_fwd(const bf16* __restrict__ preb,
                                                 float2* __restrict__ Xbuf) {
    __shared__ float2 lds[NFFT];
    int v = blockIdx.x, h = blockIdx.y, tid = threadIdx.x;
    const bf16* col = preb + (size_t)(h * D_ + v);
    for (int i = tid; i < NFFT; i += 256) {
        float re = (i < L_) ? __bfloat162float(col[(size_t)i * E_]) : 0.0f;
        lds[i] = make_float2(re, 0.0f);
    }
    fft_lds(lds, tid, -1.0f);
    float2* outp = Xbuf + ((size_t)h * D_ + v) * NFFT;
    for (int i = tid; i < NFFT; i += 256) outp[i] = lds[i];
}

// ---------------- per-frequency 64-tap circular conv over d (in place) -------
__global__ __launch_bounds__(256) void k_dconv(float2* __restrict__ Xbuf,
                                               const float2* __restrict__ Khat) {
    __shared__ float2 Xs[D_][64];
    __shared__ float2 Ks[D_][64];
    int f0 = blockIdx.x * 64, h = blockIdx.y, tid = threadIdx.x;
    float2* xb = Xbuf + (size_t)h * D_ * NFFT;
    const float2* kb = Khat + (size_t)h * D_ * NFFT;
    for (int i = tid; i < D_ * 64; i += 256) {
        int vv = i >> 6, fc = i & 63;
        Xs[vv][fc] = xb[(size_t)vv * NFFT + f0 + fc];
        Ks[vv][fc] = kb[(size_t)vv * NFFT + f0 + fc];
    }
    __syncthreads();
    for (int o = tid; o < D_ * 64; o += 256) {
        int m = o >> 6, fc = o & 63;
        float yr = 0.0f, yi = 0.0f;
        for (int u = 0; u < D_; ++u) {
            float2 kk = Ks[u][fc];
            float2 xx = Xs[(m - u) & 63][fc];
            yr += kk.x * xx.x - kk.y * xx.y;
            yi += kk.x * xx.y + kk.y * xx.x;
        }
        xb[(size_t)m * NFFT + f0 + fc] = make_float2(yr, yi);
    }
}

// ---------------- inverse FFT + GELU + bf16 scatter to convb -----------------
__global__ __launch_bounds__(256) void k_fft_inv(const float2* __restrict__ Xbuf,
                                                 bf16* __restrict__ convb) {
    __shared__ float2 lds[NFFT];
    int m = blockIdx.x, h = blockIdx.y, tid = threadIdx.x;
    const float2* in = Xbuf + ((size_t)h * D_ + m) * NFFT;
    for (int i = tid; i < NFFT; i += 256) lds[i] = in[i];
    fft_lds(lds, tid, +1.0f);
    bf16* outp = convb + (h * D_ + m);
    for (int n = tid; n < L_; n += 256) {
        float x = lds[n].x;
        float g = 0.5f * x * (1.0f + erff(x * 0.70710678118654752f));
        outp[(size_t)n * E_] = __float2bfloat16(g);
    }
}

// ---------------- sparse seq-mix: build per-row (col,val) lists --------------
__global__ __launch_bounds__(256) void k_sparse_build(const float* __restrict__ Sp,
                                                      int* __restrict__ nnz,
                                                      int* __restrict__ idxs,
                                                      float* __restrict__ vals) {
    __shared__ int cnt;
    int l = blockIdx.x, tid = threadIdx.x;
    if (tid == 0) cnt = 0;
    __syncthreads();
    const float* row = Sp + (size_t)l * L_;
    for (int s = tid; s <= l; s += 256) {
        float v = row[s];
        if (v != 0.0f) {
            int slot = atomicAdd(&cnt, 1);
            if (slot < CAP) { idxs[l * CAP + slot] = s; vals[l * CAP + slot] = v; }
        }
    }
    __syncthreads();
    if (tid == 0) nnz[l] = min(cnt, CAP);
}

// ---------------- gather-SpMM accumulate: C[b][l][:] += sum_j val_j*P[b][s_j][:]
__global__ __launch_bounds__(256) void k_spmm_acc(const int* __restrict__ nnz,
                                                  const int* __restrict__ idxs,
                                                  const float* __restrict__ vals,
                                                  const float* __restrict__ P,
                                                  float* __restrict__ C) {
    __shared__ int sidx[CAP];
    __shared__ float sval[CAP];
    int l = blockIdx.x, b = blockIdx.y, tid = threadIdx.x;
    int n = nnz[l];
    for (int j = tid; j < n; j += 256) {
        sidx[j] = idxs[l * CAP + j];
        sval[j] = vals[l * CAP + j];
    }
    __syncthreads();
    const float* Pb = P + (size_t)b * L_ * E_;
    size_t off = (size_t)tid * 4;
    float* cp = C + ((size_t)(b * L_ + l)) * E_ + off;
    float4 acc = *(float4*)cp;
    for (int j = 0; j < n; ++j) {
        float v = sval[j];
        float4 p = *(const float4*)(Pb + (size_t)sidx[j] * E_ + off);
        acc.x += v * p.x; acc.y += v * p.y; acc.z += v * p.z; acc.w += v * p.w;
    }
    *(float4*)cp = acc;
}

// ---------------- residual + LayerNorm ---------------------------------------
__global__ __launch_bounds__(256) void k_layernorm(const float* __restrict__ accb,
                                                   const float* __restrict__ emb,
                                                   const float* __restrict__ gamma,
                                                   const float* __restrict__ beta,
                                                   float* __restrict__ outp) {
    __shared__ float xs[E_];
    __shared__ float red[256];
    size_t row = blockIdx.x;
    int tid = threadIdx.x;
    const float* a = accb + row * E_;
    const float* e = emb + row * E_;
    float lsum = 0.0f;
    for (int i = tid; i < E_; i += 256) {
        float x = a[i] + e[i];
        xs[i] = x;
        lsum += x;
    }
    red[tid] = lsum; __syncthreads();
    for (int off = 128; off > 0; off >>= 1) {
        if (tid < off) red[tid] += red[tid + off];
        __syncthreads();
    }
    float mu = red[0] * (1.0f / E_);
    __syncthreads();
    float lv = 0.0f;
    for (int i = tid; i < E_; i += 256) { float d = xs[i] - mu; lv += d * d; }
    red[tid] = lv; __syncthreads();
    for (int off = 128; off > 0; off >>= 1) {
        if (tid < off) red[tid] += red[tid + off];
        __syncthreads();
    }
    float inv = rsqrtf(red[0] * (1.0f / E_) + 1e-12f);
    for (int i = tid; i < E_; i += 256)
        outp[row * E_ + i] = (xs[i] - mu) * inv * gamma[i] + beta[i];
}

extern "C" void kernel_launch(void* const* d_in, const int* in_sizes, int n_in,
                              void* d_out, int out_size, void* d_ws, size_t ws_size,
                              hipStream_t stream) {
    const float* emb    = (const float*)d_in[0];
    const float* W1     = (const float*)d_in[1];
    const float* b1     = (const float*)d_in[2];
    const float* W2     = (const float*)d_in[3];
    const float* b2     = (const float*)d_in[4];
    const float* psfs   = (const float*)d_in[5];
    const float* W3     = (const float*)d_in[6];
    const float* b3     = (const float*)d_in[7];
    const float* sparse = (const float*)d_in[8];
    const float* gamma  = (const float*)d_in[9];
    const float* beta   = (const float*)d_in[10];
    float* outp = (float*)d_out;

    const size_t BLE = (size_t)B_ * L_ * E_;   // 8.4M elems
    const size_t EE  = (size_t)E_ * E_;

    float*  pre_sparse = (float*)d_ws;                    // 33.5 MB
    float*  accb       = pre_sparse + BLE;                // 33.5 MB
    float2* Khat       = (float2*)(accb + BLE);           // 67.1 MB
    float2* Xbuf       = Khat + (size_t)H_ * D_ * NFFT;   // 67.1 MB
    bf16*   preb       = (bf16*)(Xbuf + (size_t)H_ * D_ * NFFT);  // 16.8 MB
    bf16*   actb       = preb + BLE;   // shared: embb (GEMM1) then convb (GEMM3)
    bf16*   W1b        = actb + BLE;
    bf16*   W2b        = W1b + EE;
    bf16*   W3b        = W2b + EE;
    // sparse lists overlay Xbuf (dead after the FFT loop)
    int*    s_nnz      = (int*)Xbuf;
    int*    s_idx      = s_nnz + L_;
    float*  s_val      = (float*)(s_idx + (size_t)L_ * CAP);
    // total ws use ~241 MB

    // bf16 conversions
    k_cvt<<<(int)(BLE / 4 / 256), 256, 0, stream>>>(emb, actb, (int)BLE);
    k_cvt<<<(int)(EE / 4 / 256), 256, 0, stream>>>(W1, W1b, (int)EE);
    k_cvt<<<(int)(EE / 4 / 256), 256, 0, stream>>>(W2, W2b, (int)EE);
    k_cvt<<<(int)(EE / 4 / 256), 256, 0, stream>>>(W3, W3b, (int)EE);

    // preb = bf16(emb @ W1^T + b1) ; pre_sparse = preb @ W2^T + b2 (fp32)
    k_gemm_mfma<1><<<dim3(E_ / 128, (B_ * L_) / 128), 256, 0, stream>>>(
        actb, W1b, b1, nullptr, preb, B_ * L_, E_, E_);
    k_gemm_mfma<0><<<dim3(E_ / 128, (B_ * L_) / 128), 256, 0, stream>>>(
        preb, W2b, b2, pre_sparse, nullptr, B_ * L_, E_, E_);

    // PSF softmax + seq-FFT of kernel
    k_build_khat<<<dim3(D_, H_), 256, 0, stream>>>(psfs, Khat);

    // per-batch FFT conv; conv written bf16 into actb (embb is dead)
    for (int b = 0; b < B_; ++b) {
        k_fft_fwd<<<dim3(D_, H_), 256, 0, stream>>>(preb + (size_t)b * L_ * E_, Xbuf);
        k_dconv<<<dim3(NFFT / 64, H_), 256, 0, stream>>>(Xbuf, Khat);
        k_fft_inv<<<dim3(D_, H_), 256, 0, stream>>>(Xbuf, actb + (size_t)b * L_ * E_);
    }

    // accb = convb @ W3^T + b3 (fp32)
    k_gemm_mfma<0><<<dim3(E_ / 128, (B_ * L_) / 128), 256, 0, stream>>>(
        actb, W3b, b3, accb, nullptr, B_ * L_, E_, E_);

    // accb += tril(sparse) @ pre_sparse
    k_sparse_build<<<L_, 256, 0, stream>>>(sparse, s_nnz, s_idx, s_val);
    k_spmm_acc<<<dim3(L_, B_), 256, 0, stream>>>(s_nnz, s_idx, s_val, pre_sparse, accb);

    // out = LayerNorm(accb + emb) * gamma + beta
    k_layernorm<<<B_ * L_, 256, 0, stream>>>(accb, emb, gamma, beta, outp);
}

// Round 4
// 937.654 us; speedup vs baseline: 3.3474x; 1.6239x over previous
//
#include <hip/hip_runtime.h>
#include <hip/hip_bf16.h>
#include <math.h>

#define B_ 4
#define L_ 2048
#define E_ 1024
#define H_ 16
#define D_ 64
#define NFFT 8192
#define LOG2N 13
#define CAP 128

typedef __hip_bfloat16 bf16;
typedef __attribute__((ext_vector_type(8))) short bf16x8;
typedef __attribute__((ext_vector_type(4))) float f32x4;

typedef __attribute__((address_space(1))) const unsigned int gas_u32;
typedef __attribute__((address_space(3))) unsigned int las_u32;

__device__ __forceinline__ void gload_lds16(const void* g, void* l) {
    __builtin_amdgcn_global_load_lds((gas_u32*)g, (las_u32*)l, 16, 0, 0);
}

// ---------------- twiddle table: tw[k] = exp(-2*pi*i*k/8192), k < 4096 -------
__global__ __launch_bounds__(256) void k_twiddle(float2* __restrict__ tw) {
    int k = blockIdx.x * 256 + threadIdx.x;
    if (k < NFFT / 2) {
        float ang = -(float)k * (float)(M_PI / 4096.0);
        tw[k] = make_float2(cosf(ang), sinf(ang));
    }
}

// ---------------- 8192-pt FFT, SoA LDS, DIF fwd (natural in -> bitrev out) ---
__device__ inline void fft8k_dif(float* re, float* im, int tid, const float2* __restrict__ tw) {
    for (int s = LOG2N; s >= 1; --s) {
        int half = 1 << (s - 1);
        __syncthreads();
        for (int k = tid; k < NFFT / 2; k += 256) {
            int pos = k & (half - 1);
            int grp = k >> (s - 1);
            int i0 = (grp << s) + pos;
            int i1 = i0 + half;
            float2 w = tw[pos << (LOG2N - s)];
            float ur = re[i0], ui = im[i0], vr = re[i1], vi = im[i1];
            re[i0] = ur + vr; im[i0] = ui + vi;
            float dr = ur - vr, di = ui - vi;
            re[i1] = dr * w.x - di * w.y;
            im[i1] = dr * w.y + di * w.x;
        }
    }
    __syncthreads();
}

// ---------------- 8192-pt inverse DIT (bitrev in -> natural out, unscaled) ---
__device__ inline void fft8k_dit_inv(float* re, float* im, int tid, const float2* __restrict__ tw) {
    for (int s = 1; s <= LOG2N; ++s) {
        int half = 1 << (s - 1);
        __syncthreads();
        for (int k = tid; k < NFFT / 2; k += 256) {
            int pos = k & (half - 1);
            int grp = k >> (s - 1);
            int i0 = (grp << s) + pos;
            int i1 = i0 + half;
            float2 w = tw[pos << (LOG2N - s)];  // conj applied in butterfly
            float vr = re[i1], vi = im[i1];
            float tr = vr * w.x + vi * w.y;
            float ti = vi * w.x - vr * w.y;
            float ur = re[i0], ui = im[i0];
            re[i0] = ur + tr; im[i0] = ui + ti;
            re[i1] = ur - tr; im[i1] = ui - ti;
        }
    }
    __syncthreads();
}

// ---------------- fp32 -> bf16 convert (vectorized) --------------------------
__global__ __launch_bounds__(256) void k_cvt(const float* __restrict__ in,
                                             bf16* __restrict__ out, int n) {
    int i = (blockIdx.x * 256 + threadIdx.x) * 4;
    if (i >= n) return;
    float4 v = *(const float4*)(in + i);
    bf16 tmp[4];
    tmp[0] = __float2bfloat16(v.x);
    tmp[1] = __float2bfloat16(v.y);
    tmp[2] = __float2bfloat16(v.z);
    tmp[3] = __float2bfloat16(v.w);
    *(ushort4*)(out + i) = *(ushort4*)tmp;
}

// ---------------- bf16 MFMA GEMM (m97 structure): C = A @ Wt^T + bias --------
template <int OUTB>
__global__ __launch_bounds__(256) void k_gemm_mfma(const bf16* __restrict__ A,
                                                   const bf16* __restrict__ Wt,
                                                   const float* __restrict__ bias,
                                                   float* __restrict__ C,
                                                   bf16* __restrict__ Cb,
                                                   int M, int N, int K) {
    __shared__ bf16 As[128 * 32];
    __shared__ bf16 Bs[128 * 32];
    int tid = threadIdx.x;
    int lane = tid & 63, w = tid >> 6;
    int wr = w >> 1, wc = w & 1;
    int by = blockIdx.y * 128;
    int bx = blockIdx.x * 128;

    f32x4 zz = {0.0f, 0.0f, 0.0f, 0.0f};
    f32x4 acc[4][4];
#pragma unroll
    for (int m = 0; m < 4; ++m)
#pragma unroll
        for (int n = 0; n < 4; ++n) acc[m][n] = zz;

    int koff = (lane >> 4) * 8;
    int rsub = lane & 15;

    for (int k0 = 0; k0 < K; k0 += 32) {
#pragma unroll
        for (int i = 0; i < 2; ++i) {
            int c = tid + i * 256;
            int row = c >> 2;
            int kb = (c & 3) * 8;
            gload_lds16(A + (size_t)(by + row) * K + k0 + kb, &As[c * 8]);
            gload_lds16(Wt + (size_t)(bx + row) * K + k0 + kb, &Bs[c * 8]);
        }
        __syncthreads();
        bf16x8 af[4], bfv[4];
#pragma unroll
        for (int m = 0; m < 4; ++m)
            af[m] = *(const bf16x8*)&As[(wr * 64 + m * 16 + rsub) * 32 + koff];
#pragma unroll
        for (int n = 0; n < 4; ++n)
            bfv[n] = *(const bf16x8*)&Bs[(wc * 64 + n * 16 + rsub) * 32 + koff];
#pragma unroll
        for (int m = 0; m < 4; ++m)
#pragma unroll
            for (int n = 0; n < 4; ++n)
                acc[m][n] = __builtin_amdgcn_mfma_f32_16x16x32_bf16(af[m], bfv[n], acc[m][n], 0, 0, 0);
        __syncthreads();
    }

    int cq = (lane >> 4) * 4;
    int cr = lane & 15;
#pragma unroll
    for (int m = 0; m < 4; ++m) {
        int row0 = by + wr * 64 + m * 16 + cq;
#pragma unroll
        for (int n = 0; n < 4; ++n) {
            int col = bx + wc * 64 + n * 16 + cr;
            float bv = bias[col];
#pragma unroll
            for (int j = 0; j < 4; ++j) {
                float v = acc[m][n][j] + bv;
                if constexpr (OUTB)
                    Cb[(size_t)(row0 + j) * N + col] = __float2bfloat16(v);
                else
                    C[(size_t)(row0 + j) * N + col] = v;
            }
        }
    }
}

// ---------------- PSF softmax + K8192 construction + seq-DIF-FFT -------------
__global__ __launch_bounds__(256) void k_build_khat(const float* __restrict__ psfs,
                                                    float2* __restrict__ Khat,
                                                    const float2* __restrict__ tw) {
    __shared__ float re[NFFT];
    __shared__ float im[NFFT];
    __shared__ float red[256];
    int u = blockIdx.x, h = blockIdx.y, tid = threadIdx.x;
    const float* col = psfs + (size_t)h * (2 * L_ - 1) * D_ + u;

    float lm = -1e30f;
    for (int t = tid; t < L_; t += 256) lm = fmaxf(lm, col[(size_t)t * D_]);
    red[tid] = lm; __syncthreads();
    for (int off = 128; off > 0; off >>= 1) {
        if (tid < off) red[tid] = fmaxf(red[tid], red[tid + off]);
        __syncthreads();
    }
    float M = fmaxf(red[0], 0.0f);
    __syncthreads();

    float ls = 0.0f;
    for (int t = tid; t < L_; t += 256) ls += expf(col[(size_t)t * D_] - M);
    red[tid] = ls; __syncthreads();
    for (int off = 128; off > 0; off >>= 1) {
        if (tid < off) red[tid] += red[tid + off];
        __syncthreads();
    }
    float Z = red[0] + (float)(L_ - 1) * expf(-M);
    __syncthreads();

    float invZ = 1.0f / Z;
    float cval = expf(-M) * invZ;
    for (int i = tid; i < NFFT; i += 256) {
        float r;
        if (i < L_)                     r = expf(col[(size_t)i * D_] - M) * invZ;
        else if (i >= NFFT - (L_ - 1))  r = cval;
        else                            r = 0.0f;
        re[i] = r; im[i] = 0.0f;
    }
    fft8k_dif(re, im, tid, tw);
    float sc = 1.0f / (float)NFFT;
    float2* outp = Khat + ((size_t)h * D_ + u) * NFFT;
    for (int i = tid; i < NFFT; i += 256)
        outp[i] = make_float2(re[i] * sc, im[i] * sc);
}

// ---------------- in-place DIF-FFT64 over u of Khat (+1/64 scale) ------------
__global__ __launch_bounds__(256) void k_khat_dfft(float2* __restrict__ Khat,
                                                   const float2* __restrict__ tw) {
    __shared__ float Xre[4096];
    __shared__ float Xim[4096];
    int f0 = blockIdx.x * 64, h = blockIdx.y, tid = threadIdx.x;
    float2* kb = Khat + (size_t)h * D_ * NFFT;
    for (int i = tid; i < 4096; i += 256) {
        int uu = i >> 6, fc = i & 63;
        float2 v = kb[(size_t)uu * NFFT + f0 + fc];
        Xre[i] = v.x; Xim[i] = v.y;
    }
    for (int s = 6; s >= 1; --s) {
        int half = 1 << (s - 1);
        __syncthreads();
        for (int k = tid; k < 2048; k += 256) {
            int fc = k & 63, b = k >> 6;
            int pos = b & (half - 1), grp = b >> (s - 1);
            int i0 = ((grp << s) + pos) * 64 + fc;
            int i1 = i0 + half * 64;
            float2 w = tw[pos << (LOG2N - s)];
            float ur = Xre[i0], ui = Xim[i0], vr = Xre[i1], vi = Xim[i1];
            Xre[i0] = ur + vr; Xim[i0] = ui + vi;
            float dr = ur - vr, di = ui - vi;
            Xre[i1] = dr * w.x - di * w.y;
            Xim[i1] = dr * w.y + di * w.x;
        }
    }
    __syncthreads();
    float sc = 1.0f / 64.0f;
    for (int i = tid; i < 4096; i += 256) {
        int uu = i >> 6, fc = i & 63;
        kb[(size_t)uu * NFFT + f0 + fc] = make_float2(Xre[i] * sc, Xim[i] * sc);
    }
}

// ---------------- packed fwd FFT: z = pre_b0 + i*pre_b1, per (h,v) column ----
__global__ __launch_bounds__(256) void k_fft_fwd(const bf16* __restrict__ p0,
                                                 const bf16* __restrict__ p1,
                                                 float2* __restrict__ Xbuf,
                                                 const float2* __restrict__ tw) {
    __shared__ float re[NFFT];
    __shared__ float im[NFFT];
    int v = blockIdx.x, h = blockIdx.y, tid = threadIdx.x;
    const bf16* c0 = p0 + (size_t)(h * D_ + v);
    const bf16* c1 = p1 + (size_t)(h * D_ + v);
    for (int i = tid; i < NFFT; i += 256) {
        if (i < L_) {
            re[i] = __bfloat162float(c0[(size_t)i * E_]);
            im[i] = __bfloat162float(c1[(size_t)i * E_]);
        } else { re[i] = 0.0f; im[i] = 0.0f; }
    }
    fft8k_dif(re, im, tid, tw);
    float2* outp = Xbuf + ((size_t)h * D_ + v) * NFFT;
    for (int i = tid; i < NFFT; i += 256) outp[i] = make_float2(re[i], im[i]);
}

// ------- d-axis: DIF64 over v, cmul with Khat2, DIT64 inverse (in place) -----
__global__ __launch_bounds__(256) void k_dconv(float2* __restrict__ Xbuf,
                                               const float2* __restrict__ Khat,
                                               const float2* __restrict__ tw) {
    __shared__ float Xre[4096];
    __shared__ float Xim[4096];
    __shared__ float Kre[4096];
    __shared__ float Kim[4096];
    int f0 = blockIdx.x * 64, h = blockIdx.y, tid = threadIdx.x;
    float2* xb = Xbuf + (size_t)h * D_ * NFFT;
    const float2* kb = Khat + (size_t)h * D_ * NFFT;
    for (int i = tid; i < 4096; i += 256) {
        int vv = i >> 6, fc = i & 63;
        float2 x = xb[(size_t)vv * NFFT + f0 + fc];
        float2 k = kb[(size_t)vv * NFFT + f0 + fc];
        Xre[i] = x.x; Xim[i] = x.y; Kre[i] = k.x; Kim[i] = k.y;
    }
    // forward DIF64 over v (batched over the 64 freqs)
    for (int s = 6; s >= 1; --s) {
        int half = 1 << (s - 1);
        __syncthreads();
        for (int k = tid; k < 2048; k += 256) {
            int fc = k & 63, b = k >> 6;
            int pos = b & (half - 1), grp = b >> (s - 1);
            int i0 = ((grp << s) + pos) * 64 + fc;
            int i1 = i0 + half * 64;
            float2 w = tw[pos << (LOG2N - s)];
            float ur = Xre[i0], ui = Xim[i0], vr = Xre[i1], vi = Xim[i1];
            Xre[i0] = ur + vr; Xim[i0] = ui + vi;
            float dr = ur - vr, di = ui - vi;
            Xre[i1] = dr * w.x - di * w.y;
            Xim[i1] = dr * w.y + di * w.x;
        }
    }
    __syncthreads();
    // pointwise multiply
    for (int i = tid; i < 4096; i += 256) {
        float xr = Xre[i], xi = Xim[i], kr = Kre[i], ki = Kim[i];
        Xre[i] = xr * kr - xi * ki;
        Xim[i] = xr * ki + xi * kr;
    }
    // inverse DIT64 over q
    for (int s = 1; s <= 6; ++s) {
        int half = 1 << (s - 1);
        __syncthreads();
        for (int k = tid; k < 2048; k += 256) {
            int fc = k & 63, b = k >> 6;
            int pos = b & (half - 1), grp = b >> (s - 1);
            int i0 = ((grp << s) + pos) * 64 + fc;
            int i1 = i0 + half * 64;
            float2 w = tw[pos << (LOG2N - s)];
            float vr = Xre[i1], vi = Xim[i1];
            float tr = vr * w.x + vi * w.y;
            float ti = vi * w.x - vr * w.y;
            float ur = Xre[i0], ui = Xim[i0];
            Xre[i0] = ur + tr; Xim[i0] = ui + ti;
            Xre[i1] = ur - tr; Xim[i1] = ui - ti;
        }
    }
    __syncthreads();
    for (int i = tid; i < 4096; i += 256) {
        int vv = i >> 6, fc = i & 63;
        xb[(size_t)vv * NFFT + f0 + fc] = make_float2(Xre[i], Xim[i]);
    }
}

// ------- packed inverse FFT + GELU: re -> conv_b0, im -> conv_b1 (bf16) ------
__global__ __launch_bounds__(256) void k_fft_inv(const float2* __restrict__ Xbuf,
                                                 bf16* __restrict__ o0b,
                                                 bf16* __restrict__ o1b,
                                                 const float2* __restrict__ tw) {
    __shared__ float re[NFFT];
    __shared__ float im[NFFT];
    int m = blockIdx.x, h = blockIdx.y, tid = threadIdx.x;
    const float2* in = Xbuf + ((size_t)h * D_ + m) * NFFT;
    for (int i = tid; i < NFFT; i += 256) {
        float2 v = in[i];
        re[i] = v.x; im[i] = v.y;
    }
    fft8k_dit_inv(re, im, tid, tw);
    bf16* o0 = o0b + (h * D_ + m);
    bf16* o1 = o1b + (h * D_ + m);
    for (int n = tid; n < L_; n += 256) {
        float x0 = re[n], x1 = im[n];
        float g0 = 0.5f * x0 * (1.0f + erff(x0 * 0.70710678118654752f));
        float g1 = 0.5f * x1 * (1.0f + erff(x1 * 0.70710678118654752f));
        o0[(size_t)n * E_] = __float2bfloat16(g0);
        o1[(size_t)n * E_] = __float2bfloat16(g1);
    }
}

// ---------------- sparse seq-mix: build per-row (col,val) lists --------------
__global__ __launch_bounds__(256) void k_sparse_build(const float* __restrict__ Sp,
                                                      int* __restrict__ nnz,
                                                      int* __restrict__ idxs,
                                                      float* __restrict__ vals) {
    __shared__ int cnt;
    int l = blockIdx.x, tid = threadIdx.x;
    if (tid == 0) cnt = 0;
    __syncthreads();
    const float* row = Sp + (size_t)l * L_;
    for (int s = tid; s <= l; s += 256) {
        float v = row[s];
        if (v != 0.0f) {
            int slot = atomicAdd(&cnt, 1);
            if (slot < CAP) { idxs[l * CAP + slot] = s; vals[l * CAP + slot] = v; }
        }
    }
    __syncthreads();
    if (tid == 0) nnz[l] = min(cnt, CAP);
}

// ---------------- gather-SpMM accumulate -------------------------------------
__global__ __launch_bounds__(256) void k_spmm_acc(const int* __restrict__ nnz,
                                                  const int* __restrict__ idxs,
                                                  const float* __restrict__ vals,
                                                  const float* __restrict__ P,
                                                  float* __restrict__ C) {
    __shared__ int sidx[CAP];
    __shared__ float sval[CAP];
    int l = blockIdx.x, b = blockIdx.y, tid = threadIdx.x;
    int n = nnz[l];
    for (int j = tid; j < n; j += 256) {
        sidx[j] = idxs[l * CAP + j];
        sval[j] = vals[l * CAP + j];
    }
    __syncthreads();
    const float* Pb = P + (size_t)b * L_ * E_;
    size_t off = (size_t)tid * 4;
    float* cp = C + ((size_t)(b * L_ + l)) * E_ + off;
    float4 acc = *(float4*)cp;
    for (int j = 0; j < n; ++j) {
        float v = sval[j];
        float4 p = *(const float4*)(Pb + (size_t)sidx[j] * E_ + off);
        acc.x += v * p.x; acc.y += v * p.y; acc.z += v * p.z; acc.w += v * p.w;
    }
    *(float4*)cp = acc;
}

// ---------------- residual + LayerNorm ---------------------------------------
__global__ __launch_bounds__(256) void k_layernorm(const float* __restrict__ accb,
                                                   const float* __restrict__ emb,
                                                   const float* __restrict__ gamma,
                                                   const float* __restrict__ beta,
                                                   float* __restrict__ outp) {
    __shared__ float xs[E_];
    __shared__ float red[256];
    size_t row = blockIdx.x;
    int tid = threadIdx.x;
    const float* a = accb + row * E_;
    const float* e = emb + row * E_;
    float lsum = 0.0f;
    for (int i = tid; i < E_; i += 256) {
        float x = a[i] + e[i];
        xs[i] = x;
        lsum += x;
    }
    red[tid] = lsum; __syncthreads();
    for (int off = 128; off > 0; off >>= 1) {
        if (tid < off) red[tid] += red[tid + off];
        __syncthreads();
    }
    float mu = red[0] * (1.0f / E_);
    __syncthreads();
    float lv = 0.0f;
    for (int i = tid; i < E_; i += 256) { float d = xs[i] - mu; lv += d * d; }
    red[tid] = lv; __syncthreads();
    for (int off = 128; off > 0; off >>= 1) {
        if (tid < off) red[tid] += red[tid + off];
        __syncthreads();
    }
    float inv = rsqrtf(red[0] * (1.0f / E_) + 1e-12f);
    for (int i = tid; i < E_; i += 256)
        outp[row * E_ + i] = (xs[i] - mu) * inv * gamma[i] + beta[i];
}

extern "C" void kernel_launch(void* const* d_in, const int* in_sizes, int n_in,
                              void* d_out, int out_size, void* d_ws, size_t ws_size,
                              hipStream_t stream) {
    const float* emb    = (const float*)d_in[0];
    const float* W1     = (const float*)d_in[1];
    const float* b1     = (const float*)d_in[2];
    const float* W2     = (const float*)d_in[3];
    const float* b2     = (const float*)d_in[4];
    const float* psfs   = (const float*)d_in[5];
    const float* W3     = (const float*)d_in[6];
    const float* b3     = (const float*)d_in[7];
    const float* sparse = (const float*)d_in[8];
    const float* gamma  = (const float*)d_in[9];
    const float* beta   = (const float*)d_in[10];
    float* outp = (float*)d_out;

    const size_t BLE = (size_t)B_ * L_ * E_;
    const size_t LE  = (size_t)L_ * E_;
    const size_t EE  = (size_t)E_ * E_;

    float*  pre_sparse = (float*)d_ws;                           // 33.5 MB
    float*  accb       = pre_sparse + BLE;                       // 33.5 MB
    float2* Khat       = (float2*)(accb + BLE);                  // 67.1 MB
    float2* Xbuf       = Khat + (size_t)H_ * D_ * NFFT;          // 67.1 MB
    bf16*   preb       = (bf16*)(Xbuf + (size_t)H_ * D_ * NFFT); // 16.8 MB
    bf16*   actb       = preb + BLE;                             // 16.8 MB
    bf16*   W1b        = actb + BLE;
    bf16*   W2b        = W1b + EE;
    bf16*   W3b        = W2b + EE;
    float2* twd        = (float2*)(W3b + EE);                    // 32 KB
    // sparse lists overlay Xbuf (dead after the FFT loop)
    int*    s_nnz      = (int*)Xbuf;
    int*    s_idx      = s_nnz + L_;
    float*  s_val      = (float*)(s_idx + (size_t)L_ * CAP);

    // twiddle table + bf16 conversions
    k_twiddle<<<16, 256, 0, stream>>>(twd);
    k_cvt<<<(int)(BLE / 4 / 256), 256, 0, stream>>>(emb, actb, (int)BLE);
    k_cvt<<<(int)(EE / 4 / 256), 256, 0, stream>>>(W1, W1b, (int)EE);
    k_cvt<<<(int)(EE / 4 / 256), 256, 0, stream>>>(W2, W2b, (int)EE);
    k_cvt<<<(int)(EE / 4 / 256), 256, 0, stream>>>(W3, W3b, (int)EE);

    // preb = bf16(emb @ W1^T + b1) ; pre_sparse = preb @ W2^T + b2 (fp32)
    k_gemm_mfma<1><<<dim3(E_ / 128, (B_ * L_) / 128), 256, 0, stream>>>(
        actb, W1b, b1, nullptr, preb, B_ * L_, E_, E_);
    k_gemm_mfma<0><<<dim3(E_ / 128, (B_ * L_) / 128), 256, 0, stream>>>(
        preb, W2b, b2, pre_sparse, nullptr, B_ * L_, E_, E_);

    // PSF softmax + seq-FFT, then in-place d-FFT of the kernel spectrum
    k_build_khat<<<dim3(D_, H_), 256, 0, stream>>>(psfs, Khat, twd);
    k_khat_dfft<<<dim3(NFFT / 64, H_), 256, 0, stream>>>(Khat, twd);

    // packed 2-batch FFT conv passes: (b0,b1) and (b2,b3)
    for (int p = 0; p < B_; p += 2) {
        k_fft_fwd<<<dim3(D_, H_), 256, 0, stream>>>(
            preb + (size_t)p * LE, preb + (size_t)(p + 1) * LE, Xbuf, twd);
        k_dconv<<<dim3(NFFT / 64, H_), 256, 0, stream>>>(Xbuf, Khat, twd);
        k_fft_inv<<<dim3(D_, H_), 256, 0, stream>>>(
            Xbuf, actb + (size_t)p * LE, actb + (size_t)(p + 1) * LE, twd);
    }

    // accb = convb @ W3^T + b3 (fp32)
    k_gemm_mfma<0><<<dim3(E_ / 128, (B_ * L_) / 128), 256, 0, stream>>>(
        actb, W3b, b3, accb, nullptr, B_ * L_, E_, E_);

    // accb += tril(sparse) @ pre_sparse
    k_sparse_build<<<L_, 256, 0, stream>>>(sparse, s_nnz, s_idx, s_val);
    k_spmm_acc<<<dim3(L_, B_), 256, 0, stream>>>(s_nnz, s_idx, s_val, pre_sparse, accb);

    // out = LayerNorm(accb + emb) * gamma + beta
    k_layernorm<<<B_ * L_, 256, 0, stream>>>(accb, emb, gamma, beta, outp);
}

// Round 5
// 654.009 us; speedup vs baseline: 4.7991x; 1.4337x over previous
//
#include <hip/hip_runtime.h>
#include <hip/hip_bf16.h>
#include <math.h>

#define B_ 4
#define L_ 2048
#define E_ 1024
#define H_ 16
#define D_ 64
#define NFFT 8192
#define LOG2N 13
#define CAP 128

typedef __hip_bfloat16 bf16;
typedef __attribute__((ext_vector_type(8))) short bf16x8;
typedef __attribute__((ext_vector_type(4))) float f32x4;

typedef __attribute__((address_space(1))) const unsigned int gas_u32;
typedef __attribute__((address_space(3))) unsigned int las_u32;

__device__ __forceinline__ void gload_lds16(const void* g, void* l) {
    __builtin_amdgcn_global_load_lds((gas_u32*)g, (las_u32*)l, 16, 0, 0);
}

// LDS bank swizzle for the 8K FFT (bijective within 32-blocks)
#define SWZ(i) ((i) ^ (((i) >> 3) & 28))

__device__ __forceinline__ float bfu2f(unsigned short u) {
    return __uint_as_float(((unsigned)u) << 16);
}

// ---------------- twiddle table: tw[k] = exp(-2*pi*i*k/8192), k < 8192 -------
__global__ __launch_bounds__(256) void k_twiddle(float2* __restrict__ tw) {
    int k = blockIdx.x * 256 + threadIdx.x;
    if (k < NFFT) {
        float ang = -(float)k * (float)(M_PI / 4096.0);
        tw[k] = make_float2(cosf(ang), sinf(ang));
    }
}

// ------------- 8192-pt radix-4 DIF forward (natural in -> digit-rev out) -----
__device__ inline void fft8k_r4_dif(float* re, float* im, int tid,
                                    const float2* __restrict__ tw) {
    for (int st = 0; st < 6; ++st) {
        int q = 1 << (11 - 2 * st);
        __syncthreads();
        for (int it = 0; it < 8; ++it) {
            int b = tid + (it << 8);
            int p = b & (q - 1);
            int base = ((b & ~(q - 1)) << 2) | p;
            int i0 = SWZ(base), i1 = SWZ(base + q), i2 = SWZ(base + 2 * q), i3 = SWZ(base + 3 * q);
            float x0r = re[i0], x0i = im[i0], x1r = re[i1], x1i = im[i1];
            float x2r = re[i2], x2i = im[i2], x3r = re[i3], x3i = im[i3];
            float a0r = x0r + x2r, a0i = x0i + x2i;
            float a1r = x0r - x2r, a1i = x0i - x2i;
            float a2r = x1r + x3r, a2i = x1i + x3i;
            float a3r = x1r - x3r, a3i = x1i - x3i;
            float y0r = a0r + a2r, y0i = a0i + a2i;
            float y2r = a0r - a2r, y2i = a0i - a2i;
            float y1r = a1r + a3i, y1i = a1i - a3r;
            float y3r = a1r - a3i, y3i = a1i + a3r;
            int e = p << (2 * st);
            float2 w1 = tw[e], w2 = tw[2 * e], w3 = tw[3 * e];
            re[i0] = y0r; im[i0] = y0i;
            re[i1] = y1r * w1.x - y1i * w1.y; im[i1] = y1r * w1.y + y1i * w1.x;
            re[i2] = y2r * w2.x - y2i * w2.y; im[i2] = y2r * w2.y + y2i * w2.x;
            re[i3] = y3r * w3.x - y3i * w3.y; im[i3] = y3r * w3.y + y3i * w3.x;
        }
    }
    __syncthreads();
    for (int it = 0; it < 16; ++it) {
        int b = tid + (it << 8);
        int i0 = SWZ(2 * b), i1 = SWZ(2 * b + 1);
        float ur = re[i0], ui = im[i0], vr = re[i1], vi = im[i1];
        re[i0] = ur + vr; im[i0] = ui + vi;
        re[i1] = ur - vr; im[i1] = ui - vi;
    }
    __syncthreads();
}

// ------------- 8192-pt radix-4 DIT inverse (digit-rev in -> natural out) -----
__device__ inline void fft8k_r4_inv(float* re, float* im, int tid,
                                    const float2* __restrict__ tw) {
    __syncthreads();
    for (int it = 0; it < 16; ++it) {
        int b = tid + (it << 8);
        int i0 = SWZ(2 * b), i1 = SWZ(2 * b + 1);
        float ur = re[i0], ui = im[i0], vr = re[i1], vi = im[i1];
        re[i0] = ur + vr; im[i0] = ui + vi;
        re[i1] = ur - vr; im[i1] = ui - vi;
    }
    for (int st = 5; st >= 0; --st) {
        int q = 1 << (11 - 2 * st);
        __syncthreads();
        for (int it = 0; it < 8; ++it) {
            int b = tid + (it << 8);
            int p = b & (q - 1);
            int base = ((b & ~(q - 1)) << 2) | p;
            int i0 = SWZ(base), i1 = SWZ(base + q), i2 = SWZ(base + 2 * q), i3 = SWZ(base + 3 * q);
            int e = p << (2 * st);
            float2 w1 = tw[e], w2 = tw[2 * e], w3 = tw[3 * e];
            float z0r = re[i0], z0i = im[i0];
            float t1r = re[i1], t1i = im[i1];
            float t2r = re[i2], t2i = im[i2];
            float t3r = re[i3], t3i = im[i3];
            float z1r = t1r * w1.x + t1i * w1.y, z1i = t1i * w1.x - t1r * w1.y;
            float z2r = t2r * w2.x + t2i * w2.y, z2i = t2i * w2.x - t2r * w2.y;
            float z3r = t3r * w3.x + t3i * w3.y, z3i = t3i * w3.x - t3r * w3.y;
            float b0r = z0r + z2r, b0i = z0i + z2i;
            float b1r = z0r - z2r, b1i = z0i - z2i;
            float b2r = z1r + z3r, b2i = z1i + z3i;
            float b3r = z1r - z3r, b3i = z1i - z3i;
            re[i0] = b0r + b2r; im[i0] = b0i + b2i;
            re[i2] = b0r - b2r; im[i2] = b0i - b2i;
            re[i1] = b1r - b3i; im[i1] = b1i + b3r;
            re[i3] = b1r + b3i; im[i3] = b1i - b3r;
        }
    }
    __syncthreads();
}

// ------- batched 64-pt radix-4 FFT over v in [v][fc] LDS layout (4096 el) ----
__device__ inline void fft64_b(float* xr, float* xi, int tid,
                               const float2* __restrict__ tw, int inv) {
    if (!inv) {
        for (int st = 0; st < 3; ++st) {
            int q = 1 << (4 - 2 * st);
            __syncthreads();
            for (int it = 0; it < 4; ++it) {
                int b = tid + (it << 8);
                int fc = b & 63;
                int bc = b >> 6;
                int p = bc & (q - 1);
                int basev = ((bc & ~(q - 1)) << 2) | p;
                int i0 = basev * 64 + fc, i1 = i0 + q * 64, i2 = i1 + q * 64, i3 = i2 + q * 64;
                float x0r = xr[i0], x0i = xi[i0], x1r = xr[i1], x1i = xi[i1];
                float x2r = xr[i2], x2i = xi[i2], x3r = xr[i3], x3i = xi[i3];
                float a0r = x0r + x2r, a0i = x0i + x2i;
                float a1r = x0r - x2r, a1i = x0i - x2i;
                float a2r = x1r + x3r, a2i = x1i + x3i;
                float a3r = x1r - x3r, a3i = x1i - x3i;
                float y0r = a0r + a2r, y0i = a0i + a2i;
                float y2r = a0r - a2r, y2i = a0i - a2i;
                float y1r = a1r + a3i, y1i = a1i - a3r;
                float y3r = a1r - a3i, y3i = a1i + a3r;
                int e = (p << (2 * st)) * 128;
                float2 w1 = tw[e], w2 = tw[2 * e], w3 = tw[3 * e];
                xr[i0] = y0r; xi[i0] = y0i;
                xr[i1] = y1r * w1.x - y1i * w1.y; xi[i1] = y1r * w1.y + y1i * w1.x;
                xr[i2] = y2r * w2.x - y2i * w2.y; xi[i2] = y2r * w2.y + y2i * w2.x;
                xr[i3] = y3r * w3.x - y3i * w3.y; xi[i3] = y3r * w3.y + y3i * w3.x;
            }
        }
    } else {
        for (int st = 2; st >= 0; --st) {
            int q = 1 << (4 - 2 * st);
            __syncthreads();
            for (int it = 0; it < 4; ++it) {
                int b = tid + (it << 8);
                int fc = b & 63;
                int bc = b >> 6;
                int p = bc & (q - 1);
                int basev = ((bc & ~(q - 1)) << 2) | p;
                int i0 = basev * 64 + fc, i1 = i0 + q * 64, i2 = i1 + q * 64, i3 = i2 + q * 64;
                int e = (p << (2 * st)) * 128;
                float2 w1 = tw[e], w2 = tw[2 * e], w3 = tw[3 * e];
                float z0r = xr[i0], z0i = xi[i0];
                float t1r = xr[i1], t1i = xi[i1];
                float t2r = xr[i2], t2i = xi[i2];
                float t3r = xr[i3], t3i = xi[i3];
                float z1r = t1r * w1.x + t1i * w1.y, z1i = t1i * w1.x - t1r * w1.y;
                float z2r = t2r * w2.x + t2i * w2.y, z2i = t2i * w2.x - t2r * w2.y;
                float z3r = t3r * w3.x + t3i * w3.y, z3i = t3i * w3.x - t3r * w3.y;
                float b0r = z0r + z2r, b0i = z0i + z2i;
                float b1r = z0r - z2r, b1i = z0i - z2i;
                float b2r = z1r + z3r, b2i = z1i + z3i;
                float b3r = z1r - z3r, b3i = z1i - z3i;
                xr[i0] = b0r + b2r; xi[i0] = b0i + b2i;
                xr[i2] = b0r - b2r; xi[i2] = b0i - b2i;
                xr[i1] = b1r - b3i; xi[i1] = b1i + b3r;
                xr[i3] = b1r + b3i; xi[i3] = b1i - b3r;
            }
        }
    }
    __syncthreads();
}

// ---------------- fp32 -> bf16 convert (vectorized) --------------------------
__global__ __launch_bounds__(256) void k_cvt(const float* __restrict__ in,
                                             bf16* __restrict__ out, int n) {
    int i = (blockIdx.x * 256 + threadIdx.x) * 4;
    if (i >= n) return;
    float4 v = *(const float4*)(in + i);
    bf16 tmp[4];
    tmp[0] = __float2bfloat16(v.x);
    tmp[1] = __float2bfloat16(v.y);
    tmp[2] = __float2bfloat16(v.z);
    tmp[3] = __float2bfloat16(v.w);
    *(ushort4*)(out + i) = *(ushort4*)tmp;
}

// ---------------- fp32 transpose: out[c*R+r] = in[r*C+c], 64x64 tiles --------
__global__ __launch_bounds__(256) void k_tf32(const float* __restrict__ in,
                                              float* __restrict__ out,
                                              int R, int C, long inB, long outB) {
    __shared__ float tile[64][65];
    in += (size_t)blockIdx.z * inB;
    out += (size_t)blockIdx.z * outB;
    int r0 = blockIdx.y * 64, c0 = blockIdx.x * 64;
    int t = threadIdx.x;
    int tx4 = (t & 15) * 4, ty = t >> 4;
#pragma unroll
    for (int k = 0; k < 4; ++k) {
        int r = ty + 16 * k;
        float4 v = *(const float4*)&in[(size_t)(r0 + r) * C + c0 + tx4];
        tile[r][tx4 + 0] = v.x; tile[r][tx4 + 1] = v.y;
        tile[r][tx4 + 2] = v.z; tile[r][tx4 + 3] = v.w;
    }
    __syncthreads();
#pragma unroll
    for (int k = 0; k < 4; ++k) {
        int c = ty + 16 * k;
        float4 w;
        w.x = tile[tx4 + 0][c]; w.y = tile[tx4 + 1][c];
        w.z = tile[tx4 + 2][c]; w.w = tile[tx4 + 3][c];
        *(float4*)&out[(size_t)(c0 + c) * R + r0 + tx4] = w;
    }
}

// ---------------- bf16 transpose: out[c*R+r] = in[r*C+c], 64x64 tiles --------
__global__ __launch_bounds__(256) void k_tbf16(const bf16* __restrict__ in,
                                               bf16* __restrict__ out,
                                               int R, int C, long inB, long outB) {
    __shared__ unsigned short tile[64][65];
    in += (size_t)blockIdx.z * inB;
    out += (size_t)blockIdx.z * outB;
    int r0 = blockIdx.y * 64, c0 = blockIdx.x * 64;
    int t = threadIdx.x;
    int tx4 = (t & 15) * 4, ty = t >> 4;
#pragma unroll
    for (int k = 0; k < 4; ++k) {
        int r = ty + 16 * k;
        ushort4 v = *(const ushort4*)&in[(size_t)(r0 + r) * C + c0 + tx4];
        tile[r][tx4 + 0] = v.x; tile[r][tx4 + 1] = v.y;
        tile[r][tx4 + 2] = v.z; tile[r][tx4 + 3] = v.w;
    }
    __syncthreads();
#pragma unroll
    for (int k = 0; k < 4; ++k) {
        int c = ty + 16 * k;
        ushort4 w;
        w.x = tile[tx4 + 0][c]; w.y = tile[tx4 + 1][c];
        w.z = tile[tx4 + 2][c]; w.w = tile[tx4 + 3][c];
        *(ushort4*)&out[(size_t)(c0 + c) * R + r0 + tx4] = w;
    }
}

// ---------------- bf16 MFMA GEMM (m97 structure): C = A @ Wt^T + bias --------
template <int OUTB>
__global__ __launch_bounds__(256) void k_gemm_mfma(const bf16* __restrict__ A,
                                                   const bf16* __restrict__ Wt,
                                                   const float* __restrict__ bias,
                                                   float* __restrict__ C,
                                                   bf16* __restrict__ Cb,
                                                   int M, int N, int K) {
    __shared__ bf16 As[128 * 32];
    __shared__ bf16 Bs[128 * 32];
    int tid = threadIdx.x;
    int lane = tid & 63, w = tid >> 6;
    int wr = w >> 1, wc = w & 1;
    int by = blockIdx.y * 128;
    int bx = blockIdx.x * 128;

    f32x4 zz = {0.0f, 0.0f, 0.0f, 0.0f};
    f32x4 acc[4][4];
#pragma unroll
    for (int m = 0; m < 4; ++m)
#pragma unroll
        for (int n = 0; n < 4; ++n) acc[m][n] = zz;

    int koff = (lane >> 4) * 8;
    int rsub = lane & 15;

    for (int k0 = 0; k0 < K; k0 += 32) {
#pragma unroll
        for (int i = 0; i < 2; ++i) {
            int c = tid + i * 256;
            int row = c >> 2;
            int kb = (c & 3) * 8;
            gload_lds16(A + (size_t)(by + row) * K + k0 + kb, &As[c * 8]);
            gload_lds16(Wt + (size_t)(bx + row) * K + k0 + kb, &Bs[c * 8]);
        }
        __syncthreads();
        bf16x8 af[4], bfv[4];
#pragma unroll
        for (int m = 0; m < 4; ++m)
            af[m] = *(const bf16x8*)&As[(wr * 64 + m * 16 + rsub) * 32 + koff];
#pragma unroll
        for (int n = 0; n < 4; ++n)
            bfv[n] = *(const bf16x8*)&Bs[(wc * 64 + n * 16 + rsub) * 32 + koff];
#pragma unroll
        for (int m = 0; m < 4; ++m)
#pragma unroll
            for (int n = 0; n < 4; ++n)
                acc[m][n] = __builtin_amdgcn_mfma_f32_16x16x32_bf16(af[m], bfv[n], acc[m][n], 0, 0, 0);
        __syncthreads();
    }

    int cq = (lane >> 4) * 4;
    int cr = lane & 15;
#pragma unroll
    for (int m = 0; m < 4; ++m) {
        int row0 = by + wr * 64 + m * 16 + cq;
#pragma unroll
        for (int n = 0; n < 4; ++n) {
            int col = bx + wc * 64 + n * 16 + cr;
            float bv = bias[col];
#pragma unroll
            for (int j = 0; j < 4; ++j) {
                float v = acc[m][n][j] + bv;
                if constexpr (OUTB)
                    Cb[(size_t)(row0 + j) * N + col] = __float2bfloat16(v);
                else
                    C[(size_t)(row0 + j) * N + col] = v;
            }
        }
    }
}

// -------- PSF softmax (coalesced via psfT) + K8192 + radix-4 seq-FFT ---------
__global__ __launch_bounds__(256) void k_build_khat(const float* __restrict__ psfT,
                                                    float2* __restrict__ Khat,
                                                    const float2* __restrict__ tw) {
    __shared__ float re[NFFT];
    __shared__ float im[NFFT];
    __shared__ float red[256];
    int u = blockIdx.x, h = blockIdx.y, tid = threadIdx.x;
    const float* col = psfT + ((size_t)(h * D_ + u)) * L_;

    float v[8];
    float4 a0 = *(const float4*)(col + tid * 8);
    float4 a1 = *(const float4*)(col + tid * 8 + 4);
    v[0] = a0.x; v[1] = a0.y; v[2] = a0.z; v[3] = a0.w;
    v[4] = a1.x; v[5] = a1.y; v[6] = a1.z; v[7] = a1.w;

    float lm = v[0];
#pragma unroll
    for (int j = 1; j < 8; ++j) lm = fmaxf(lm, v[j]);
    red[tid] = lm; __syncthreads();
    for (int off = 128; off > 0; off >>= 1) {
        if (tid < off) red[tid] = fmaxf(red[tid], red[tid + off]);
        __syncthreads();
    }
    float M = fmaxf(red[0], 0.0f);
    __syncthreads();

    float e[8];
    float ls = 0.0f;
#pragma unroll
    for (int j = 0; j < 8; ++j) { e[j] = expf(v[j] - M); ls += e[j]; }
    red[tid] = ls; __syncthreads();
    for (int off = 128; off > 0; off >>= 1) {
        if (tid < off) red[tid] += red[tid + off];
        __syncthreads();
    }
    float Z = red[0] + (float)(L_ - 1) * expf(-M);
    __syncthreads();

    float invZ = 1.0f / Z;
    float cval = expf(-M) * invZ;
#pragma unroll
    for (int j = 0; j < 8; ++j) {
        int i = tid * 8 + j;
        re[SWZ(i)] = e[j] * invZ;
    }
    for (int i = L_ + tid; i < NFFT; i += 256)
        re[SWZ(i)] = (i >= NFFT - (L_ - 1)) ? cval : 0.0f;
    for (int i = tid; i < NFFT; i += 256) im[i] = 0.0f;

    fft8k_r4_dif(re, im, tid, tw);

    float sc = 1.0f / (float)NFFT;
    float2* outp = Khat + ((size_t)h * D_ + u) * NFFT;
    for (int i = tid; i < NFFT; i += 256)
        outp[i] = make_float2(re[SWZ(i)] * sc, im[SWZ(i)] * sc);
}

// ---------------- in-place radix-4 FFT64 over u of Khat (+1/64 scale) --------
__global__ __launch_bounds__(256) void k_khat_dfft(float2* __restrict__ Khat,
                                                   const float2* __restrict__ tw) {
    __shared__ float Xre[4096];
    __shared__ float Xim[4096];
    int f0 = blockIdx.x * 64, h = blockIdx.y, tid = threadIdx.x;
    float2* kb = Khat + (size_t)h * D_ * NFFT;
    for (int i = tid; i < 4096; i += 256) {
        int uu = i >> 6, fc = i & 63;
        float2 v = kb[(size_t)uu * NFFT + f0 + fc];
        Xre[i] = v.x; Xim[i] = v.y;
    }
    fft64_b(Xre, Xim, tid, tw, 0);
    float sc = 1.0f / 64.0f;
    for (int i = tid; i < 4096; i += 256) {
        int uu = i >> 6, fc = i & 63;
        kb[(size_t)uu * NFFT + f0 + fc] = make_float2(Xre[i] * sc, Xim[i] * sc);
    }
}

// -------- packed fwd FFT from preT (contiguous bf16): z = b0 + i*b1 ----------
__global__ __launch_bounds__(256) void k_fft_fwd(const bf16* __restrict__ p0T,
                                                 const bf16* __restrict__ p1T,
                                                 float2* __restrict__ Xbuf,
                                                 const float2* __restrict__ tw) {
    __shared__ float re[NFFT];
    __shared__ float im[NFFT];
    int v = blockIdx.x, h = blockIdx.y, tid = threadIdx.x;
    size_t cb = ((size_t)(h * D_ + v)) * L_;
    bf16x8 va = *(const bf16x8*)(p0T + cb + tid * 8);
    bf16x8 vb = *(const bf16x8*)(p1T + cb + tid * 8);
#pragma unroll
    for (int j = 0; j < 8; ++j) {
        int i = tid * 8 + j;
        re[SWZ(i)] = bfu2f((unsigned short)va[j]);
        im[SWZ(i)] = bfu2f((unsigned short)vb[j]);
    }
    for (int i = L_ + tid; i < NFFT; i += 256) {
        re[SWZ(i)] = 0.0f; im[SWZ(i)] = 0.0f;
    }
    fft8k_r4_dif(re, im, tid, tw);
    float2* outp = Xbuf + ((size_t)h * D_ + v) * NFFT;
    for (int i = tid; i < NFFT; i += 256)
        outp[i] = make_float2(re[SWZ(i)], im[SWZ(i)]);
}

// ------- d-axis: radix-4 FFT64 over v, cmul with Khat2, inverse (in place) ---
__global__ __launch_bounds__(256) void k_dconv(float2* __restrict__ Xbuf,
                                               const float2* __restrict__ Khat,
                                               const float2* __restrict__ tw) {
    __shared__ float Xre[4096];
    __shared__ float Xim[4096];
    __shared__ float Kre[4096];
    __shared__ float Kim[4096];
    int f0 = blockIdx.x * 64, h = blockIdx.y, tid = threadIdx.x;
    float2* xb = Xbuf + (size_t)h * D_ * NFFT;
    const float2* kb = Khat + (size_t)h * D_ * NFFT;
    for (int i = tid; i < 4096; i += 256) {
        int vv = i >> 6, fc = i & 63;
        float2 x = xb[(size_t)vv * NFFT + f0 + fc];
        float2 k = kb[(size_t)vv * NFFT + f0 + fc];
        Xre[i] = x.x; Xim[i] = x.y; Kre[i] = k.x; Kim[i] = k.y;
    }
    fft64_b(Xre, Xim, tid, tw, 0);
    for (int i = tid; i < 4096; i += 256) {
        float xr = Xre[i], xi = Xim[i], kr = Kre[i], ki = Kim[i];
        Xre[i] = xr * kr - xi * ki;
        Xim[i] = xr * ki + xi * kr;
    }
    fft64_b(Xre, Xim, tid, tw, 1);
    for (int i = tid; i < 4096; i += 256) {
        int vv = i >> 6, fc = i & 63;
        xb[(size_t)vv * NFFT + f0 + fc] = make_float2(Xre[i], Xim[i]);
    }
}

// ------- packed inverse FFT + GELU -> convT (contiguous bf16 per column) -----
__global__ __launch_bounds__(256) void k_fft_inv(const float2* __restrict__ Xbuf,
                                                 bf16* __restrict__ o0T,
                                                 bf16* __restrict__ o1T,
                                                 const float2* __restrict__ tw) {
    __shared__ float re[NFFT];
    __shared__ float im[NFFT];
    int m = blockIdx.x, h = blockIdx.y, tid = threadIdx.x;
    const float2* in = Xbuf + ((size_t)h * D_ + m) * NFFT;
    for (int i = tid; i < NFFT; i += 256) {
        float2 v = in[i];
        re[SWZ(i)] = v.x; im[SWZ(i)] = v.y;
    }
    fft8k_r4_inv(re, im, tid, tw);
    size_t cb = ((size_t)(h * D_ + m)) * L_;
    unsigned short g0[8], g1[8];
#pragma unroll
    for (int j = 0; j < 8; ++j) {
        int n = tid * 8 + j;
        float x0 = re[SWZ(n)], x1 = im[SWZ(n)];
        float a0 = 0.5f * x0 * (1.0f + erff(x0 * 0.70710678118654752f));
        float a1 = 0.5f * x1 * (1.0f + erff(x1 * 0.70710678118654752f));
        bf16 b0 = __float2bfloat16(a0), b1 = __float2bfloat16(a1);
        g0[j] = *(unsigned short*)&b0; g1[j] = *(unsigned short*)&b1;
    }
    *(ushort4*)(o0T + cb + tid * 8)     = make_ushort4(g0[0], g0[1], g0[2], g0[3]);
    *(ushort4*)(o0T + cb + tid * 8 + 4) = make_ushort4(g0[4], g0[5], g0[6], g0[7]);
    *(ushort4*)(o1T + cb + tid * 8)     = make_ushort4(g1[0], g1[1], g1[2], g1[3]);
    *(ushort4*)(o1T + cb + tid * 8 + 4) = make_ushort4(g1[4], g1[5], g1[6], g1[7]);
}

// ---------------- sparse seq-mix: build per-row (col,val) lists --------------
__global__ __launch_bounds__(256) void k_sparse_build(const float* __restrict__ Sp,
                                                      int* __restrict__ nnz,
                                                      int* __restrict__ idxs,
                                                      float* __restrict__ vals) {
    __shared__ int cnt;
    int l = blockIdx.x, tid = threadIdx.x;
    if (tid == 0) cnt = 0;
    __syncthreads();
    const float* row = Sp + (size_t)l * L_;
    for (int s = tid; s <= l; s += 256) {
        float v = row[s];
        if (v != 0.0f) {
            int slot = atomicAdd(&cnt, 1);
            if (slot < CAP) { idxs[l * CAP + slot] = s; vals[l * CAP + slot] = v; }
        }
    }
    __syncthreads();
    if (tid == 0) nnz[l] = min(cnt, CAP);
}

// ---------------- gather-SpMM accumulate -------------------------------------
__global__ __launch_bounds__(256) void k_spmm_acc(const int* __restrict__ nnz,
                                                  const int* __restrict__ idxs,
                                                  const float* __restrict__ vals,
                                                  const float* __restrict__ P,
                                                  float* __restrict__ C) {
    __shared__ int sidx[CAP];
    __shared__ float sval[CAP];
    int l = blockIdx.x, b = blockIdx.y, tid = threadIdx.x;
    int n = nnz[l];
    for (int j = tid; j < n; j += 256) {
        sidx[j] = idxs[l * CAP + j];
        sval[j] = vals[l * CAP + j];
    }
    __syncthreads();
    const float* Pb = P + (size_t)b * L_ * E_;
    size_t off = (size_t)tid * 4;
    float* cp = C + ((size_t)(b * L_ + l)) * E_ + off;
    float4 acc = *(float4*)cp;
    for (int j = 0; j < n; ++j) {
        float v = sval[j];
        float4 p = *(const float4*)(Pb + (size_t)sidx[j] * E_ + off);
        acc.x += v * p.x; acc.y += v * p.y; acc.z += v * p.z; acc.w += v * p.w;
    }
    *(float4*)cp = acc;
}

// ---------------- residual + LayerNorm ---------------------------------------
__global__ __launch_bounds__(256) void k_layernorm(const float* __restrict__ accb,
                                                   const float* __restrict__ emb,
                                                   const float* __restrict__ gamma,
                                                   const float* __restrict__ beta,
                                                   float* __restrict__ outp) {
    __shared__ float xs[E_];
    __shared__ float red[256];
    size_t row = blockIdx.x;
    int tid = threadIdx.x;
    const float* a = accb + row * E_;
    const float* e = emb + row * E_;
    float lsum = 0.0f;
    for (int i = tid; i < E_; i += 256) {
        float x = a[i] + e[i];
        xs[i] = x;
        lsum += x;
    }
    red[tid] = lsum; __syncthreads();
    for (int off = 128; off > 0; off >>= 1) {
        if (tid < off) red[tid] += red[tid + off];
        __syncthreads();
    }
    float mu = red[0] * (1.0f / E_);
    __syncthreads();
    float lv = 0.0f;
    for (int i = tid; i < E_; i += 256) { float d = xs[i] - mu; lv += d * d; }
    red[tid] = lv; __syncthreads();
    for (int off = 128; off > 0; off >>= 1) {
        if (tid < off) red[tid] += red[tid + off];
        __syncthreads();
    }
    float inv = rsqrtf(red[0] * (1.0f / E_) + 1e-12f);
    for (int i = tid; i < E_; i += 256)
        outp[row * E_ + i] = (xs[i] - mu) * inv * gamma[i] + beta[i];
}

extern "C" void kernel_launch(void* const* d_in, const int* in_sizes, int n_in,
                              void* d_out, int out_size, void* d_ws, size_t ws_size,
                              hipStream_t stream) {
    const float* emb    = (const float*)d_in[0];
    const float* W1     = (const float*)d_in[1];
    const float* b1     = (const float*)d_in[2];
    const float* W2     = (const float*)d_in[3];
    const float* b2     = (const float*)d_in[4];
    const float* psfs   = (const float*)d_in[5];
    const float* W3     = (const float*)d_in[6];
    const float* b3     = (const float*)d_in[7];
    const float* sparse = (const float*)d_in[8];
    const float* gamma  = (const float*)d_in[9];
    const float* beta   = (const float*)d_in[10];
    float* outp = (float*)d_out;

    const size_t BLE = (size_t)B_ * L_ * E_;
    const size_t LE  = (size_t)L_ * E_;
    const size_t EE  = (size_t)E_ * E_;

    float*  pre_sparse = (float*)d_ws;                           // 33.5 MB
    float*  accb       = pre_sparse + BLE;                       // 33.5 MB
    float2* Khat       = (float2*)(accb + BLE);                  // 67.1 MB
    float2* Xbuf       = Khat + (size_t)H_ * D_ * NFFT;          // 67.1 MB
    bf16*   preb       = (bf16*)(Xbuf + (size_t)H_ * D_ * NFFT); // 16.8 MB
    bf16*   actb       = preb + BLE;                             // 16.8 MB
    bf16*   W1b        = actb + BLE;
    bf16*   W2b        = W1b + EE;
    bf16*   W3b        = W2b + EE;
    float2* twd        = (float2*)(W3b + EE);                    // 64 KB
    // time-multiplexed overlays:
    bf16*   preT       = (bf16*)accb;        // [B][E][L] bf16, dead before GEMM3
    bf16*   convT      = preT + BLE;         // [B][E][L] bf16, dead before GEMM3
    float*  psfT       = (float*)Xbuf;       // [H][D][L] fp32, dead before fft loop
    int*    s_nnz      = (int*)Xbuf;         // sparse lists, used after fft loop
    int*    s_idx      = s_nnz + L_;
    float*  s_val      = (float*)(s_idx + (size_t)L_ * CAP);

    // twiddle table + bf16 conversions
    k_twiddle<<<32, 256, 0, stream>>>(twd);
    k_cvt<<<(int)(BLE / 4 / 256), 256, 0, stream>>>(emb, actb, (int)BLE);
    k_cvt<<<(int)(EE / 4 / 256), 256, 0, stream>>>(W1, W1b, (int)EE);
    k_cvt<<<(int)(EE / 4 / 256), 256, 0, stream>>>(W2, W2b, (int)EE);
    k_cvt<<<(int)(EE / 4 / 256), 256, 0, stream>>>(W3, W3b, (int)EE);

    // preb = bf16(emb @ W1^T + b1) ; pre_sparse = preb @ W2^T + b2 (fp32)
    k_gemm_mfma<1><<<dim3(E_ / 128, (B_ * L_) / 128), 256, 0, stream>>>(
        actb, W1b, b1, nullptr, preb, B_ * L_, E_, E_);
    k_gemm_mfma<0><<<dim3(E_ / 128, (B_ * L_) / 128), 256, 0, stream>>>(
        preb, W2b, b2, pre_sparse, nullptr, B_ * L_, E_, E_);

    // psfT[h][u][t<2048] = psfs[h][t][u]  (coalesced softmax input)
    k_tf32<<<dim3(1, L_ / 64, H_), 256, 0, stream>>>(
        psfs, psfT, L_, D_, (long)(2 * L_ - 1) * D_, (long)D_ * L_);

    // PSF softmax + radix-4 seq-FFT, then in-place d-FFT of the kernel spectrum
    k_build_khat<<<dim3(D_, H_), 256, 0, stream>>>(psfT, Khat, twd);
    k_khat_dfft<<<dim3(NFFT / 64, H_), 256, 0, stream>>>(Khat, twd);

    // preT[b][e][l] = preb[b][l][e]  (contiguous FFT input)
    k_tbf16<<<dim3(E_ / 64, L_ / 64, B_), 256, 0, stream>>>(
        preb, preT, L_, E_, (long)LE, (long)LE);

    // packed 2-batch FFT conv passes: (b0,b1) and (b2,b3)
    for (int p = 0; p < B_; p += 2) {
        k_fft_fwd<<<dim3(D_, H_), 256, 0, stream>>>(
            preT + (size_t)p * LE, preT + (size_t)(p + 1) * LE, Xbuf, twd);
        k_dconv<<<dim3(NFFT / 64, H_), 256, 0, stream>>>(Xbuf, Khat, twd);
        k_fft_inv<<<dim3(D_, H_), 256, 0, stream>>>(
            Xbuf, convT + (size_t)p * LE, convT + (size_t)(p + 1) * LE, twd);
    }

    // actb[b][l][e] = convT[b][e][l]
    k_tbf16<<<dim3(L_ / 64, E_ / 64, B_), 256, 0, stream>>>(
        convT, actb, E_, L_, (long)LE, (long)LE);

    // accb = convb @ W3^T + b3 (fp32)
    k_gemm_mfma<0><<<dim3(E_ / 128, (B_ * L_) / 128), 256, 0, stream>>>(
        actb, W3b, b3, accb, nullptr, B_ * L_, E_, E_);

    // accb += tril(sparse) @ pre_sparse
    k_sparse_build<<<L_, 256, 0, stream>>>(sparse, s_nnz, s_idx, s_val);
    k_spmm_acc<<<dim3(L_, B_), 256, 0, stream>>>(s_nnz, s_idx, s_val, pre_sparse, accb);

    // out = LayerNorm(accb + emb) * gamma + beta
    k_layernorm<<<B_ * L_, 256, 0, stream>>>(accb, emb, gamma, beta, outp);
}

// Round 6
// 456.069 us; speedup vs baseline: 6.8820x; 1.4340x over previous
//
#include <hip/hip_runtime.h>
#include <hip/hip_bf16.h>
#include <math.h>

#define B_ 4
#define L_ 2048
#define E_ 1024
#define H_ 16
#define D_ 64
#define NFFT 4096
#define CAP 128

typedef __hip_bfloat16 bf16;
typedef __attribute__((ext_vector_type(8))) short bf16x8;
typedef __attribute__((ext_vector_type(4))) float f32x4;

typedef __attribute__((address_space(1))) const unsigned int gas_u32;
typedef __attribute__((address_space(3))) unsigned int las_u32;

__device__ __forceinline__ void gload_lds16(const void* g, void* l) {
    __builtin_amdgcn_global_load_lds((gas_u32*)g, (las_u32*)l, 16, 0, 0);
}

// LDS bank swizzle (bijective; only low bits 2..4 flipped from bits 5..7)
#define SWZ(i) ((i) ^ (((i) >> 3) & 28))

__device__ __forceinline__ float bfu2f(unsigned short u) {
    return __uint_as_float(((unsigned)u) << 16);
}

// ---------------- twiddle table: tw[k] = exp(-2*pi*i*k/4096), k < 4096 -------
__global__ __launch_bounds__(256) void k_twiddle(float2* __restrict__ tw) {
    int k = blockIdx.x * 256 + threadIdx.x;
    if (k < NFFT) {
        float ang = -(float)k * (float)(M_PI / 2048.0);
        tw[k] = make_float2(cosf(ang), sinf(ang));
    }
}

// ------------- 4096-pt radix-4 DIF forward (natural in -> digit-rev out) -----
__device__ inline void fft4k_r4_dif(float* re, float* im, int tid,
                                    const float2* __restrict__ tw) {
    for (int st = 0; st < 6; ++st) {
        int q = 1 << (10 - 2 * st);
        __syncthreads();
        for (int it = 0; it < 4; ++it) {
            int b = tid + (it << 8);
            int p = b & (q - 1);
            int base = ((b & ~(q - 1)) << 2) | p;
            int i0 = SWZ(base), i1 = SWZ(base + q), i2 = SWZ(base + 2 * q), i3 = SWZ(base + 3 * q);
            float x0r = re[i0], x0i = im[i0], x1r = re[i1], x1i = im[i1];
            float x2r = re[i2], x2i = im[i2], x3r = re[i3], x3i = im[i3];
            float a0r = x0r + x2r, a0i = x0i + x2i;
            float a1r = x0r - x2r, a1i = x0i - x2i;
            float a2r = x1r + x3r, a2i = x1i + x3i;
            float a3r = x1r - x3r, a3i = x1i - x3i;
            float y0r = a0r + a2r, y0i = a0i + a2i;
            float y2r = a0r - a2r, y2i = a0i - a2i;
            float y1r = a1r + a3i, y1i = a1i - a3r;
            float y3r = a1r - a3i, y3i = a1i + a3r;
            int e = p << (2 * st);
            float2 w1 = tw[e], w2 = tw[2 * e], w3 = tw[3 * e];
            re[i0] = y0r; im[i0] = y0i;
            re[i1] = y1r * w1.x - y1i * w1.y; im[i1] = y1r * w1.y + y1i * w1.x;
            re[i2] = y2r * w2.x - y2i * w2.y; im[i2] = y2r * w2.y + y2i * w2.x;
            re[i3] = y3r * w3.x - y3i * w3.y; im[i3] = y3r * w3.y + y3i * w3.x;
        }
    }
    __syncthreads();
}

// ------------- 4096-pt radix-4 DIT inverse (digit-rev in -> natural out) -----
__device__ inline void fft4k_r4_inv(float* re, float* im, int tid,
                                    const float2* __restrict__ tw) {
    for (int st = 5; st >= 0; --st) {
        int q = 1 << (10 - 2 * st);
        __syncthreads();
        for (int it = 0; it < 4; ++it) {
            int b = tid + (it << 8);
            int p = b & (q - 1);
            int base = ((b & ~(q - 1)) << 2) | p;
            int i0 = SWZ(base), i1 = SWZ(base + q), i2 = SWZ(base + 2 * q), i3 = SWZ(base + 3 * q);
            int e = p << (2 * st);
            float2 w1 = tw[e], w2 = tw[2 * e], w3 = tw[3 * e];
            float z0r = re[i0], z0i = im[i0];
            float t1r = re[i1], t1i = im[i1];
            float t2r = re[i2], t2i = im[i2];
            float t3r = re[i3], t3i = im[i3];
            float z1r = t1r * w1.x + t1i * w1.y, z1i = t1i * w1.x - t1r * w1.y;
            float z2r = t2r * w2.x + t2i * w2.y, z2i = t2i * w2.x - t2r * w2.y;
            float z3r = t3r * w3.x + t3i * w3.y, z3i = t3i * w3.x - t3r * w3.y;
            float b0r = z0r + z2r, b0i = z0i + z2i;
            float b1r = z0r - z2r, b1i = z0i - z2i;
            float b2r = z1r + z3r, b2i = z1i + z3i;
            float b3r = z1r - z3r, b3i = z1i - z3i;
            re[i0] = b0r + b2r; im[i0] = b0i + b2i;
            re[i2] = b0r - b2r; im[i2] = b0i - b2i;
            re[i1] = b1r - b3i; im[i1] = b1i + b3r;
            re[i3] = b1r + b3i; im[i3] = b1i - b3r;
        }
    }
    __syncthreads();
}

// ------- batched 64-pt radix-4 FFT over v in [v][fc] LDS layout (4096 el) ----
__device__ inline void fft64_b(float* xr, float* xi, int tid,
                               const float2* __restrict__ tw, int inv) {
    if (!inv) {
        for (int st = 0; st < 3; ++st) {
            int q = 1 << (4 - 2 * st);
            __syncthreads();
            for (int it = 0; it < 4; ++it) {
                int b = tid + (it << 8);
                int fc = b & 63;
                int bc = b >> 6;
                int p = bc & (q - 1);
                int basev = ((bc & ~(q - 1)) << 2) | p;
                int i0 = basev * 64 + fc, i1 = i0 + q * 64, i2 = i1 + q * 64, i3 = i2 + q * 64;
                float x0r = xr[i0], x0i = xi[i0], x1r = xr[i1], x1i = xi[i1];
                float x2r = xr[i2], x2i = xi[i2], x3r = xr[i3], x3i = xi[i3];
                float a0r = x0r + x2r, a0i = x0i + x2i;
                float a1r = x0r - x2r, a1i = x0i - x2i;
                float a2r = x1r + x3r, a2i = x1i + x3i;
                float a3r = x1r - x3r, a3i = x1i - x3i;
                float y0r = a0r + a2r, y0i = a0i + a2i;
                float y2r = a0r - a2r, y2i = a0i - a2i;
                float y1r = a1r + a3i, y1i = a1i - a3r;
                float y3r = a1r - a3i, y3i = a1i + a3r;
                int e = (p << (2 * st)) * 64;
                float2 w1 = tw[e], w2 = tw[2 * e], w3 = tw[3 * e];
                xr[i0] = y0r; xi[i0] = y0i;
                xr[i1] = y1r * w1.x - y1i * w1.y; xi[i1] = y1r * w1.y + y1i * w1.x;
                xr[i2] = y2r * w2.x - y2i * w2.y; xi[i2] = y2r * w2.y + y2i * w2.x;
                xr[i3] = y3r * w3.x - y3i * w3.y; xi[i3] = y3r * w3.y + y3i * w3.x;
            }
        }
    } else {
        for (int st = 2; st >= 0; --st) {
            int q = 1 << (4 - 2 * st);
            __syncthreads();
            for (int it = 0; it < 4; ++it) {
                int b = tid + (it << 8);
                int fc = b & 63;
                int bc = b >> 6;
                int p = bc & (q - 1);
                int basev = ((bc & ~(q - 1)) << 2) | p;
                int i0 = basev * 64 + fc, i1 = i0 + q * 64, i2 = i1 + q * 64, i3 = i2 + q * 64;
                int e = (p << (2 * st)) * 64;
                float2 w1 = tw[e], w2 = tw[2 * e], w3 = tw[3 * e];
                float z0r = xr[i0], z0i = xi[i0];
                float t1r = xr[i1], t1i = xi[i1];
                float t2r = xr[i2], t2i = xi[i2];
                float t3r = xr[i3], t3i = xi[i3];
                float z1r = t1r * w1.x + t1i * w1.y, z1i = t1i * w1.x - t1r * w1.y;
                float z2r = t2r * w2.x + t2i * w2.y, z2i = t2i * w2.x - t2r * w2.y;
                float z3r = t3r * w3.x + t3i * w3.y, z3i = t3i * w3.x - t3r * w3.y;
                float b0r = z0r + z2r, b0i = z0i + z2i;
                float b1r = z0r - z2r, b1i = z0i - z2i;
                float b2r = z1r + z3r, b2i = z1i + z3i;
                float b3r = z1r - z3r, b3i = z1i - z3i;
                xr[i0] = b0r + b2r; xi[i0] = b0i + b2i;
                xr[i2] = b0r - b2r; xi[i2] = b0i - b2i;
                xr[i1] = b1r - b3i; xi[i1] = b1i + b3r;
                xr[i3] = b1r + b3i; xi[i3] = b1i - b3r;
            }
        }
    }
    __syncthreads();
}

// ---------------- fp32 -> bf16 convert (vectorized) --------------------------
__global__ __launch_bounds__(256) void k_cvt(const float* __restrict__ in,
                                             bf16* __restrict__ out, int n) {
    int i = (blockIdx.x * 256 + threadIdx.x) * 4;
    if (i >= n) return;
    float4 v = *(const float4*)(in + i);
    bf16 tmp[4];
    tmp[0] = __float2bfloat16(v.x);
    tmp[1] = __float2bfloat16(v.y);
    tmp[2] = __float2bfloat16(v.z);
    tmp[3] = __float2bfloat16(v.w);
    *(ushort4*)(out + i) = *(ushort4*)tmp;
}

// ---------------- fp32 transpose: out[c*R+r] = in[r*C+c], 64x64 tiles --------
__global__ __launch_bounds__(256) void k_tf32(const float* __restrict__ in,
                                              float* __restrict__ out,
                                              int R, int C, long inB, long outB) {
    __shared__ float tile[64][65];
    in += (size_t)blockIdx.z * inB;
    out += (size_t)blockIdx.z * outB;
    int r0 = blockIdx.y * 64, c0 = blockIdx.x * 64;
    int t = threadIdx.x;
    int tx4 = (t & 15) * 4, ty = t >> 4;
#pragma unroll
    for (int k = 0; k < 4; ++k) {
        int r = ty + 16 * k;
        float4 v = *(const float4*)&in[(size_t)(r0 + r) * C + c0 + tx4];
        tile[r][tx4 + 0] = v.x; tile[r][tx4 + 1] = v.y;
        tile[r][tx4 + 2] = v.z; tile[r][tx4 + 3] = v.w;
    }
    __syncthreads();
#pragma unroll
    for (int k = 0; k < 4; ++k) {
        int c = ty + 16 * k;
        float4 w;
        w.x = tile[tx4 + 0][c]; w.y = tile[tx4 + 1][c];
        w.z = tile[tx4 + 2][c]; w.w = tile[tx4 + 3][c];
        *(float4*)&out[(size_t)(c0 + c) * R + r0 + tx4] = w;
    }
}

// ---------------- bf16 transpose: out[c*R+r] = in[r*C+c], 64x64 tiles --------
__global__ __launch_bounds__(256) void k_tbf16(const bf16* __restrict__ in,
                                               bf16* __restrict__ out,
                                               int R, int C, long inB, long outB) {
    __shared__ unsigned short tile[64][65];
    in += (size_t)blockIdx.z * inB;
    out += (size_t)blockIdx.z * outB;
    int r0 = blockIdx.y * 64, c0 = blockIdx.x * 64;
    int t = threadIdx.x;
    int tx4 = (t & 15) * 4, ty = t >> 4;
#pragma unroll
    for (int k = 0; k < 4; ++k) {
        int r = ty + 16 * k;
        ushort4 v = *(const ushort4*)&in[(size_t)(r0 + r) * C + c0 + tx4];
        tile[r][tx4 + 0] = v.x; tile[r][tx4 + 1] = v.y;
        tile[r][tx4 + 2] = v.z; tile[r][tx4 + 3] = v.w;
    }
    __syncthreads();
#pragma unroll
    for (int k = 0; k < 4; ++k) {
        int c = ty + 16 * k;
        ushort4 w;
        w.x = tile[tx4 + 0][c]; w.y = tile[tx4 + 1][c];
        w.z = tile[tx4 + 2][c]; w.w = tile[tx4 + 3][c];
        *(ushort4*)&out[(size_t)(c0 + c) * R + r0 + tx4] = w;
    }
}

// ---------------- bf16 MFMA GEMM (m97 structure): C = A @ Wt^T + bias --------
template <int OUTB>
__global__ __launch_bounds__(256) void k_gemm_mfma(const bf16* __restrict__ A,
                                                   const bf16* __restrict__ Wt,
                                                   const float* __restrict__ bias,
                                                   float* __restrict__ C,
                                                   bf16* __restrict__ Cb,
                                                   int M, int N, int K) {
    __shared__ bf16 As[128 * 32];
    __shared__ bf16 Bs[128 * 32];
    int tid = threadIdx.x;
    int lane = tid & 63, w = tid >> 6;
    int wr = w >> 1, wc = w & 1;
    int by = blockIdx.y * 128;
    int bx = blockIdx.x * 128;

    f32x4 zz = {0.0f, 0.0f, 0.0f, 0.0f};
    f32x4 acc[4][4];
#pragma unroll
    for (int m = 0; m < 4; ++m)
#pragma unroll
        for (int n = 0; n < 4; ++n) acc[m][n] = zz;

    int koff = (lane >> 4) * 8;
    int rsub = lane & 15;

    for (int k0 = 0; k0 < K; k0 += 32) {
#pragma unroll
        for (int i = 0; i < 2; ++i) {
            int c = tid + i * 256;
            int row = c >> 2;
            int kb = (c & 3) * 8;
            gload_lds16(A + (size_t)(by + row) * K + k0 + kb, &As[c * 8]);
            gload_lds16(Wt + (size_t)(bx + row) * K + k0 + kb, &Bs[c * 8]);
        }
        __syncthreads();
        bf16x8 af[4], bfv[4];
#pragma unroll
        for (int m = 0; m < 4; ++m)
            af[m] = *(const bf16x8*)&As[(wr * 64 + m * 16 + rsub) * 32 + koff];
#pragma unroll
        for (int n = 0; n < 4; ++n)
            bfv[n] = *(const bf16x8*)&Bs[(wc * 64 + n * 16 + rsub) * 32 + koff];
#pragma unroll
        for (int m = 0; m < 4; ++m)
#pragma unroll
            for (int n = 0; n < 4; ++n)
                acc[m][n] = __builtin_amdgcn_mfma_f32_16x16x32_bf16(af[m], bfv[n], acc[m][n], 0, 0, 0);
        __syncthreads();
    }

    int cq = (lane >> 4) * 4;
    int cr = lane & 15;
#pragma unroll
    for (int m = 0; m < 4; ++m) {
        int row0 = by + wr * 64 + m * 16 + cq;
#pragma unroll
        for (int n = 0; n < 4; ++n) {
            int col = bx + wc * 64 + n * 16 + cr;
            float bv = bias[col];
#pragma unroll
            for (int j = 0; j < 4; ++j) {
                float v = acc[m][n][j] + bv;
                if constexpr (OUTB)
                    Cb[(size_t)(row0 + j) * N + col] = __float2bfloat16(v);
                else
                    C[(size_t)(row0 + j) * N + col] = v;
            }
        }
    }
}

// -------- PSF softmax + causal K4096 + radix-4 seq-FFT + Ccv circulant -------
// Anticausal taps are all cval=exp(-M)/Z -> handled by suffix-sum path, so the
// FFT kernel holds only the 2048 causal weights (zero-padded to 4096).
__global__ __launch_bounds__(256) void k_build_khat(const float* __restrict__ psfT,
                                                    float2* __restrict__ Khat,
                                                    float* __restrict__ Ccv,
                                                    const float2* __restrict__ tw) {
    __shared__ float re[NFFT];
    __shared__ float im[NFFT];
    __shared__ float red[256];
    int u = blockIdx.x, h = blockIdx.y, tid = threadIdx.x;
    const float* col = psfT + ((size_t)(h * D_ + u)) * L_;

    float v[8];
    float4 a0 = *(const float4*)(col + tid * 8);
    float4 a1 = *(const float4*)(col + tid * 8 + 4);
    v[0] = a0.x; v[1] = a0.y; v[2] = a0.z; v[3] = a0.w;
    v[4] = a1.x; v[5] = a1.y; v[6] = a1.z; v[7] = a1.w;

    float lm = v[0];
#pragma unroll
    for (int j = 1; j < 8; ++j) lm = fmaxf(lm, v[j]);
    red[tid] = lm; __syncthreads();
    for (int off = 128; off > 0; off >>= 1) {
        if (tid < off) red[tid] = fmaxf(red[tid], red[tid + off]);
        __syncthreads();
    }
    float M = fmaxf(red[0], 0.0f);
    __syncthreads();

    float e[8];
    float ls = 0.0f;
#pragma unroll
    for (int j = 0; j < 8; ++j) { e[j] = expf(v[j] - M); ls += e[j]; }
    red[tid] = ls; __syncthreads();
    for (int off = 128; off > 0; off >>= 1) {
        if (tid < off) red[tid] += red[tid + off];
        __syncthreads();
    }
    float Z = red[0] + (float)(L_ - 1) * expf(-M);
    __syncthreads();

    float invZ = 1.0f / Z;
    float cval = expf(-M) * invZ;
    // circulant for the anticausal rank-1 path: Ccv[h][j][(j+u)&63] = cval
    if (tid < 64)
        Ccv[((size_t)h * 64 + tid) * 64 + ((tid + u) & 63)] = cval;

#pragma unroll
    for (int j = 0; j < 8; ++j) {
        int i = tid * 8 + j;
        re[SWZ(i)] = e[j] * invZ;
    }
    for (int i = L_ + tid; i < NFFT; i += 256) re[SWZ(i)] = 0.0f;
    for (int i = tid; i < NFFT; i += 256) im[i] = 0.0f;

    fft4k_r4_dif(re, im, tid, tw);

    float sc = 1.0f / (float)NFFT;
    float2* outp = Khat + ((size_t)h * D_ + u) * NFFT;
    for (int i = tid; i < NFFT; i += 256)
        outp[i] = make_float2(re[SWZ(i)] * sc, im[SWZ(i)] * sc);
}

// ---------------- in-place radix-4 FFT64 over u of Khat (+1/64 scale) --------
__global__ __launch_bounds__(256) void k_khat_dfft(float2* __restrict__ Khat,
                                                   const float2* __restrict__ tw) {
    __shared__ float Xre[4096];
    __shared__ float Xim[4096];
    int f0 = blockIdx.x * 64, h = blockIdx.y, tid = threadIdx.x;
    float2* kb = Khat + (size_t)h * D_ * NFFT;
    for (int i = tid; i < 4096; i += 256) {
        int uu = i >> 6, fc = i & 63;
        float2 v = kb[(size_t)uu * NFFT + f0 + fc];
        Xre[i] = v.x; Xim[i] = v.y;
    }
    fft64_b(Xre, Xim, tid, tw, 0);
    float sc = 1.0f / 64.0f;
    for (int i = tid; i < 4096; i += 256) {
        int uu = i >> 6, fc = i & 63;
        kb[(size_t)uu * NFFT + f0 + fc] = make_float2(Xre[i] * sc, Xim[i] * sc);
    }
}

// ------- y = x (conv64) cval circulant: yT[b][h*64+m][l] per (b,h) -----------
__global__ __launch_bounds__(256) void k_ymat(const bf16* __restrict__ preT,
                                              const float* __restrict__ Ccv,
                                              bf16* __restrict__ yT) {
    __shared__ float Cs[64][64];
    __shared__ unsigned short Xs[64][128];
    int l0 = blockIdx.x * 128, h = blockIdx.y, b = blockIdx.z;
    int tid = threadIdx.x;
    const float* cc = Ccv + (size_t)h * 64 * 64;
    for (int i = tid; i < 4096; i += 256) ((float*)Cs)[i] = cc[i];
    const bf16* xp = preT + ((size_t)b * E_ + h * 64) * L_;
    for (int i = tid; i < 64 * 16; i += 256) {
        int j = i >> 4, c8 = (i & 15) * 8;
        *(bf16x8*)&Xs[j][c8] = *(const bf16x8*)(xp + (size_t)j * L_ + l0 + c8);
    }
    __syncthreads();
    int lt = (tid & 15) * 8, mt = (tid >> 4) * 4;
    float acc[4][8];
#pragma unroll
    for (int a = 0; a < 4; ++a)
#pragma unroll
        for (int k = 0; k < 8; ++k) acc[a][k] = 0.0f;
    for (int j = 0; j < 64; ++j) {
        float c0 = Cs[j][mt], c1 = Cs[j][mt + 1], c2 = Cs[j][mt + 2], c3 = Cs[j][mt + 3];
        bf16x8 xr = *(bf16x8*)&Xs[j][lt];
        float xv[8];
#pragma unroll
        for (int k = 0; k < 8; ++k) xv[k] = bfu2f((unsigned short)xr[k]);
#pragma unroll
        for (int k = 0; k < 8; ++k) {
            acc[0][k] += c0 * xv[k];
            acc[1][k] += c1 * xv[k];
            acc[2][k] += c2 * xv[k];
            acc[3][k] += c3 * xv[k];
        }
    }
    bf16* yp = yT + ((size_t)b * E_ + h * 64) * L_;
#pragma unroll
    for (int mm = 0; mm < 4; ++mm) {
        unsigned short o[8];
#pragma unroll
        for (int k = 0; k < 8; ++k) {
            bf16 t = __float2bfloat16(acc[mm][k]);
            o[k] = *(unsigned short*)&t;
        }
        *(ushort4*)(yp + (size_t)(mt + mm) * L_ + l0 + lt) = make_ushort4(o[0], o[1], o[2], o[3]);
        *(ushort4*)(yp + (size_t)(mt + mm) * L_ + l0 + lt + 4) = make_ushort4(o[4], o[5], o[6], o[7]);
    }
}

// -------- packed fwd FFT from preT (contiguous bf16): z = b0 + i*b1 ----------
__global__ __launch_bounds__(256) void k_fft_fwd(const bf16* __restrict__ p0T,
                                                 const bf16* __restrict__ p1T,
                                                 float2* __restrict__ Xbuf,
                                                 const float2* __restrict__ tw) {
    __shared__ float re[NFFT];
    __shared__ float im[NFFT];
    int v = blockIdx.x, h = blockIdx.y, tid = threadIdx.x;
    size_t cb = ((size_t)(h * D_ + v)) * L_;
    bf16x8 va = *(const bf16x8*)(p0T + cb + tid * 8);
    bf16x8 vb = *(const bf16x8*)(p1T + cb + tid * 8);
#pragma unroll
    for (int j = 0; j < 8; ++j) {
        int i = tid * 8 + j;
        re[SWZ(i)] = bfu2f((unsigned short)va[j]);
        im[SWZ(i)] = bfu2f((unsigned short)vb[j]);
    }
    for (int i = L_ + tid; i < NFFT; i += 256) {
        re[SWZ(i)] = 0.0f; im[SWZ(i)] = 0.0f;
    }
    fft4k_r4_dif(re, im, tid, tw);
    float2* outp = Xbuf + ((size_t)h * D_ + v) * NFFT;
    for (int i = tid; i < NFFT; i += 256)
        outp[i] = make_float2(re[SWZ(i)], im[SWZ(i)]);
}

// ------- d-axis: radix-4 FFT64 over v, cmul with Khat2, inverse (in place) ---
__global__ __launch_bounds__(256) void k_dconv(float2* __restrict__ Xbuf,
                                               const float2* __restrict__ Khat,
                                               const float2* __restrict__ tw) {
    __shared__ float Xre[4096];
    __shared__ float Xim[4096];
    __shared__ float Kre[4096];
    __shared__ float Kim[4096];
    int f0 = blockIdx.x * 64, h = blockIdx.y, tid = threadIdx.x;
    float2* xb = Xbuf + (size_t)h * D_ * NFFT;
    const float2* kb = Khat + (size_t)h * D_ * NFFT;
    for (int i = tid; i < 4096; i += 256) {
        int vv = i >> 6, fc = i & 63;
        float2 x = xb[(size_t)vv * NFFT + f0 + fc];
        float2 k = kb[(size_t)vv * NFFT + f0 + fc];
        Xre[i] = x.x; Xim[i] = x.y; Kre[i] = k.x; Kim[i] = k.y;
    }
    fft64_b(Xre, Xim, tid, tw, 0);
    for (int i = tid; i < 4096; i += 256) {
        float xr = Xre[i], xi = Xim[i], kr = Kre[i], ki = Kim[i];
        Xre[i] = xr * kr - xi * ki;
        Xim[i] = xr * ki + xi * kr;
    }
    fft64_b(Xre, Xim, tid, tw, 1);
    for (int i = tid; i < 4096; i += 256) {
        int vv = i >> 6, fc = i & 63;
        xb[(size_t)vv * NFFT + f0 + fc] = make_float2(Xre[i], Xim[i]);
    }
}

// --- packed inverse FFT + suffix-sum anticausal correction + GELU -> convT ---
__global__ __launch_bounds__(256) void k_fft_inv(const float2* __restrict__ Xbuf,
                                                 const bf16* __restrict__ y0T,
                                                 const bf16* __restrict__ y1T,
                                                 bf16* __restrict__ o0T,
                                                 bf16* __restrict__ o1T,
                                                 const float2* __restrict__ tw) {
    __shared__ float re[NFFT];
    __shared__ float im[NFFT];
    __shared__ float s0[256];
    __shared__ float s1[256];
    int m = blockIdx.x, h = blockIdx.y, tid = threadIdx.x;
    const float2* in = Xbuf + ((size_t)h * D_ + m) * NFFT;
    for (int i = tid; i < NFFT; i += 256) {
        float2 v = in[i];
        re[SWZ(i)] = v.x; im[SWZ(i)] = v.y;
    }
    fft4k_r4_inv(re, im, tid, tw);

    size_t cb = ((size_t)(h * D_ + m)) * L_;
    bf16x8 ya = *(const bf16x8*)(y0T + cb + tid * 8);
    bf16x8 yb = *(const bf16x8*)(y1T + cb + tid * 8);
    float y0v[8], y1v[8], t0 = 0.0f, t1 = 0.0f;
#pragma unroll
    for (int j = 0; j < 8; ++j) {
        y0v[j] = bfu2f((unsigned short)ya[j]); t0 += y0v[j];
        y1v[j] = bfu2f((unsigned short)yb[j]); t1 += y1v[j];
    }
    s0[tid] = t0; s1[tid] = t1; __syncthreads();
    for (int off = 1; off < 256; off <<= 1) {
        float a0 = (tid + off < 256) ? s0[tid + off] : 0.0f;
        float a1 = (tid + off < 256) ? s1[tid + off] : 0.0f;
        __syncthreads();
        s0[tid] += a0; s1[tid] += a1;
        __syncthreads();
    }
    float g0 = s0[tid] - t0, g1 = s1[tid] - t1;  // sum over threads > tid
    unsigned short o0[8], o1[8];
    for (int j = 7; j >= 0; --j) {
        int n = tid * 8 + j;
        float x0 = re[SWZ(n)] + g0;
        float x1 = im[SWZ(n)] + g1;
        float a0g = 0.5f * x0 * (1.0f + erff(x0 * 0.70710678118654752f));
        float a1g = 0.5f * x1 * (1.0f + erff(x1 * 0.70710678118654752f));
        bf16 b0 = __float2bfloat16(a0g), b1 = __float2bfloat16(a1g);
        o0[j] = *(unsigned short*)&b0; o1[j] = *(unsigned short*)&b1;
        g0 += y0v[j]; g1 += y1v[j];
    }
    *(ushort4*)(o0T + cb + tid * 8)     = make_ushort4(o0[0], o0[1], o0[2], o0[3]);
    *(ushort4*)(o0T + cb + tid * 8 + 4) = make_ushort4(o0[4], o0[5], o0[6], o0[7]);
    *(ushort4*)(o1T + cb + tid * 8)     = make_ushort4(o1[0], o1[1], o1[2], o1[3]);
    *(ushort4*)(o1T + cb + tid * 8 + 4) = make_ushort4(o1[4], o1[5], o1[6], o1[7]);
}

// ---------------- sparse seq-mix: build per-row (col,val) lists --------------
__global__ __launch_bounds__(256) void k_sparse_build(const float* __restrict__ Sp,
                                                      int* __restrict__ nnz,
                                                      int* __restrict__ idxs,
                                                      float* __restrict__ vals) {
    __shared__ int cnt;
    int l = blockIdx.x, tid = threadIdx.x;
    if (tid == 0) cnt = 0;
    __syncthreads();
    const float* row = Sp + (size_t)l * L_;
    for (int s = tid; s <= l; s += 256) {
        float v = row[s];
        if (v != 0.0f) {
            int slot = atomicAdd(&cnt, 1);
            if (slot < CAP) { idxs[l * CAP + slot] = s; vals[l * CAP + slot] = v; }
        }
    }
    __syncthreads();
    if (tid == 0) nnz[l] = min(cnt, CAP);
}

// ---------------- gather-SpMM accumulate -------------------------------------
__global__ __launch_bounds__(256) void k_spmm_acc(const int* __restrict__ nnz,
                                                  const int* __restrict__ idxs,
                                                  const float* __restrict__ vals,
                                                  const float* __restrict__ P,
                                                  float* __restrict__ C) {
    __shared__ int sidx[CAP];
    __shared__ float sval[CAP];
    int l = blockIdx.x, b = blockIdx.y, tid = threadIdx.x;
    int n = nnz[l];
    for (int j = tid; j < n; j += 256) {
        sidx[j] = idxs[l * CAP + j];
        sval[j] = vals[l * CAP + j];
    }
    __syncthreads();
    const float* Pb = P + (size_t)b * L_ * E_;
    size_t off = (size_t)tid * 4;
    float* cp = C + ((size_t)(b * L_ + l)) * E_ + off;
    float4 acc = *(float4*)cp;
    for (int j = 0; j < n; ++j) {
        float v = sval[j];
        float4 p = *(const float4*)(Pb + (size_t)sidx[j] * E_ + off);
        acc.x += v * p.x; acc.y += v * p.y; acc.z += v * p.z; acc.w += v * p.w;
    }
    *(float4*)cp = acc;
}

// ---------------- residual + LayerNorm ---------------------------------------
__global__ __launch_bounds__(256) void k_layernorm(const float* __restrict__ accb,
                                                   const float* __restrict__ emb,
                                                   const float* __restrict__ gamma,
                                                   const float* __restrict__ beta,
                                                   float* __restrict__ outp) {
    __shared__ float xs[E_];
    __shared__ float red[256];
    size_t row = blockIdx.x;
    int tid = threadIdx.x;
    const float* a = accb + row * E_;
    const float* e = emb + row * E_;
    float lsum = 0.0f;
    for (int i = tid; i < E_; i += 256) {
        float x = a[i] + e[i];
        xs[i] = x;
        lsum += x;
    }
    red[tid] = lsum; __syncthreads();
    for (int off = 128; off > 0; off >>= 1) {
        if (tid < off) red[tid] += red[tid + off];
        __syncthreads();
    }
    float mu = red[0] * (1.0f / E_);
    __syncthreads();
    float lv = 0.0f;
    for (int i = tid; i < E_; i += 256) { float d = xs[i] - mu; lv += d * d; }
    red[tid] = lv; __syncthreads();
    for (int off = 128; off > 0; off >>= 1) {
        if (tid < off) red[tid] += red[tid + off];
        __syncthreads();
    }
    float inv = rsqrtf(red[0] * (1.0f / E_) + 1e-12f);
    for (int i = tid; i < E_; i += 256)
        outp[row * E_ + i] = (xs[i] - mu) * inv * gamma[i] + beta[i];
}

extern "C" void kernel_launch(void* const* d_in, const int* in_sizes, int n_in,
                              void* d_out, int out_size, void* d_ws, size_t ws_size,
                              hipStream_t stream) {
    const float* emb    = (const float*)d_in[0];
    const float* W1     = (const float*)d_in[1];
    const float* b1     = (const float*)d_in[2];
    const float* W2     = (const float*)d_in[3];
    const float* b2     = (const float*)d_in[4];
    const float* psfs   = (const float*)d_in[5];
    const float* W3     = (const float*)d_in[6];
    const float* b3     = (const float*)d_in[7];
    const float* sparse = (const float*)d_in[8];
    const float* gamma  = (const float*)d_in[9];
    const float* beta   = (const float*)d_in[10];
    float* outp = (float*)d_out;

    const size_t BLE  = (size_t)B_ * L_ * E_;
    const size_t LE   = (size_t)L_ * E_;
    const size_t EE   = (size_t)E_ * E_;
    const size_t FREQ = (size_t)H_ * D_ * NFFT;   // 4.19M float2 = 33.5 MB

    float*  pre_sparse = (float*)d_ws;                 // 33.5 MB
    float*  accb       = pre_sparse + BLE;             // 33.5 MB
    float2* Khat       = (float2*)(accb + BLE);        // 33.5 MB
    float2* Xbuf       = Khat + FREQ;                  // 33.5 MB
    bf16*   preb       = (bf16*)(Xbuf + FREQ);         // 16.8 MB
    bf16*   actb       = preb + BLE;                   // 16.8 MB
    bf16*   W1b        = actb + BLE;
    bf16*   W2b        = W1b + EE;
    bf16*   W3b        = W2b + EE;                     // 3x 2.1 MB
    float2* twd        = (float2*)(W3b + EE);          // 32 KB
    float*  Ccv        = (float*)(twd + NFFT);         // 256 KB
    bf16*   yT         = (bf16*)(Ccv + (size_t)H_ * 64 * 64);  // 16.8 MB
    // time-multiplexed overlays:
    bf16*   preT       = (bf16*)accb;        // [B][E][L] bf16, dead before GEMM3
    bf16*   convT      = preT + BLE;         // [B][E][L] bf16, dead before GEMM3
    float*  psfT       = (float*)Xbuf;       // [H][D][L] fp32, dead before fft loop
    int*    s_nnz      = (int*)Xbuf;         // sparse lists, used after fft loop
    int*    s_idx      = s_nnz + L_;
    float*  s_val      = (float*)(s_idx + (size_t)L_ * CAP);
    // total ws use ~192 MB

    // twiddle table + bf16 conversions
    k_twiddle<<<16, 256, 0, stream>>>(twd);
    k_cvt<<<(int)(BLE / 4 / 256), 256, 0, stream>>>(emb, actb, (int)BLE);
    k_cvt<<<(int)(EE / 4 / 256), 256, 0, stream>>>(W1, W1b, (int)EE);
    k_cvt<<<(int)(EE / 4 / 256), 256, 0, stream>>>(W2, W2b, (int)EE);
    k_cvt<<<(int)(EE / 4 / 256), 256, 0, stream>>>(W3, W3b, (int)EE);

    // preb = bf16(emb @ W1^T + b1) ; pre_sparse = preb @ W2^T + b2 (fp32)
    k_gemm_mfma<1><<<dim3(E_ / 128, (B_ * L_) / 128), 256, 0, stream>>>(
        actb, W1b, b1, nullptr, preb, B_ * L_, E_, E_);
    k_gemm_mfma<0><<<dim3(E_ / 128, (B_ * L_) / 128), 256, 0, stream>>>(
        preb, W2b, b2, pre_sparse, nullptr, B_ * L_, E_, E_);

    // psfT[h][u][t<2048] = psfs[h][t][u]  (coalesced softmax input)
    k_tf32<<<dim3(1, L_ / 64, H_), 256, 0, stream>>>(
        psfs, psfT, L_, D_, (long)(2 * L_ - 1) * D_, (long)D_ * L_);

    // PSF softmax + causal-only 4096-FFT + Ccv; then d-FFT of kernel spectrum
    k_build_khat<<<dim3(D_, H_), 256, 0, stream>>>(psfT, Khat, Ccv, twd);
    k_khat_dfft<<<dim3(NFFT / 64, H_), 256, 0, stream>>>(Khat, twd);

    // preT[b][e][l] = preb[b][l][e]  (contiguous FFT input)
    k_tbf16<<<dim3(E_ / 64, L_ / 64, B_), 256, 0, stream>>>(
        preb, preT, L_, E_, (long)LE, (long)LE);

    // anticausal rank-1 path: yT = preT conv64 cval (per head circulant)
    k_ymat<<<dim3(L_ / 128, H_, B_), 256, 0, stream>>>(preT, Ccv, yT);

    // packed 2-batch FFT conv passes: (b0,b1) and (b2,b3)
    for (int p = 0; p < B_; p += 2) {
        k_fft_fwd<<<dim3(D_, H_), 256, 0, stream>>>(
            preT + (size_t)p * LE, preT + (size_t)(p + 1) * LE, Xbuf, twd);
        k_dconv<<<dim3(NFFT / 64, H_), 256, 0, stream>>>(Xbuf, Khat, twd);
        k_fft_inv<<<dim3(D_, H_), 256, 0, stream>>>(
            Xbuf, yT + (size_t)p * LE, yT + (size_t)(p + 1) * LE,
            convT + (size_t)p * LE, convT + (size_t)(p + 1) * LE, twd);
    }

    // actb[b][l][e] = convT[b][e][l]
    k_tbf16<<<dim3(L_ / 64, E_ / 64, B_), 256, 0, stream>>>(
        convT, actb, E_, L_, (long)LE, (long)LE);

    // accb = convb @ W3^T + b3 (fp32)
    k_gemm_mfma<0><<<dim3(E_ / 128, (B_ * L_) / 128), 256, 0, stream>>>(
        actb, W3b, b3, accb, nullptr, B_ * L_, E_, E_);

    // accb += tril(sparse) @ pre_sparse
    k_sparse_build<<<L_, 256, 0, stream>>>(sparse, s_nnz, s_idx, s_val);
    k_spmm_acc<<<dim3(L_, B_), 256, 0, stream>>>(s_nnz, s_idx, s_val, pre_sparse, accb);

    // out = LayerNorm(accb + emb) * gamma + beta
    k_layernorm<<<B_ * L_, 256, 0, stream>>>(accb, emb, gamma, beta, outp);
}

// Round 7
// 355.340 us; speedup vs baseline: 8.8329x; 1.2835x over previous
//
#include <hip/hip_runtime.h>
#include <hip/hip_bf16.h>
#include <math.h>

#define B_ 4
#define L_ 2048
#define E_ 1024
#define H_ 16
#define D_ 64
#define NFFT 4096
#define CAP 128

typedef __hip_bfloat16 bf16;
typedef __attribute__((ext_vector_type(8))) short bf16x8;
typedef __attribute__((ext_vector_type(4))) float f32x4;

typedef __attribute__((address_space(1))) const unsigned int gas_u32;
typedef __attribute__((address_space(3))) unsigned int las_u32;

__device__ __forceinline__ void gload_lds16(const void* g, void* l) {
    __builtin_amdgcn_global_load_lds((gas_u32*)g, (las_u32*)l, 16, 0, 0);
}

// LDS bank swizzle for the 4K FFT (bijective within 32-blocks)
#define SWZ(i) ((i) ^ (((i) >> 3) & 28))

__device__ __forceinline__ float bfu2f(unsigned short u) {
    return __uint_as_float(((unsigned)u) << 16);
}

// base-4 3-digit reversal (involution), for 64-pt FFT natural<->digitrev order
__device__ __forceinline__ int drev64(int k) {
    return ((k & 3) << 4) | (k & 12) | ((k >> 4) & 3);
}

// ---------------- twiddle table: tw[k] = exp(-2*pi*i*k/4096), k < 4096 -------
__global__ __launch_bounds__(256) void k_twiddle(float2* __restrict__ tw) {
    int k = blockIdx.x * 256 + threadIdx.x;
    if (k < NFFT) {
        float ang = -(float)k * (float)(M_PI / 2048.0);
        tw[k] = make_float2(cosf(ang), sinf(ang));
    }
}

// ------------- 4096-pt radix-4 DIF forward (natural in -> digit-rev out) -----
__device__ inline void fft4k_r4_dif(float* re, float* im, int tid,
                                    const float2* __restrict__ tw) {
    for (int st = 0; st < 6; ++st) {
        int q = 1 << (10 - 2 * st);
        __syncthreads();
        for (int it = 0; it < 4; ++it) {
            int b = tid + (it << 8);
            int p = b & (q - 1);
            int base = ((b & ~(q - 1)) << 2) | p;
            int i0 = SWZ(base), i1 = SWZ(base + q), i2 = SWZ(base + 2 * q), i3 = SWZ(base + 3 * q);
            float x0r = re[i0], x0i = im[i0], x1r = re[i1], x1i = im[i1];
            float x2r = re[i2], x2i = im[i2], x3r = re[i3], x3i = im[i3];
            float a0r = x0r + x2r, a0i = x0i + x2i;
            float a1r = x0r - x2r, a1i = x0i - x2i;
            float a2r = x1r + x3r, a2i = x1i + x3i;
            float a3r = x1r - x3r, a3i = x1i - x3i;
            float y0r = a0r + a2r, y0i = a0i + a2i;
            float y2r = a0r - a2r, y2i = a0i - a2i;
            float y1r = a1r + a3i, y1i = a1i - a3r;
            float y3r = a1r - a3i, y3i = a1i + a3r;
            int e = p << (2 * st);
            float2 w1 = tw[e], w2 = tw[2 * e], w3 = tw[3 * e];
            re[i0] = y0r; im[i0] = y0i;
            re[i1] = y1r * w1.x - y1i * w1.y; im[i1] = y1r * w1.y + y1i * w1.x;
            re[i2] = y2r * w2.x - y2i * w2.y; im[i2] = y2r * w2.y + y2i * w2.x;
            re[i3] = y3r * w3.x - y3i * w3.y; im[i3] = y3r * w3.y + y3i * w3.x;
        }
    }
    __syncthreads();
}

// ------------- 4096-pt radix-4 DIT inverse (digit-rev in -> natural out) -----
__device__ inline void fft4k_r4_inv(float* re, float* im, int tid,
                                    const float2* __restrict__ tw) {
    for (int st = 5; st >= 0; --st) {
        int q = 1 << (10 - 2 * st);
        __syncthreads();
        for (int it = 0; it < 4; ++it) {
            int b = tid + (it << 8);
            int p = b & (q - 1);
            int base = ((b & ~(q - 1)) << 2) | p;
            int i0 = SWZ(base), i1 = SWZ(base + q), i2 = SWZ(base + 2 * q), i3 = SWZ(base + 3 * q);
            int e = p << (2 * st);
            float2 w1 = tw[e], w2 = tw[2 * e], w3 = tw[3 * e];
            float z0r = re[i0], z0i = im[i0];
            float t1r = re[i1], t1i = im[i1];
            float t2r = re[i2], t2i = im[i2];
            float t3r = re[i3], t3i = im[i3];
            float z1r = t1r * w1.x + t1i * w1.y, z1i = t1i * w1.x - t1r * w1.y;
            float z2r = t2r * w2.x + t2i * w2.y, z2i = t2i * w2.x - t2r * w2.y;
            float z3r = t3r * w3.x + t3i * w3.y, z3i = t3i * w3.x - t3r * w3.y;
            float b0r = z0r + z2r, b0i = z0i + z2i;
            float b1r = z0r - z2r, b1i = z0i - z2i;
            float b2r = z1r + z3r, b2i = z1i + z3i;
            float b3r = z1r - z3r, b3i = z1i - z3i;
            re[i0] = b0r + b2r; im[i0] = b0i + b2i;
            re[i2] = b0r - b2r; im[i2] = b0i - b2i;
            re[i1] = b1r - b3i; im[i1] = b1i + b3r;
            re[i3] = b1r + b3i; im[i3] = b1i - b3r;
        }
    }
    __syncthreads();
}

// ---- batched 64-pt radix-4 over rows, LDS layout idx = row*66 + col ---------
// natural-in -> digit-rev-out. CONJ=0: forward (w^-). CONJ=1: unnormalized inverse.
template <int CONJ>
__device__ inline void fft64_rows(float* xr, float* xi, int tid,
                                  const float2* __restrict__ tw) {
    for (int st = 0; st < 3; ++st) {
        int q = 1 << (4 - 2 * st);
        __syncthreads();
        for (int it = 0; it < 4; ++it) {
            int w = tid + (it << 8);
            int lc = w & 63, bc = w >> 6;
            int p = bc & (q - 1);
            int basev = ((bc & ~(q - 1)) << 2) | p;
            int i0 = basev * 66 + lc, i1 = i0 + q * 66, i2 = i1 + q * 66, i3 = i2 + q * 66;
            float x0r = xr[i0], x0i = xi[i0], x1r = xr[i1], x1i = xi[i1];
            float x2r = xr[i2], x2i = xi[i2], x3r = xr[i3], x3i = xi[i3];
            float a0r = x0r + x2r, a0i = x0i + x2i;
            float a1r = x0r - x2r, a1i = x0i - x2i;
            float a2r = x1r + x3r, a2i = x1i + x3i;
            float a3r = x1r - x3r, a3i = x1i - x3i;
            float y0r = a0r + a2r, y0i = a0i + a2i;
            float y2r = a0r - a2r, y2i = a0i - a2i;
            float y1r, y1i, y3r, y3i;
            if (!CONJ) {
                y1r = a1r + a3i; y1i = a1i - a3r;
                y3r = a1r - a3i; y3i = a1i + a3r;
            } else {
                y1r = a1r - a3i; y1i = a1i + a3r;
                y3r = a1r + a3i; y3i = a1i - a3r;
            }
            int e = (p << (2 * st)) * 64;
            float2 w1 = tw[e], w2 = tw[2 * e], w3 = tw[3 * e];
            float w1y = CONJ ? -w1.y : w1.y;
            float w2y = CONJ ? -w2.y : w2.y;
            float w3y = CONJ ? -w3.y : w3.y;
            xr[i0] = y0r; xi[i0] = y0i;
            xr[i1] = y1r * w1.x - y1i * w1y; xi[i1] = y1r * w1y + y1i * w1.x;
            xr[i2] = y2r * w2.x - y2i * w2y; xi[i2] = y2r * w2y + y2i * w2.x;
            xr[i3] = y3r * w3.x - y3i * w3y; xi[i3] = y3r * w3y + y3i * w3.x;
        }
    }
    __syncthreads();
}

// ------- batched 64-pt radix-4 FFT over rows in [row*64+col] layout (khat) ---
__device__ inline void fft64_b(float* xr, float* xi, int tid,
                               const float2* __restrict__ tw) {
    for (int st = 0; st < 3; ++st) {
        int q = 1 << (4 - 2 * st);
        __syncthreads();
        for (int it = 0; it < 4; ++it) {
            int b = tid + (it << 8);
            int fc = b & 63;
            int bc = b >> 6;
            int p = bc & (q - 1);
            int basev = ((bc & ~(q - 1)) << 2) | p;
            int i0 = basev * 64 + fc, i1 = i0 + q * 64, i2 = i1 + q * 64, i3 = i2 + q * 64;
            float x0r = xr[i0], x0i = xi[i0], x1r = xr[i1], x1i = xi[i1];
            float x2r = xr[i2], x2i = xi[i2], x3r = xr[i3], x3i = xi[i3];
            float a0r = x0r + x2r, a0i = x0i + x2i;
            float a1r = x0r - x2r, a1i = x0i - x2i;
            float a2r = x1r + x3r, a2i = x1i + x3i;
            float a3r = x1r - x3r, a3i = x1i - x3i;
            float y0r = a0r + a2r, y0i = a0i + a2i;
            float y2r = a0r - a2r, y2i = a0i - a2i;
            float y1r = a1r + a3i, y1i = a1i - a3r;
            float y3r = a1r - a3i, y3i = a1i + a3r;
            int e = (p << (2 * st)) * 64;
            float2 w1 = tw[e], w2 = tw[2 * e], w3 = tw[3 * e];
            xr[i0] = y0r; xi[i0] = y0i;
            xr[i1] = y1r * w1.x - y1i * w1.y; xi[i1] = y1r * w1.y + y1i * w1.x;
            xr[i2] = y2r * w2.x - y2i * w2.y; xi[i2] = y2r * w2.y + y2i * w2.x;
            xr[i3] = y3r * w3.x - y3i * w3.y; xi[i3] = y3r * w3.y + y3i * w3.x;
        }
    }
    __syncthreads();
}

// ---------------- fp32 -> bf16 convert (vectorized) --------------------------
__global__ __launch_bounds__(256) void k_cvt(const float* __restrict__ in,
                                             bf16* __restrict__ out, int n) {
    int i = (blockIdx.x * 256 + threadIdx.x) * 4;
    if (i >= n) return;
    float4 v = *(const float4*)(in + i);
    bf16 tmp[4];
    tmp[0] = __float2bfloat16(v.x);
    tmp[1] = __float2bfloat16(v.y);
    tmp[2] = __float2bfloat16(v.z);
    tmp[3] = __float2bfloat16(v.w);
    *(ushort4*)(out + i) = *(ushort4*)tmp;
}

// ---------------- fp32 transpose: out[c*R+r] = in[r*C+c], 64x64 tiles --------
__global__ __launch_bounds__(256) void k_tf32(const float* __restrict__ in,
                                              float* __restrict__ out,
                                              int R, int C, long inB, long outB) {
    __shared__ float tile[64][65];
    in += (size_t)blockIdx.z * inB;
    out += (size_t)blockIdx.z * outB;
    int r0 = blockIdx.y * 64, c0 = blockIdx.x * 64;
    int t = threadIdx.x;
    int tx4 = (t & 15) * 4, ty = t >> 4;
#pragma unroll
    for (int k = 0; k < 4; ++k) {
        int r = ty + 16 * k;
        float4 v = *(const float4*)&in[(size_t)(r0 + r) * C + c0 + tx4];
        tile[r][tx4 + 0] = v.x; tile[r][tx4 + 1] = v.y;
        tile[r][tx4 + 2] = v.z; tile[r][tx4 + 3] = v.w;
    }
    __syncthreads();
#pragma unroll
    for (int k = 0; k < 4; ++k) {
        int c = ty + 16 * k;
        float4 w;
        w.x = tile[tx4 + 0][c]; w.y = tile[tx4 + 1][c];
        w.z = tile[tx4 + 2][c]; w.w = tile[tx4 + 3][c];
        *(float4*)&out[(size_t)(c0 + c) * R + r0 + tx4] = w;
    }
}

// ------ bf16 MFMA GEMM, BK=64, XOR-swizzled LDS, XCD-chunked block swizzle ---
// A: [M][K] bf16, Wt: [N][K] bf16 (NT). OUTB=0 -> C fp32; OUTB=1 -> Cb bf16.
template <int OUTB>
__global__ __launch_bounds__(256) void k_gemm_mfma(const bf16* __restrict__ A,
                                                   const bf16* __restrict__ Wt,
                                                   const float* __restrict__ bias,
                                                   float* __restrict__ C,
                                                   bf16* __restrict__ Cb,
                                                   int M, int N, int K) {
    __shared__ bf16 As[128 * 64];
    __shared__ bf16 Bs[128 * 64];
    int tid = threadIdx.x;
    int lane = tid & 63, w = tid >> 6;
    int wr = w >> 1, wc = w & 1;

    // XCD-chunked swizzle (nwg divisible by 8)
    int nwg = gridDim.x * gridDim.y;
    int flat = blockIdx.y * gridDim.x + blockIdx.x;
    int cpx = nwg >> 3;
    int swz = (flat & 7) * cpx + (flat >> 3);
    int bx = (swz % gridDim.x) * 128;   // N
    int by = (swz / gridDim.x) * 128;   // M

    f32x4 zz = {0.0f, 0.0f, 0.0f, 0.0f};
    f32x4 acc[4][4];
#pragma unroll
    for (int m = 0; m < 4; ++m)
#pragma unroll
        for (int n = 0; n < 4; ++n) acc[m][n] = zz;

    int koff = (lane >> 4) * 8;
    int rsub = lane & 15;

    for (int k0 = 0; k0 < K; k0 += 64) {
        // stage 128x64 tiles; source pre-swizzled so LDS row r holds k-chunk
        // (kb ^ ((r&7)<<3)) at linear slot kb  (G21: both-sides-or-neither)
#pragma unroll
        for (int i = 0; i < 4; ++i) {
            int c = tid + i * 256;          // 0..1023
            int row = c >> 3;
            int kb = (c & 7) * 8;
            int kbs = kb ^ ((row & 7) << 3);
            gload_lds16(A + (size_t)(by + row) * K + k0 + kbs, &As[c * 8]);
            gload_lds16(Wt + (size_t)(bx + row) * K + k0 + kbs, &Bs[c * 8]);
        }
        __syncthreads();
#pragma unroll
        for (int half = 0; half < 2; ++half) {
            int ko = koff + half * 32;
            bf16x8 af[4], bfv[4];
#pragma unroll
            for (int m = 0; m < 4; ++m) {
                int R = wr * 64 + m * 16 + rsub;
                af[m] = *(const bf16x8*)&As[R * 64 + (ko ^ ((R & 7) << 3))];
            }
#pragma unroll
            for (int n = 0; n < 4; ++n) {
                int R = wc * 64 + n * 16 + rsub;
                bfv[n] = *(const bf16x8*)&Bs[R * 64 + (ko ^ ((R & 7) << 3))];
            }
#pragma unroll
            for (int m = 0; m < 4; ++m)
#pragma unroll
                for (int n = 0; n < 4; ++n)
                    acc[m][n] = __builtin_amdgcn_mfma_f32_16x16x32_bf16(af[m], bfv[n], acc[m][n], 0, 0, 0);
        }
        __syncthreads();
    }

    int cq = (lane >> 4) * 4;
    int cr = lane & 15;
#pragma unroll
    for (int m = 0; m < 4; ++m) {
        int row0 = by + wr * 64 + m * 16 + cq;
#pragma unroll
        for (int n = 0; n < 4; ++n) {
            int col = bx + wc * 64 + n * 16 + cr;
            float bv = bias[col];
#pragma unroll
            for (int j = 0; j < 4; ++j) {
                float v = acc[m][n][j] + bv;
                if constexpr (OUTB)
                    Cb[(size_t)(row0 + j) * N + col] = __float2bfloat16(v);
                else
                    C[(size_t)(row0 + j) * N + col] = v;
            }
        }
    }
}

// -------- PSF softmax + causal K4096 + radix-4 seq-FFT + Cv (cval per u) -----
__global__ __launch_bounds__(256) void k_build_khat(const float* __restrict__ psfT,
                                                    float2* __restrict__ Khat,
                                                    float* __restrict__ Cv,
                                                    const float2* __restrict__ tw) {
    __shared__ float re[NFFT];
    __shared__ float im[NFFT];
    __shared__ float red[256];
    int u = blockIdx.x, h = blockIdx.y, tid = threadIdx.x;
    const float* col = psfT + ((size_t)(h * D_ + u)) * L_;

    float v[8];
    float4 a0 = *(const float4*)(col + tid * 8);
    float4 a1 = *(const float4*)(col + tid * 8 + 4);
    v[0] = a0.x; v[1] = a0.y; v[2] = a0.z; v[3] = a0.w;
    v[4] = a1.x; v[5] = a1.y; v[6] = a1.z; v[7] = a1.w;

    float lm = v[0];
#pragma unroll
    for (int j = 1; j < 8; ++j) lm = fmaxf(lm, v[j]);
    red[tid] = lm; __syncthreads();
    for (int off = 128; off > 0; off >>= 1) {
        if (tid < off) red[tid] = fmaxf(red[tid], red[tid + off]);
        __syncthreads();
    }
    float M = fmaxf(red[0], 0.0f);
    __syncthreads();

    float e[8];
    float ls = 0.0f;
#pragma unroll
    for (int j = 0; j < 8; ++j) { e[j] = expf(v[j] - M); ls += e[j]; }
    red[tid] = ls; __syncthreads();
    for (int off = 128; off > 0; off >>= 1) {
        if (tid < off) red[tid] += red[tid + off];
        __syncthreads();
    }
    float Z = red[0] + (float)(L_ - 1) * expf(-M);
    __syncthreads();

    float invZ = 1.0f / Z;
    float cval = expf(-M) * invZ;
    if (tid == 0) Cv[h * 64 + u] = cval;

#pragma unroll
    for (int j = 0; j < 8; ++j) {
        int i = tid * 8 + j;
        re[SWZ(i)] = e[j] * invZ;
    }
    for (int i = L_ + tid; i < NFFT; i += 256) re[SWZ(i)] = 0.0f;
    for (int i = tid; i < NFFT; i += 256) im[i] = 0.0f;

    fft4k_r4_dif(re, im, tid, tw);

    float sc = 1.0f / (float)NFFT;
    float2* outp = Khat + ((size_t)h * D_ + u) * NFFT;
    for (int i = tid; i < NFFT; i += 256)
        outp[i] = make_float2(re[SWZ(i)] * sc, im[SWZ(i)] * sc);
}

// --- in-place FFT64 over u of Khat (natural-k order out, +1/64); + Chat ------
__global__ __launch_bounds__(256) void k_khat_dfft(float2* __restrict__ Khat,
                                                   const float* __restrict__ Cv,
                                                   float2* __restrict__ Chat,
                                                   const float2* __restrict__ tw) {
    __shared__ float Xre[4096];
    __shared__ float Xim[4096];
    int f0 = blockIdx.x * 64, h = blockIdx.y, tid = threadIdx.x;
    float2* kb = Khat + (size_t)h * D_ * NFFT;
    for (int i = tid; i < 4096; i += 256) {
        int uu = i >> 6, fc = i & 63;
        float2 v = kb[(size_t)uu * NFFT + f0 + fc];
        Xre[i] = v.x; Xim[i] = v.y;
    }
    fft64_b(Xre, Xim, tid, tw);
    float sc = 1.0f / 64.0f;
    for (int i = tid; i < 4096; i += 256) {
        int s = i >> 6, fc = i & 63;
        // LDS slot s holds natural bin drev64(s) -> store at natural position
        kb[(size_t)drev64(s) * NFFT + f0 + fc] = make_float2(Xre[i] * sc, Xim[i] * sc);
    }
    // chat[h][k] = (1/64) sum_u Cv[h][u] w64^{-ku}, k=0..32 (one block per h)
    if (blockIdx.x == 0 && tid < 33) {
        int k = tid;
        float cr = 0.0f, ci = 0.0f;
        for (int u = 0; u < 64; ++u) {
            float cu = Cv[h * 64 + u];
            float2 wv = tw[((k * u) & 63) * 64];
            cr += cu * wv.x; ci += cu * wv.y;
        }
        Chat[h * 33 + k] = make_float2(cr * (1.0f / 64.0f), ci * (1.0f / 64.0f));
    }
}

// ------ A: v-FFT64 in time domain: preb[b][l][e] -> Xv[b][h][k=0..32][l] -----
__global__ __launch_bounds__(256) void k_vfft(const bf16* __restrict__ preb,
                                              float2* __restrict__ Xv,
                                              const float2* __restrict__ tw) {
    __shared__ float Xre[64 * 66];
    __shared__ float Xim[64 * 66];
    int l0 = blockIdx.x * 64, h = blockIdx.y, b = blockIdx.z;
    int tid = threadIdx.x;
    const bf16* src = preb + ((size_t)(b * L_ + l0)) * E_ + h * 64;
#pragma unroll
    for (int it = 0; it < 2; ++it) {
        int c = tid + it * 256;          // 0..511
        int lc = c >> 3, v8 = (c & 7) * 8;
        bf16x8 xv8 = *(const bf16x8*)(src + (size_t)lc * E_ + v8);
#pragma unroll
        for (int j = 0; j < 8; ++j) {
            Xre[(v8 + j) * 66 + lc] = bfu2f((unsigned short)xv8[j]);
            Xim[(v8 + j) * 66 + lc] = 0.0f;
        }
    }
    fft64_rows<0>(Xre, Xim, tid, tw);
    // natural bin k lives at LDS row drev64(k)
    for (int i = tid; i < 33 * 64; i += 256) {
        int k = i >> 6, lc = i & 63;
        int s = drev64(k);
        Xv[((size_t)(b * H_ + h) * 33 + k) * L_ + l0 + lc] =
            make_float2(Xre[s * 66 + lc], Xim[s * 66 + lc]);
    }
}

// ------ B: fused seq conv per (k,h,b): FFT4096 -> cmul Khat2 -> IFFT4096
//           + anticausal suffix correction (chat[k] * suffix-sum of input) ----
__global__ __launch_bounds__(256) void k_seqconv(float2* __restrict__ Xv,
                                                 const float2* __restrict__ Khat,
                                                 const float2* __restrict__ Chat,
                                                 const float2* __restrict__ tw) {
    __shared__ float re[NFFT];
    __shared__ float im[NFFT];
    __shared__ float sre[256];
    __shared__ float sim[256];
    int k = blockIdx.x, h = blockIdx.y, b = blockIdx.z;
    int tid = threadIdx.x;
    float2* col = Xv + ((size_t)(b * H_ + h) * 33 + k) * L_;

    float vr[8], vi[8];
#pragma unroll
    for (int j = 0; j < 8; ++j) {
        int n = tid * 8 + j;
        float2 z = col[n];
        vr[j] = z.x; vi[j] = z.y;
        re[SWZ(n)] = z.x; im[SWZ(n)] = z.y;
    }
    for (int i = L_ + tid; i < NFFT; i += 256) { re[SWZ(i)] = 0.0f; im[SWZ(i)] = 0.0f; }

    float2 ch = Chat[h * 33 + k];

    fft4k_r4_dif(re, im, tid, tw);
    const float2* kh = Khat + ((size_t)h * 64 + k) * NFFT;
    for (int i = tid; i < NFFT; i += 256) {
        float2 kk = kh[i];
        int s = SWZ(i);
        float xr = re[s], xi = im[s];
        re[s] = xr * kk.x - xi * kk.y;
        im[s] = xr * kk.y + xi * kk.x;
    }
    fft4k_r4_inv(re, im, tid, tw);

    // suffix scan of the input column (complex), g(n) = sum_{s>n} x[s]
    float t0 = 0.0f, t1 = 0.0f;
#pragma unroll
    for (int j = 0; j < 8; ++j) { t0 += vr[j]; t1 += vi[j]; }
    sre[tid] = t0; sim[tid] = t1; __syncthreads();
    for (int off = 1; off < 256; off <<= 1) {
        float a0 = (tid + off < 256) ? sre[tid + off] : 0.0f;
        float a1 = (tid + off < 256) ? sim[tid + off] : 0.0f;
        __syncthreads();
        sre[tid] += a0; sim[tid] += a1;
        __syncthreads();
    }
    float g0 = sre[tid] - t0, g1 = sim[tid] - t1;
    float2 out[8];
    for (int j = 7; j >= 0; --j) {
        int n = tid * 8 + j;
        float yr = re[SWZ(n)], yi = im[SWZ(n)];
        out[j] = make_float2(yr + ch.x * g0 - ch.y * g1,
                             yi + ch.x * g1 + ch.y * g0);
        g0 += vr[j]; g1 += vi[j];
    }
#pragma unroll
    for (int j = 0; j < 8; ++j) col[tid * 8 + j] = out[j];
}

// ------ C: inverse v-FFT64 (Hermitian) + GELU -> actb[b][l][e] bf16 ----------
__global__ __launch_bounds__(256) void k_vifft(const float2* __restrict__ Xv,
                                               bf16* __restrict__ actb,
                                               const float2* __restrict__ tw) {
    __shared__ float Xre[64 * 66];
    __shared__ float Xim[64 * 66];
    int l0 = blockIdx.x * 64, h = blockIdx.y, b = blockIdx.z;
    int tid = threadIdx.x;
    for (int i = tid; i < 33 * 64; i += 256) {
        int k = i >> 6, lc = i & 63;
        float2 z = Xv[((size_t)(b * H_ + h) * 33 + k) * L_ + l0 + lc];
        Xre[k * 66 + lc] = z.x; Xim[k * 66 + lc] = z.y;
    }
    __syncthreads();
    for (int i = tid; i < 31 * 64; i += 256) {
        int k = 33 + (i >> 6), lc = i & 63;
        Xre[k * 66 + lc] =  Xre[(64 - k) * 66 + lc];
        Xim[k * 66 + lc] = -Xim[(64 - k) * 66 + lc];
    }
    fft64_rows<1>(Xre, Xim, tid, tw);   // unnormalized inverse; out digit-rev in m
    bf16* dst = actb + ((size_t)(b * L_ + l0)) * E_ + h * 64;
#pragma unroll
    for (int it = 0; it < 2; ++it) {
        int c = tid + it * 256;
        int lc = c >> 3, m8 = (c & 7) * 8;
        unsigned short o[8];
#pragma unroll
        for (int j = 0; j < 8; ++j) {
            float x = Xre[drev64(m8 + j) * 66 + lc];
            float g = 0.5f * x * (1.0f + erff(x * 0.70710678118654752f));
            bf16 bb = __float2bfloat16(g);
            o[j] = *(unsigned short*)&bb;
        }
        *(ushort4*)(dst + (size_t)lc * E_ + m8)     = make_ushort4(o[0], o[1], o[2], o[3]);
        *(ushort4*)(dst + (size_t)lc * E_ + m8 + 4) = make_ushort4(o[4], o[5], o[6], o[7]);
    }
}

// ---------------- sparse seq-mix: build per-row (col,val) lists --------------
__global__ __launch_bounds__(256) void k_sparse_build(const float* __restrict__ Sp,
                                                      int* __restrict__ nnz,
                                                      int* __restrict__ idxs,
                                                      float* __restrict__ vals) {
    __shared__ int cnt;
    int l = blockIdx.x, tid = threadIdx.x;
    if (tid == 0) cnt = 0;
    __syncthreads();
    const float* row = Sp + (size_t)l * L_;
    for (int s = tid; s <= l; s += 256) {
        float v = row[s];
        if (v != 0.0f) {
            int slot = atomicAdd(&cnt, 1);
            if (slot < CAP) { idxs[l * CAP + slot] = s; vals[l * CAP + slot] = v; }
        }
    }
    __syncthreads();
    if (tid == 0) nnz[l] = min(cnt, CAP);
}

// ------- gather-SpMM accumulate: C[b][l][:] += sum_j val_j*P[b][s_j][:] ------
__global__ __launch_bounds__(256) void k_spmm_acc(const int* __restrict__ nnz,
                                                  const int* __restrict__ idxs,
                                                  const float* __restrict__ vals,
                                                  const bf16* __restrict__ P,
                                                  float* __restrict__ C) {
    __shared__ int sidx[CAP];
    __shared__ float sval[CAP];
    int l = blockIdx.x, b = blockIdx.y, tid = threadIdx.x;
    int n = nnz[l];
    for (int j = tid; j < n; j += 256) {
        sidx[j] = idxs[l * CAP + j];
        sval[j] = vals[l * CAP + j];
    }
    __syncthreads();
    const bf16* Pb = P + (size_t)b * L_ * E_;
    size_t off = (size_t)tid * 4;
    float* cp = C + ((size_t)(b * L_ + l)) * E_ + off;
    float4 acc = *(float4*)cp;
    for (int j = 0; j < n; ++j) {
        float v = sval[j];
        ushort4 p = *(const ushort4*)(Pb + (size_t)sidx[j] * E_ + off);
        acc.x += v * bfu2f(p.x); acc.y += v * bfu2f(p.y);
        acc.z += v * bfu2f(p.z); acc.w += v * bfu2f(p.w);
    }
    *(float4*)cp = acc;
}

// ---------------- residual + LayerNorm ---------------------------------------
__global__ __launch_bounds__(256) void k_layernorm(const float* __restrict__ accb,
                                                   const float* __restrict__ emb,
                                                   const float* __restrict__ gamma,
                                                   const float* __restrict__ beta,
                                                   float* __restrict__ outp) {
    __shared__ float xs[E_];
    __shared__ float red[256];
    size_t row = blockIdx.x;
    int tid = threadIdx.x;
    const float* a = accb + row * E_;
    const float* e = emb + row * E_;
    float lsum = 0.0f;
    for (int i = tid; i < E_; i += 256) {
        float x = a[i] + e[i];
        xs[i] = x;
        lsum += x;
    }
    red[tid] = lsum; __syncthreads();
    for (int off = 128; off > 0; off >>= 1) {
        if (tid < off) red[tid] += red[tid + off];
        __syncthreads();
    }
    float mu = red[0] * (1.0f / E_);
    __syncthreads();
    float lv = 0.0f;
    for (int i = tid; i < E_; i += 256) { float d = xs[i] - mu; lv += d * d; }
    red[tid] = lv; __syncthreads();
    for (int off = 128; off > 0; off >>= 1) {
        if (tid < off) red[tid] += red[tid + off];
        __syncthreads();
    }
    float inv = rsqrtf(red[0] * (1.0f / E_) + 1e-12f);
    for (int i = tid; i < E_; i += 256)
        outp[row * E_ + i] = (xs[i] - mu) * inv * gamma[i] + beta[i];
}

extern "C" void kernel_launch(void* const* d_in, const int* in_sizes, int n_in,
                              void* d_out, int out_size, void* d_ws, size_t ws_size,
                              hipStream_t stream) {
    const float* emb    = (const float*)d_in[0];
    const float* W1     = (const float*)d_in[1];
    const float* b1     = (const float*)d_in[2];
    const float* W2     = (const float*)d_in[3];
    const float* b2     = (const float*)d_in[4];
    const float* psfs   = (const float*)d_in[5];
    const float* W3     = (const float*)d_in[6];
    const float* b3     = (const float*)d_in[7];
    const float* sparse = (const float*)d_in[8];
    const float* gamma  = (const float*)d_in[9];
    const float* beta   = (const float*)d_in[10];
    float* outp = (float*)d_out;

    const size_t BLE  = (size_t)B_ * L_ * E_;
    const size_t EE   = (size_t)E_ * E_;
    const size_t XVSZ = (size_t)B_ * H_ * 33 * L_;     // float2 elems, 34.6 MB

    float*  accb       = (float*)d_ws;                       // 33.5 MB fp32
    bf16*   pre_sparse = (bf16*)(accb + BLE);                // 16.8 MB bf16
    float2* Khat       = (float2*)(pre_sparse + BLE);        // 33.5 MB
    float2* Xv         = Khat + (size_t)H_ * D_ * NFFT;      // 34.6 MB
    bf16*   preb       = (bf16*)(Xv + XVSZ);                 // 16.8 MB
    bf16*   actb       = preb + BLE;                         // 16.8 MB
    bf16*   W1b        = actb + BLE;
    bf16*   W2b        = W1b + EE;
    bf16*   W3b        = W2b + EE;                           // 3x 2.1 MB
    float2* twd        = (float2*)(W3b + EE);                // 32 KB
    float*  Cv         = (float*)(twd + NFFT);               // 4 KB
    float2* Chat       = (float2*)(Cv + (size_t)H_ * 64);    // 4.2 KB
    // time-multiplexed overlays on Xv (dead before k_vfft / after k_vifft):
    float*  psfT       = (float*)Xv;          // [H][D][L] fp32, 8.4 MB
    int*    s_nnz      = (int*)Xv;            // sparse lists (used after conv)
    int*    s_idx      = s_nnz + L_;
    float*  s_val      = (float*)(s_idx + (size_t)L_ * CAP);
    // total ws use ~158 MB

    // twiddle table + bf16 conversions
    k_twiddle<<<16, 256, 0, stream>>>(twd);
    k_cvt<<<(int)(BLE / 4 / 256), 256, 0, stream>>>(emb, actb, (int)BLE);
    k_cvt<<<(int)(EE / 4 / 256), 256, 0, stream>>>(W1, W1b, (int)EE);
    k_cvt<<<(int)(EE / 4 / 256), 256, 0, stream>>>(W2, W2b, (int)EE);
    k_cvt<<<(int)(EE / 4 / 256), 256, 0, stream>>>(W3, W3b, (int)EE);

    // preb = bf16(emb @ W1^T + b1) ; pre_sparse = bf16(preb @ W2^T + b2)
    k_gemm_mfma<1><<<dim3(E_ / 128, (B_ * L_) / 128), 256, 0, stream>>>(
        actb, W1b, b1, nullptr, preb, B_ * L_, E_, E_);
    k_gemm_mfma<1><<<dim3(E_ / 128, (B_ * L_) / 128), 256, 0, stream>>>(
        preb, W2b, b2, nullptr, pre_sparse, B_ * L_, E_, E_);

    // psfT[h][u][t<2048] = psfs[h][t][u]  (coalesced softmax input)
    k_tf32<<<dim3(1, L_ / 64, H_), 256, 0, stream>>>(
        psfs, psfT, L_, D_, (long)(2 * L_ - 1) * D_, (long)D_ * L_);

    // PSF softmax + causal seq-FFT + cval; d-FFT of kernel spectrum + chat
    k_build_khat<<<dim3(D_, H_), 256, 0, stream>>>(psfT, Khat, Cv, twd);
    k_khat_dfft<<<dim3(NFFT / 64, H_), 256, 0, stream>>>(Khat, Cv, Chat, twd);

    // conv: time-domain v-FFT -> fused per-(k,h,b) seq conv (in place) -> inv v-FFT
    k_vfft<<<dim3(L_ / 64, H_, B_), 256, 0, stream>>>(preb, Xv, twd);
    k_seqconv<<<dim3(33, H_, B_), 256, 0, stream>>>(Xv, Khat, Chat, twd);
    k_vifft<<<dim3(L_ / 64, H_, B_), 256, 0, stream>>>(Xv, actb, twd);

    // accb = conv @ W3^T + b3 (fp32)
    k_gemm_mfma<0><<<dim3(E_ / 128, (B_ * L_) / 128), 256, 0, stream>>>(
        actb, W3b, b3, accb, nullptr, B_ * L_, E_, E_);

    // accb += tril(sparse) @ pre_sparse
    k_sparse_build<<<L_, 256, 0, stream>>>(sparse, s_nnz, s_idx, s_val);
    k_spmm_acc<<<dim3(L_, B_), 256, 0, stream>>>(s_nnz, s_idx, s_val, pre_sparse, accb);

    // out = LayerNorm(accb + emb) * gamma + beta
    k_layernorm<<<B_ * L_, 256, 0, stream>>>(accb, emb, gamma, beta, outp);
}

// Round 8
// 300.528 us; speedup vs baseline: 10.4439x; 1.1824x over previous
//
#include <hip/hip_runtime.h>
#include <hip/hip_bf16.h>
#include <math.h>

#define B_ 4
#define L_ 2048
#define E_ 1024
#define H_ 16
#define D_ 64
#define NFFT 4096
#define CAP 128

typedef __hip_bfloat16 bf16;
typedef __attribute__((ext_vector_type(8))) short bf16x8;
typedef __attribute__((ext_vector_type(4))) float f32x4;

typedef __attribute__((address_space(1))) const unsigned int gas_u32;
typedef __attribute__((address_space(3))) unsigned int las_u32;

__device__ __forceinline__ void gload_lds16(const void* g, void* l) {
    __builtin_amdgcn_global_load_lds((gas_u32*)g, (las_u32*)l, 16, 0, 0);
}

// padded LDS slot: +1 float per 16 (<=2-way conflicts for all 3 phase patterns)
#define SL(i) ((i) + ((i) >> 4))
#define LDSN (NFFT + NFFT / 16)   // 4352

__device__ __forceinline__ float bfu2f(unsigned short u) {
    return __uint_as_float(((unsigned)u) << 16);
}

// base-4 3-digit reversal (involution), for 64-pt FFT natural<->digitrev order
__device__ __forceinline__ int drev64(int k) {
    return ((k & 3) << 4) | (k & 12) | ((k >> 4) & 3);
}

// ---------------- twiddle table: tw[k] = exp(-2*pi*i*k/4096), k < 4096 -------
__global__ __launch_bounds__(256) void k_twiddle(float2* __restrict__ tw) {
    int k = blockIdx.x * 256 + threadIdx.x;
    if (k < NFFT) {
        float ang = -(float)k * (float)(M_PI / 2048.0);
        tw[k] = make_float2(cosf(ang), sinf(ang));
    }
}

// ---------------- register radix-4 butterflies -------------------------------
__device__ __forceinline__ void r4dif(float& x0r, float& x0i, float& x1r, float& x1i,
                                      float& x2r, float& x2i, float& x3r, float& x3i,
                                      int e, const float2* __restrict__ tw) {
    float a0r = x0r + x2r, a0i = x0i + x2i, a1r = x0r - x2r, a1i = x0i - x2i;
    float a2r = x1r + x3r, a2i = x1i + x3i, a3r = x1r - x3r, a3i = x1i - x3i;
    float y0r = a0r + a2r, y0i = a0i + a2i, y2r = a0r - a2r, y2i = a0i - a2i;
    float y1r = a1r + a3i, y1i = a1i - a3r, y3r = a1r - a3i, y3i = a1i + a3r;
    float2 w1 = tw[e], w2 = tw[2 * e], w3 = tw[3 * e];
    x0r = y0r; x0i = y0i;
    x1r = y1r * w1.x - y1i * w1.y; x1i = y1r * w1.y + y1i * w1.x;
    x2r = y2r * w2.x - y2i * w2.y; x2i = y2r * w2.y + y2i * w2.x;
    x3r = y3r * w3.x - y3i * w3.y; x3i = y3r * w3.y + y3i * w3.x;
}
__device__ __forceinline__ void r4dif_nt(float& x0r, float& x0i, float& x1r, float& x1i,
                                         float& x2r, float& x2i, float& x3r, float& x3i) {
    float a0r = x0r + x2r, a0i = x0i + x2i, a1r = x0r - x2r, a1i = x0i - x2i;
    float a2r = x1r + x3r, a2i = x1i + x3i, a3r = x1r - x3r, a3i = x1i - x3i;
    x0r = a0r + a2r; x0i = a0i + a2i;
    x2r = a0r - a2r; x2i = a0i - a2i;
    float y1r = a1r + a3i, y1i = a1i - a3r, y3r = a1r - a3i, y3i = a1i + a3r;
    x1r = y1r; x1i = y1i; x3r = y3r; x3i = y3i;
}
__device__ __forceinline__ void r4dit(float& x0r, float& x0i, float& x1r, float& x1i,
                                      float& x2r, float& x2i, float& x3r, float& x3i,
                                      int e, const float2* __restrict__ tw) {
    float2 w1 = tw[e], w2 = tw[2 * e], w3 = tw[3 * e];
    float z1r = x1r * w1.x + x1i * w1.y, z1i = x1i * w1.x - x1r * w1.y;
    float z2r = x2r * w2.x + x2i * w2.y, z2i = x2i * w2.x - x2r * w2.y;
    float z3r = x3r * w3.x + x3i * w3.y, z3i = x3i * w3.x - x3r * w3.y;
    float b0r = x0r + z2r, b0i = x0i + z2i, b1r = x0r - z2r, b1i = x0i - z2i;
    float b2r = z1r + z3r, b2i = z1i + z3i, b3r = z1r - z3r, b3i = z1i - z3i;
    x0r = b0r + b2r; x0i = b0i + b2i;
    x2r = b0r - b2r; x2i = b0i - b2i;
    x1r = b1r - b3i; x1i = b1i + b3r;
    x3r = b1r + b3i; x3i = b1i - b3r;
}
__device__ __forceinline__ void r4dit_nt(float& x0r, float& x0i, float& x1r, float& x1i,
                                         float& x2r, float& x2i, float& x3r, float& x3i) {
    float b0r = x0r + x2r, b0i = x0i + x2i, b1r = x0r - x2r, b1i = x0i - x2i;
    float b2r = x1r + x3r, b2i = x1i + x3i, b3r = x1r - x3r, b3i = x1i - x3i;
    x0r = b0r + b2r; x0i = b0i + b2i;
    x2r = b0r - b2r; x2i = b0i - b2i;
    x1r = b1r - b3i; x1i = b1i + b3r;
    x3r = b1r + b3i; x3i = b1i - b3r;
}

// ---- phase A (stages 0,1): thread p owns X[j]=a[p+256j] ---------------------
__device__ __forceinline__ void fftA_fwd(float* xr, float* xi, int p, const float2* __restrict__ tw) {
#pragma unroll
    for (int j0 = 0; j0 < 4; ++j0)
        r4dif(xr[j0], xi[j0], xr[j0 + 4], xi[j0 + 4], xr[j0 + 8], xi[j0 + 8],
              xr[j0 + 12], xi[j0 + 12], p + 256 * j0, tw);
#pragma unroll
    for (int g = 0; g < 4; ++g)
        r4dif(xr[4 * g], xi[4 * g], xr[4 * g + 1], xi[4 * g + 1], xr[4 * g + 2],
              xi[4 * g + 2], xr[4 * g + 3], xi[4 * g + 3], p << 2, tw);
}
__device__ __forceinline__ void fftA_inv(float* xr, float* xi, int p, const float2* __restrict__ tw) {
#pragma unroll
    for (int g = 0; g < 4; ++g)
        r4dit(xr[4 * g], xi[4 * g], xr[4 * g + 1], xi[4 * g + 1], xr[4 * g + 2],
              xi[4 * g + 2], xr[4 * g + 3], xi[4 * g + 3], p << 2, tw);
#pragma unroll
    for (int j0 = 0; j0 < 4; ++j0)
        r4dit(xr[j0], xi[j0], xr[j0 + 4], xi[j0 + 4], xr[j0 + 8], xi[j0 + 8],
              xr[j0 + 12], xi[j0 + 12], p + 256 * j0, tw);
}
// ---- phase B (stages 2,3): thread (b,o) owns X[j]=a[b*256+o+16j] ------------
__device__ __forceinline__ void fftB_fwd(float* xr, float* xi, int o, const float2* __restrict__ tw) {
#pragma unroll
    for (int j0 = 0; j0 < 4; ++j0)
        r4dif(xr[j0], xi[j0], xr[j0 + 4], xi[j0 + 4], xr[j0 + 8], xi[j0 + 8],
              xr[j0 + 12], xi[j0 + 12], (o + 16 * j0) << 4, tw);
#pragma unroll
    for (int g = 0; g < 4; ++g)
        r4dif(xr[4 * g], xi[4 * g], xr[4 * g + 1], xi[4 * g + 1], xr[4 * g + 2],
              xi[4 * g + 2], xr[4 * g + 3], xi[4 * g + 3], o << 6, tw);
}
__device__ __forceinline__ void fftB_inv(float* xr, float* xi, int o, const float2* __restrict__ tw) {
#pragma unroll
    for (int g = 0; g < 4; ++g)
        r4dit(xr[4 * g], xi[4 * g], xr[4 * g + 1], xi[4 * g + 1], xr[4 * g + 2],
              xi[4 * g + 2], xr[4 * g + 3], xi[4 * g + 3], o << 6, tw);
#pragma unroll
    for (int j0 = 0; j0 < 4; ++j0)
        r4dit(xr[j0], xi[j0], xr[j0 + 4], xi[j0 + 4], xr[j0 + 8], xi[j0 + 8],
              xr[j0 + 12], xi[j0 + 12], (o + 16 * j0) << 4, tw);
}
// ---- phase C fwd (stages 4,5): thread t owns X[j]=a[16t+j] ------------------
__device__ __forceinline__ void fftC_fwd(float* xr, float* xi, const float2* __restrict__ tw) {
#pragma unroll
    for (int j0 = 0; j0 < 4; ++j0)
        r4dif(xr[j0], xi[j0], xr[j0 + 4], xi[j0 + 4], xr[j0 + 8], xi[j0 + 8],
              xr[j0 + 12], xi[j0 + 12], j0 << 8, tw);
#pragma unroll
    for (int g = 0; g < 4; ++g)
        r4dif_nt(xr[4 * g], xi[4 * g], xr[4 * g + 1], xi[4 * g + 1], xr[4 * g + 2],
                 xi[4 * g + 2], xr[4 * g + 3], xi[4 * g + 3]);
}
__device__ __forceinline__ void fftC_inv(float* xr, float* xi, const float2* __restrict__ tw) {
#pragma unroll
    for (int g = 0; g < 4; ++g)
        r4dit_nt(xr[4 * g], xi[4 * g], xr[4 * g + 1], xi[4 * g + 1], xr[4 * g + 2],
                 xi[4 * g + 2], xr[4 * g + 3], xi[4 * g + 3]);
#pragma unroll
    for (int j0 = 0; j0 < 4; ++j0)
        r4dit(xr[j0], xi[j0], xr[j0 + 4], xi[j0 + 4], xr[j0 + 8], xi[j0 + 8],
              xr[j0 + 12], xi[j0 + 12], j0 << 8, tw);
}

// ---- batched 64-pt radix-4 over rows, LDS layout idx = row*66 + col ---------
template <int CONJ>
__device__ inline void fft64_rows(float* xr, float* xi, int tid,
                                  const float2* __restrict__ tw) {
    for (int st = 0; st < 3; ++st) {
        int q = 1 << (4 - 2 * st);
        __syncthreads();
        for (int it = 0; it < 4; ++it) {
            int w = tid + (it << 8);
            int lc = w & 63, bc = w >> 6;
            int p = bc & (q - 1);
            int basev = ((bc & ~(q - 1)) << 2) | p;
            int i0 = basev * 66 + lc, i1 = i0 + q * 66, i2 = i1 + q * 66, i3 = i2 + q * 66;
            float x0r = xr[i0], x0i = xi[i0], x1r = xr[i1], x1i = xi[i1];
            float x2r = xr[i2], x2i = xi[i2], x3r = xr[i3], x3i = xi[i3];
            float a0r = x0r + x2r, a0i = x0i + x2i;
            float a1r = x0r - x2r, a1i = x0i - x2i;
            float a2r = x1r + x3r, a2i = x1i + x3i;
            float a3r = x1r - x3r, a3i = x1i - x3i;
            float y0r = a0r + a2r, y0i = a0i + a2i;
            float y2r = a0r - a2r, y2i = a0i - a2i;
            float y1r, y1i, y3r, y3i;
            if (!CONJ) {
                y1r = a1r + a3i; y1i = a1i - a3r;
                y3r = a1r - a3i; y3i = a1i + a3r;
            } else {
                y1r = a1r - a3i; y1i = a1i + a3r;
                y3r = a1r + a3i; y3i = a1i - a3r;
            }
            int e = (p << (2 * st)) * 64;
            float2 w1 = tw[e], w2 = tw[2 * e], w3 = tw[3 * e];
            float w1y = CONJ ? -w1.y : w1.y;
            float w2y = CONJ ? -w2.y : w2.y;
            float w3y = CONJ ? -w3.y : w3.y;
            xr[i0] = y0r; xi[i0] = y0i;
            xr[i1] = y1r * w1.x - y1i * w1y; xi[i1] = y1r * w1y + y1i * w1.x;
            xr[i2] = y2r * w2.x - y2i * w2y; xi[i2] = y2r * w2y + y2i * w2.x;
            xr[i3] = y3r * w3.x - y3i * w3y; xi[i3] = y3r * w3y + y3i * w3.x;
        }
    }
    __syncthreads();
}

// ------- batched 64-pt radix-4 FFT over rows in [row*64+col] layout (khat) ---
__device__ inline void fft64_b(float* xr, float* xi, int tid,
                               const float2* __restrict__ tw) {
    for (int st = 0; st < 3; ++st) {
        int q = 1 << (4 - 2 * st);
        __syncthreads();
        for (int it = 0; it < 4; ++it) {
            int b = tid + (it << 8);
            int fc = b & 63;
            int bc = b >> 6;
            int p = bc & (q - 1);
            int basev = ((bc & ~(q - 1)) << 2) | p;
            int i0 = basev * 64 + fc, i1 = i0 + q * 64, i2 = i1 + q * 64, i3 = i2 + q * 64;
            float x0r = xr[i0], x0i = xi[i0], x1r = xr[i1], x1i = xi[i1];
            float x2r = xr[i2], x2i = xi[i2], x3r = xr[i3], x3i = xi[i3];
            float a0r = x0r + x2r, a0i = x0i + x2i;
            float a1r = x0r - x2r, a1i = x0i - x2i;
            float a2r = x1r + x3r, a2i = x1i + x3i;
            float a3r = x1r - x3r, a3i = x1i - x3i;
            float y0r = a0r + a2r, y0i = a0i + a2i;
            float y2r = a0r - a2r, y2i = a0i - a2i;
            float y1r = a1r + a3i, y1i = a1i - a3r;
            float y3r = a1r - a3i, y3i = a1i + a3r;
            int e = (p << (2 * st)) * 64;
            float2 w1 = tw[e], w2 = tw[2 * e], w3 = tw[3 * e];
            xr[i0] = y0r; xi[i0] = y0i;
            xr[i1] = y1r * w1.x - y1i * w1.y; xi[i1] = y1r * w1.y + y1i * w1.x;
            xr[i2] = y2r * w2.x - y2i * w2.y; xi[i2] = y2r * w2.y + y2i * w2.x;
            xr[i3] = y3r * w3.x - y3i * w3.y; xi[i3] = y3r * w3.y + y3i * w3.x;
        }
    }
    __syncthreads();
}

// ---------------- fp32 -> bf16 convert (vectorized) --------------------------
__global__ __launch_bounds__(256) void k_cvt(const float* __restrict__ in,
                                             bf16* __restrict__ out, int n) {
    int i = (blockIdx.x * 256 + threadIdx.x) * 4;
    if (i >= n) return;
    float4 v = *(const float4*)(in + i);
    bf16 tmp[4];
    tmp[0] = __float2bfloat16(v.x);
    tmp[1] = __float2bfloat16(v.y);
    tmp[2] = __float2bfloat16(v.z);
    tmp[3] = __float2bfloat16(v.w);
    *(ushort4*)(out + i) = *(ushort4*)tmp;
}

// ---------------- fp32 transpose: out[c*R+r] = in[r*C+c], 64x64 tiles --------
__global__ __launch_bounds__(256) void k_tf32(const float* __restrict__ in,
                                              float* __restrict__ out,
                                              int R, int C, long inB, long outB) {
    __shared__ float tile[64][65];
    in += (size_t)blockIdx.z * inB;
    out += (size_t)blockIdx.z * outB;
    int r0 = blockIdx.y * 64, c0 = blockIdx.x * 64;
    int t = threadIdx.x;
    int tx4 = (t & 15) * 4, ty = t >> 4;
#pragma unroll
    for (int k = 0; k < 4; ++k) {
        int r = ty + 16 * k;
        float4 v = *(const float4*)&in[(size_t)(r0 + r) * C + c0 + tx4];
        tile[r][tx4 + 0] = v.x; tile[r][tx4 + 1] = v.y;
        tile[r][tx4 + 2] = v.z; tile[r][tx4 + 3] = v.w;
    }
    __syncthreads();
#pragma unroll
    for (int k = 0; k < 4; ++k) {
        int c = ty + 16 * k;
        float4 w;
        w.x = tile[tx4 + 0][c]; w.y = tile[tx4 + 1][c];
        w.z = tile[tx4 + 2][c]; w.w = tile[tx4 + 3][c];
        *(float4*)&out[(size_t)(c0 + c) * R + r0 + tx4] = w;
    }
}

// ------ bf16 MFMA GEMM, BK=64, XOR-swizzled LDS, XCD-chunked block swizzle ---
template <int OUTB>
__global__ __launch_bounds__(256) void k_gemm_mfma(const bf16* __restrict__ A,
                                                   const bf16* __restrict__ Wt,
                                                   const float* __restrict__ bias,
                                                   float* __restrict__ C,
                                                   bf16* __restrict__ Cb,
                                                   int M, int N, int K) {
    __shared__ bf16 As[128 * 64];
    __shared__ bf16 Bs[128 * 64];
    int tid = threadIdx.x;
    int lane = tid & 63, w = tid >> 6;
    int wr = w >> 1, wc = w & 1;

    int nwg = gridDim.x * gridDim.y;
    int flat = blockIdx.y * gridDim.x + blockIdx.x;
    int cpx = nwg >> 3;
    int swz = (flat & 7) * cpx + (flat >> 3);
    int bx = (swz % gridDim.x) * 128;
    int by = (swz / gridDim.x) * 128;

    f32x4 zz = {0.0f, 0.0f, 0.0f, 0.0f};
    f32x4 acc[4][4];
#pragma unroll
    for (int m = 0; m < 4; ++m)
#pragma unroll
        for (int n = 0; n < 4; ++n) acc[m][n] = zz;

    int koff = (lane >> 4) * 8;
    int rsub = lane & 15;

    for (int k0 = 0; k0 < K; k0 += 64) {
#pragma unroll
        for (int i = 0; i < 4; ++i) {
            int c = tid + i * 256;
            int row = c >> 3;
            int kb = (c & 7) * 8;
            int kbs = kb ^ ((row & 7) << 3);
            gload_lds16(A + (size_t)(by + row) * K + k0 + kbs, &As[c * 8]);
            gload_lds16(Wt + (size_t)(bx + row) * K + k0 + kbs, &Bs[c * 8]);
        }
        __syncthreads();
#pragma unroll
        for (int half = 0; half < 2; ++half) {
            int ko = koff + half * 32;
            bf16x8 af[4], bfv[4];
#pragma unroll
            for (int m = 0; m < 4; ++m) {
                int R = wr * 64 + m * 16 + rsub;
                af[m] = *(const bf16x8*)&As[R * 64 + (ko ^ ((R & 7) << 3))];
            }
#pragma unroll
            for (int n = 0; n < 4; ++n) {
                int R = wc * 64 + n * 16 + rsub;
                bfv[n] = *(const bf16x8*)&Bs[R * 64 + (ko ^ ((R & 7) << 3))];
            }
#pragma unroll
            for (int m = 0; m < 4; ++m)
#pragma unroll
                for (int n = 0; n < 4; ++n)
                    acc[m][n] = __builtin_amdgcn_mfma_f32_16x16x32_bf16(af[m], bfv[n], acc[m][n], 0, 0, 0);
        }
        __syncthreads();
    }

    int cq = (lane >> 4) * 4;
    int cr = lane & 15;
#pragma unroll
    for (int m = 0; m < 4; ++m) {
        int row0 = by + wr * 64 + m * 16 + cq;
#pragma unroll
        for (int n = 0; n < 4; ++n) {
            int col = bx + wc * 64 + n * 16 + cr;
            float bv = bias[col];
#pragma unroll
            for (int j = 0; j < 4; ++j) {
                float v = acc[m][n][j] + bv;
                if constexpr (OUTB)
                    Cb[(size_t)(row0 + j) * N + col] = __float2bfloat16(v);
                else
                    C[(size_t)(row0 + j) * N + col] = v;
            }
        }
    }
}

// -------- PSF softmax + FULL K4096 (causal + uniform anticausal) + fwd FFT ---
// K4096: [0..2047]=causal softmax weights, 2048=0, [2049..4095]=cval.
// Alias-free: x zero-padded [2048,4096), outputs only read at n<2048.
__global__ __launch_bounds__(256) void k_build_khat(const float* __restrict__ psfT,
                                                    float2* __restrict__ Khat,
                                                    const float2* __restrict__ tw) {
    __shared__ float re[LDSN];
    __shared__ float im[LDSN];
    __shared__ float red[256];
    int u = blockIdx.x, h = blockIdx.y, tid = threadIdx.x;
    const float* col = psfT + ((size_t)(h * D_ + u)) * L_;
    int p = tid;

    // load causal logits at phase-A ownership: v[j] = col[p+256j], j<8
    float v[8];
#pragma unroll
    for (int j = 0; j < 8; ++j) v[j] = col[p + 256 * j];

    float lm = v[0];
#pragma unroll
    for (int j = 1; j < 8; ++j) lm = fmaxf(lm, v[j]);
    red[tid] = lm; __syncthreads();
    for (int off = 128; off > 0; off >>= 1) {
        if (tid < off) red[tid] = fmaxf(red[tid], red[tid + off]);
        __syncthreads();
    }
    float M = fmaxf(red[0], 0.0f);
    __syncthreads();

    float e[8];
    float ls = 0.0f;
#pragma unroll
    for (int j = 0; j < 8; ++j) { e[j] = expf(v[j] - M); ls += e[j]; }
    red[tid] = ls; __syncthreads();
    for (int off = 128; off > 0; off >>= 1) {
        if (tid < off) red[tid] += red[tid + off];
        __syncthreads();
    }
    float Z = red[0] + (float)(L_ - 1) * expf(-M);
    float invZ = 1.0f / Z;
    float cval = expf(-M) * invZ;

    float xr[16], xi[16];
#pragma unroll
    for (int j = 0; j < 16; ++j) {
        int i = p + 256 * j;
        xr[j] = (j < 8) ? e[j] * invZ : ((i == 2048) ? 0.0f : cval);
        xi[j] = 0.0f;
    }
    __syncthreads();  // red[] reuse done

    fftA_fwd(xr, xi, p, tw);
#pragma unroll
    for (int j = 0; j < 16; ++j) { re[SL(p + 256 * j)] = xr[j]; im[SL(p + 256 * j)] = xi[j]; }
    __syncthreads();
    {
        int b = tid >> 4, o = tid & 15;
#pragma unroll
        for (int j = 0; j < 16; ++j) {
            int i = b * 256 + o + 16 * j;
            xr[j] = re[SL(i)]; xi[j] = im[SL(i)];
        }
        fftB_fwd(xr, xi, o, tw);
#pragma unroll
        for (int j = 0; j < 16; ++j) {
            int i = b * 256 + o + 16 * j;
            re[SL(i)] = xr[j]; im[SL(i)] = xi[j];
        }
    }
    __syncthreads();
#pragma unroll
    for (int j = 0; j < 16; ++j) { xr[j] = re[SL(16 * tid + j)]; xi[j] = im[SL(16 * tid + j)]; }
    fftC_fwd(xr, xi, tw);

    float sc = 1.0f / (float)NFFT;
    float2* outp = Khat + ((size_t)h * D_ + u) * NFFT + 16 * tid;
#pragma unroll
    for (int j = 0; j < 16; ++j) outp[j] = make_float2(xr[j] * sc, xi[j] * sc);
}

// --- in-place FFT64 over u of Khat (natural-k order out, +1/64 scale) --------
__global__ __launch_bounds__(256) void k_khat_dfft(float2* __restrict__ Khat,
                                                   const float2* __restrict__ tw) {
    __shared__ float Xre[4096];
    __shared__ float Xim[4096];
    int f0 = blockIdx.x * 64, h = blockIdx.y, tid = threadIdx.x;
    float2* kb = Khat + (size_t)h * D_ * NFFT;
    for (int i = tid; i < 4096; i += 256) {
        int uu = i >> 6, fc = i & 63;
        float2 v = kb[(size_t)uu * NFFT + f0 + fc];
        Xre[i] = v.x; Xim[i] = v.y;
    }
    fft64_b(Xre, Xim, tid, tw);
    float sc = 1.0f / 64.0f;
    for (int i = tid; i < 4096; i += 256) {
        int s = i >> 6, fc = i & 63;
        kb[(size_t)drev64(s) * NFFT + f0 + fc] = make_float2(Xre[i] * sc, Xim[i] * sc);
    }
}

// ------ A: v-FFT64 in time domain: preb[b][l][e] -> Xv[b][h][k=0..32][l] -----
__global__ __launch_bounds__(256) void k_vfft(const bf16* __restrict__ preb,
                                              float2* __restrict__ Xv,
                                              const float2* __restrict__ tw) {
    __shared__ float Xre[64 * 66];
    __shared__ float Xim[64 * 66];
    int l0 = blockIdx.x * 64, h = blockIdx.y, b = blockIdx.z;
    int tid = threadIdx.x;
    const bf16* src = preb + ((size_t)(b * L_ + l0)) * E_ + h * 64;
#pragma unroll
    for (int it = 0; it < 2; ++it) {
        int c = tid + it * 256;
        int lc = c >> 3, v8 = (c & 7) * 8;
        bf16x8 xv8 = *(const bf16x8*)(src + (size_t)lc * E_ + v8);
#pragma unroll
        for (int j = 0; j < 8; ++j) {
            Xre[(v8 + j) * 66 + lc] = bfu2f((unsigned short)xv8[j]);
            Xim[(v8 + j) * 66 + lc] = 0.0f;
        }
    }
    fft64_rows<0>(Xre, Xim, tid, tw);
    for (int i = tid; i < 33 * 64; i += 256) {
        int k = i >> 6, lc = i & 63;
        int s = drev64(k);
        Xv[((size_t)(b * H_ + h) * 33 + k) * L_ + l0 + lc] =
            make_float2(Xre[s * 66 + lc], Xim[s * 66 + lc]);
    }
}

// ------ B: fused seq conv per (k,h,b): FFT4096 -> cmul Khat -> IFFT4096 ------
// register radix-16 phases; cmul fused in the middle register session.
__global__ __launch_bounds__(256) void k_seqconv(float2* __restrict__ Xv,
                                                 const float2* __restrict__ Khat,
                                                 const float2* __restrict__ tw) {
    __shared__ float re[LDSN];
    __shared__ float im[LDSN];
    int k = blockIdx.x, h = blockIdx.y, b = blockIdx.z;
    int tid = threadIdx.x, p = tid;
    float2* col = Xv + ((size_t)(b * H_ + h) * 33 + k) * L_;

    float xr[16], xi[16];
#pragma unroll
    for (int j = 0; j < 16; ++j) {
        if (j < 8) {
            float2 z = col[p + 256 * j];
            xr[j] = z.x; xi[j] = z.y;
        } else { xr[j] = 0.0f; xi[j] = 0.0f; }
    }
    fftA_fwd(xr, xi, p, tw);
#pragma unroll
    for (int j = 0; j < 16; ++j) { re[SL(p + 256 * j)] = xr[j]; im[SL(p + 256 * j)] = xi[j]; }
    __syncthreads();
    {
        int bb = tid >> 4, o = tid & 15;
#pragma unroll
        for (int j = 0; j < 16; ++j) {
            int i = bb * 256 + o + 16 * j;
            xr[j] = re[SL(i)]; xi[j] = im[SL(i)];
        }
        fftB_fwd(xr, xi, o, tw);
#pragma unroll
        for (int j = 0; j < 16; ++j) {
            int i = bb * 256 + o + 16 * j;
            re[SL(i)] = xr[j]; im[SL(i)] = xi[j];
        }
    }
    __syncthreads();
    {
#pragma unroll
        for (int j = 0; j < 16; ++j) { xr[j] = re[SL(16 * tid + j)]; xi[j] = im[SL(16 * tid + j)]; }
        fftC_fwd(xr, xi, tw);
        const float2* kh = Khat + ((size_t)h * 64 + k) * NFFT + 16 * tid;
#pragma unroll
        for (int j = 0; j < 16; ++j) {
            float2 kk = kh[j];
            float ar = xr[j], ai = xi[j];
            xr[j] = ar * kk.x - ai * kk.y;
            xi[j] = ar * kk.y + ai * kk.x;
        }
        fftC_inv(xr, xi, tw);
#pragma unroll
        for (int j = 0; j < 16; ++j) { re[SL(16 * tid + j)] = xr[j]; im[SL(16 * tid + j)] = xi[j]; }
    }
    __syncthreads();
    {
        int bb = tid >> 4, o = tid & 15;
#pragma unroll
        for (int j = 0; j < 16; ++j) {
            int i = bb * 256 + o + 16 * j;
            xr[j] = re[SL(i)]; xi[j] = im[SL(i)];
        }
        fftB_inv(xr, xi, o, tw);
#pragma unroll
        for (int j = 0; j < 16; ++j) {
            int i = bb * 256 + o + 16 * j;
            re[SL(i)] = xr[j]; im[SL(i)] = xi[j];
        }
    }
    __syncthreads();
#pragma unroll
    for (int j = 0; j < 16; ++j) { xr[j] = re[SL(p + 256 * j)]; xi[j] = im[SL(p + 256 * j)]; }
    fftA_inv(xr, xi, p, tw);
#pragma unroll
    for (int j = 0; j < 8; ++j)  // only n<2048 needed
        col[p + 256 * j] = make_float2(xr[j], xi[j]);
}

// ------ C: inverse v-FFT64 (Hermitian) + GELU -> actb[b][l][e] bf16 ----------
__global__ __launch_bounds__(256) void k_vifft(const float2* __restrict__ Xv,
                                               bf16* __restrict__ actb,
                                               const float2* __restrict__ tw) {
    __shared__ float Xre[64 * 66];
    __shared__ float Xim[64 * 66];
    int l0 = blockIdx.x * 64, h = blockIdx.y, b = blockIdx.z;
    int tid = threadIdx.x;
    for (int i = tid; i < 33 * 64; i += 256) {
        int k = i >> 6, lc = i & 63;
        float2 z = Xv[((size_t)(b * H_ + h) * 33 + k) * L_ + l0 + lc];
        Xre[k * 66 + lc] = z.x; Xim[k * 66 + lc] = z.y;
    }
    __syncthreads();
    for (int i = tid; i < 31 * 64; i += 256) {
        int k = 33 + (i >> 6), lc = i & 63;
        Xre[k * 66 + lc] =  Xre[(64 - k) * 66 + lc];
        Xim[k * 66 + lc] = -Xim[(64 - k) * 66 + lc];
    }
    fft64_rows<1>(Xre, Xim, tid, tw);
    bf16* dst = actb + ((size_t)(b * L_ + l0)) * E_ + h * 64;
#pragma unroll
    for (int it = 0; it < 2; ++it) {
        int c = tid + it * 256;
        int lc = c >> 3, m8 = (c & 7) * 8;
        unsigned short o[8];
#pragma unroll
        for (int j = 0; j < 8; ++j) {
            float x = Xre[drev64(m8 + j) * 66 + lc];
            float g = 0.5f * x * (1.0f + erff(x * 0.70710678118654752f));
            bf16 bb = __float2bfloat16(g);
            o[j] = *(unsigned short*)&bb;
        }
        *(ushort4*)(dst + (size_t)lc * E_ + m8)     = make_ushort4(o[0], o[1], o[2], o[3]);
        *(ushort4*)(dst + (size_t)lc * E_ + m8 + 4) = make_ushort4(o[4], o[5], o[6], o[7]);
    }
}

// ---------------- sparse seq-mix: build per-row (col,val) lists --------------
__global__ __launch_bounds__(256) void k_sparse_build(const float* __restrict__ Sp,
                                                      int* __restrict__ nnz,
                                                      int* __restrict__ idxs,
                                                      float* __restrict__ vals) {
    __shared__ int cnt;
    int l = blockIdx.x, tid = threadIdx.x;
    if (tid == 0) cnt = 0;
    __syncthreads();
    const float* row = Sp + (size_t)l * L_;
    for (int s = tid; s <= l; s += 256) {
        float v = row[s];
        if (v != 0.0f) {
            int slot = atomicAdd(&cnt, 1);
            if (slot < CAP) { idxs[l * CAP + slot] = s; vals[l * CAP + slot] = v; }
        }
    }
    __syncthreads();
    if (tid == 0) nnz[l] = min(cnt, CAP);
}

// ------- gather-SpMM accumulate: C[b][l][:] += sum_j val_j*P[b][s_j][:] ------
__global__ __launch_bounds__(256) void k_spmm_acc(const int* __restrict__ nnz,
                                                  const int* __restrict__ idxs,
                                                  const float* __restrict__ vals,
                                                  const bf16* __restrict__ P,
                                                  float* __restrict__ C) {
    __shared__ int sidx[CAP];
    __shared__ float sval[CAP];
    int l = blockIdx.x, b = blockIdx.y, tid = threadIdx.x;
    int n = nnz[l];
    for (int j = tid; j < n; j += 256) {
        sidx[j] = idxs[l * CAP + j];
        sval[j] = vals[l * CAP + j];
    }
    __syncthreads();
    const bf16* Pb = P + (size_t)b * L_ * E_;
    size_t off = (size_t)tid * 4;
    float* cp = C + ((size_t)(b * L_ + l)) * E_ + off;
    float4 acc = *(float4*)cp;
    for (int j = 0; j < n; ++j) {
        float v = sval[j];
        ushort4 p = *(const ushort4*)(Pb + (size_t)sidx[j] * E_ + off);
        acc.x += v * bfu2f(p.x); acc.y += v * bfu2f(p.y);
        acc.z += v * bfu2f(p.z); acc.w += v * bfu2f(p.w);
    }
    *(float4*)cp = acc;
}

// ---------------- residual + LayerNorm ---------------------------------------
__global__ __launch_bounds__(256) void k_layernorm(const float* __restrict__ accb,
                                                   const float* __restrict__ emb,
                                                   const float* __restrict__ gamma,
                                                   const float* __restrict__ beta,
                                                   float* __restrict__ outp) {
    __shared__ float xs[E_];
    __shared__ float red[256];
    size_t row = blockIdx.x;
    int tid = threadIdx.x;
    const float* a = accb + row * E_;
    const float* e = emb + row * E_;
    float lsum = 0.0f;
    for (int i = tid; i < E_; i += 256) {
        float x = a[i] + e[i];
        xs[i] = x;
        lsum += x;
    }
    red[tid] = lsum; __syncthreads();
    for (int off = 128; off > 0; off >>= 1) {
        if (tid < off) red[tid] += red[tid + off];
        __syncthreads();
    }
    float mu = red[0] * (1.0f / E_);
    __syncthreads();
    float lv = 0.0f;
    for (int i = tid; i < E_; i += 256) { float d = xs[i] - mu; lv += d * d; }
    red[tid] = lv; __syncthreads();
    for (int off = 128; off > 0; off >>= 1) {
        if (tid < off) red[tid] += red[tid + off];
        __syncthreads();
    }
    float inv = rsqrtf(red[0] * (1.0f / E_) + 1e-12f);
    for (int i = tid; i < E_; i += 256)
        outp[row * E_ + i] = (xs[i] - mu) * inv * gamma[i] + beta[i];
}

extern "C" void kernel_launch(void* const* d_in, const int* in_sizes, int n_in,
                              void* d_out, int out_size, void* d_ws, size_t ws_size,
                              hipStream_t stream) {
    const float* emb    = (const float*)d_in[0];
    const float* W1     = (const float*)d_in[1];
    const float* b1     = (const float*)d_in[2];
    const float* W2     = (const float*)d_in[3];
    const float* b2     = (const float*)d_in[4];
    const float* psfs   = (const float*)d_in[5];
    const float* W3     = (const float*)d_in[6];
    const float* b3     = (const float*)d_in[7];
    const float* sparse = (const float*)d_in[8];
    const float* gamma  = (const float*)d_in[9];
    const float* beta   = (const float*)d_in[10];
    float* outp = (float*)d_out;

    const size_t BLE  = (size_t)B_ * L_ * E_;
    const size_t EE   = (size_t)E_ * E_;
    const size_t XVSZ = (size_t)B_ * H_ * 33 * L_;

    float*  accb       = (float*)d_ws;
    bf16*   pre_sparse = (bf16*)(accb + BLE);
    float2* Khat       = (float2*)(pre_sparse + BLE);
    float2* Xv         = Khat + (size_t)H_ * D_ * NFFT;
    bf16*   preb       = (bf16*)(Xv + XVSZ);
    bf16*   actb       = preb + BLE;
    bf16*   W1b        = actb + BLE;
    bf16*   W2b        = W1b + EE;
    bf16*   W3b        = W2b + EE;
    float2* twd        = (float2*)(W3b + EE);
    // overlays on Xv (dead before k_vfft / after k_vifft):
    float*  psfT       = (float*)Xv;
    int*    s_nnz      = (int*)Xv;
    int*    s_idx      = s_nnz + L_;
    float*  s_val      = (float*)(s_idx + (size_t)L_ * CAP);

    k_twiddle<<<16, 256, 0, stream>>>(twd);
    k_cvt<<<(int)(BLE / 4 / 256), 256, 0, stream>>>(emb, actb, (int)BLE);
    k_cvt<<<(int)(EE / 4 / 256), 256, 0, stream>>>(W1, W1b, (int)EE);
    k_cvt<<<(int)(EE / 4 / 256), 256, 0, stream>>>(W2, W2b, (int)EE);
    k_cvt<<<(int)(EE / 4 / 256), 256, 0, stream>>>(W3, W3b, (int)EE);

    // preb = bf16(emb @ W1^T + b1) ; pre_sparse = bf16(preb @ W2^T + b2)
    k_gemm_mfma<1><<<dim3(E_ / 128, (B_ * L_) / 128), 256, 0, stream>>>(
        actb, W1b, b1, nullptr, preb, B_ * L_, E_, E_);
    k_gemm_mfma<1><<<dim3(E_ / 128, (B_ * L_) / 128), 256, 0, stream>>>(
        preb, W2b, b2, nullptr, pre_sparse, B_ * L_, E_, E_);

    // psfT[h][u][t<2048] = psfs[h][t][u]
    k_tf32<<<dim3(1, L_ / 64, H_), 256, 0, stream>>>(
        psfs, psfT, L_, D_, (long)(2 * L_ - 1) * D_, (long)D_ * L_);

    // PSF softmax + full K4096 + fwd seq-FFT; d-FFT of kernel spectrum
    k_build_khat<<<dim3(D_, H_), 256, 0, stream>>>(psfT, Khat, twd);
    k_khat_dfft<<<dim3(NFFT / 64, H_), 256, 0, stream>>>(Khat, twd);

    // conv: v-FFT -> fused per-(k,h,b) seq conv (in place) -> inverse v-FFT
    k_vfft<<<dim3(L_ / 64, H_, B_), 256, 0, stream>>>(preb, Xv, twd);
    k_seqconv<<<dim3(33, H_, B_), 256, 0, stream>>>(Xv, Khat, twd);
    k_vifft<<<dim3(L_ / 64, H_, B_), 256, 0, stream>>>(Xv, actb, twd);

    // accb = conv @ W3^T + b3 (fp32)
    k_gemm_mfma<0><<<dim3(E_ / 128, (B_ * L_) / 128), 256, 0, stream>>>(
        actb, W3b, b3, accb, nullptr, B_ * L_, E_, E_);

    // accb += tril(sparse) @ pre_sparse
    k_sparse_build<<<L_, 256, 0, stream>>>(sparse, s_nnz, s_idx, s_val);
    k_spmm_acc<<<dim3(L_, B_), 256, 0, stream>>>(s_nnz, s_idx, s_val, pre_sparse, accb);

    // out = LayerNorm(accb + emb) * gamma + beta
    k_layernorm<<<B_ * L_, 256, 0, stream>>>(accb, emb, gamma, beta, outp);
}

// Round 10
// 252.108 us; speedup vs baseline: 12.4497x; 1.1921x over previous
//
#include <hip/hip_runtime.h>
#include <hip/hip_bf16.h>
#include <hip/hip_fp16.h>
#include <math.h>

#define B_ 4
#define L_ 2048
#define E_ 1024
#define H_ 16
#define D_ 64
#define NFFT 4096
#define CAP 128

typedef __hip_bfloat16 bf16;
typedef __attribute__((ext_vector_type(8))) short bf16x8;
typedef __attribute__((ext_vector_type(4))) float f32x4;
typedef __attribute__((ext_vector_type(2))) __fp16 f16x2;

typedef __attribute__((address_space(1))) const unsigned int gas_u32;
typedef __attribute__((address_space(3))) unsigned int las_u32;

__device__ __forceinline__ void gload_lds16(const void* g, void* l) {
    __builtin_amdgcn_global_load_lds((gas_u32*)g, (las_u32*)l, 16, 0, 0);
}

// padded LDS slot: +1 per 16 (<=2-way conflicts for all 3 phase patterns)
#define SL(i) ((i) + ((i) >> 4))
#define LDSN (NFFT + NFFT / 16)   // 4352

__device__ __forceinline__ float bfu2f(unsigned short u) {
    return __uint_as_float(((unsigned)u) << 16);
}
__device__ __forceinline__ f16x2 pk2(float a, float b) {
    return __builtin_amdgcn_cvt_pkrtz(a, b);
}

// base-4 3-digit reversal (involution)
__device__ __forceinline__ int drev64(int k) {
    return ((k & 3) << 4) | (k & 12) | ((k >> 4) & 3);
}

// ---------------- twiddle table: tw[k] = exp(-2*pi*i*k/4096) -----------------
__global__ __launch_bounds__(256) void k_twiddle(float2* __restrict__ tw) {
    int k = blockIdx.x * 256 + threadIdx.x;
    if (k < NFFT) {
        float ang = -(float)k * (float)(M_PI / 2048.0);
        tw[k] = make_float2(cosf(ang), sinf(ang));
    }
}

// ---------------- register radix-4 butterflies -------------------------------
__device__ __forceinline__ void r4dif(float& x0r, float& x0i, float& x1r, float& x1i,
                                      float& x2r, float& x2i, float& x3r, float& x3i,
                                      int e, const float2* __restrict__ tw) {
    float a0r = x0r + x2r, a0i = x0i + x2i, a1r = x0r - x2r, a1i = x0i - x2i;
    float a2r = x1r + x3r, a2i = x1i + x3i, a3r = x1r - x3r, a3i = x1i - x3i;
    float y0r = a0r + a2r, y0i = a0i + a2i, y2r = a0r - a2r, y2i = a0i - a2i;
    float y1r = a1r + a3i, y1i = a1i - a3r, y3r = a1r - a3i, y3i = a1i + a3r;
    float2 w1 = tw[e], w2 = tw[2 * e], w3 = tw[3 * e];
    x0r = y0r; x0i = y0i;
    x1r = y1r * w1.x - y1i * w1.y; x1i = y1r * w1.y + y1i * w1.x;
    x2r = y2r * w2.x - y2i * w2.y; x2i = y2r * w2.y + y2i * w2.x;
    x3r = y3r * w3.x - y3i * w3.y; x3i = y3r * w3.y + y3i * w3.x;
}
__device__ __forceinline__ void r4dif_nt(float& x0r, float& x0i, float& x1r, float& x1i,
                                         float& x2r, float& x2i, float& x3r, float& x3i) {
    float a0r = x0r + x2r, a0i = x0i + x2i, a1r = x0r - x2r, a1i = x0i - x2i;
    float a2r = x1r + x3r, a2i = x1i + x3i, a3r = x1r - x3r, a3i = x1i - x3i;
    x0r = a0r + a2r; x0i = a0i + a2i;
    x2r = a0r - a2r; x2i = a0i - a2i;
    float y1r = a1r + a3i, y1i = a1i - a3r, y3r = a1r - a3i, y3i = a1i + a3r;
    x1r = y1r; x1i = y1i; x3r = y3r; x3i = y3i;
}
__device__ __forceinline__ void r4dit(float& x0r, float& x0i, float& x1r, float& x1i,
                                      float& x2r, float& x2i, float& x3r, float& x3i,
                                      int e, const float2* __restrict__ tw) {
    float2 w1 = tw[e], w2 = tw[2 * e], w3 = tw[3 * e];
    float z1r = x1r * w1.x + x1i * w1.y, z1i = x1i * w1.x - x1r * w1.y;
    float z2r = x2r * w2.x + x2i * w2.y, z2i = x2i * w2.x - x2r * w2.y;
    float z3r = x3r * w3.x + x3i * w3.y, z3i = x3i * w3.x - x3r * w3.y;
    float b0r = x0r + z2r, b0i = x0i + z2i, b1r = x0r - z2r, b1i = x0i - z2i;
    float b2r = z1r + z3r, b2i = z1i + z3i, b3r = z1r - z3r, b3i = z1i - z3i;
    x0r = b0r + b2r; x0i = b0i + b2i;
    x2r = b0r - b2r; x2i = b0i - b2i;
    x1r = b1r - b3i; x1i = b1i + b3r;
    x3r = b1r + b3i; x3i = b1i - b3r;
}
__device__ __forceinline__ void r4dit_nt(float& x0r, float& x0i, float& x1r, float& x1i,
                                         float& x2r, float& x2i, float& x3r, float& x3i) {
    float b0r = x0r + x2r, b0i = x0i + x2i, b1r = x0r - x2r, b1i = x0i - x2i;
    float b2r = x1r + x3r, b2i = x1i + x3i, b3r = x1r - x3r, b3i = x1i - x3i;
    x0r = b0r + b2r; x0i = b0i + b2i;
    x2r = b0r - b2r; x2i = b0i - b2i;
    x1r = b1r - b3i; x1i = b1i + b3r;
    x3r = b1r + b3i; x3i = b1i - b3r;
}

// ---- phase A (stages 0,1): thread p owns X[j]=a[p+256j] ---------------------
__device__ __forceinline__ void fftA_fwd(float* xr, float* xi, int p, const float2* __restrict__ tw) {
#pragma unroll
    for (int j0 = 0; j0 < 4; ++j0)
        r4dif(xr[j0], xi[j0], xr[j0 + 4], xi[j0 + 4], xr[j0 + 8], xi[j0 + 8],
              xr[j0 + 12], xi[j0 + 12], p + 256 * j0, tw);
#pragma unroll
    for (int g = 0; g < 4; ++g)
        r4dif(xr[4 * g], xi[4 * g], xr[4 * g + 1], xi[4 * g + 1], xr[4 * g + 2],
              xi[4 * g + 2], xr[4 * g + 3], xi[4 * g + 3], p << 2, tw);
}
__device__ __forceinline__ void fftA_inv(float* xr, float* xi, int p, const float2* __restrict__ tw) {
#pragma unroll
    for (int g = 0; g < 4; ++g)
        r4dit(xr[4 * g], xi[4 * g], xr[4 * g + 1], xi[4 * g + 1], xr[4 * g + 2],
              xi[4 * g + 2], xr[4 * g + 3], xi[4 * g + 3], p << 2, tw);
#pragma unroll
    for (int j0 = 0; j0 < 4; ++j0)
        r4dit(xr[j0], xi[j0], xr[j0 + 4], xi[j0 + 4], xr[j0 + 8], xi[j0 + 8],
              xr[j0 + 12], xi[j0 + 12], p + 256 * j0, tw);
}
// ---- phase B (stages 2,3): thread (b,o) owns X[j]=a[b*256+o+16j] ------------
__device__ __forceinline__ void fftB_fwd(float* xr, float* xi, int o, const float2* __restrict__ tw) {
#pragma unroll
    for (int j0 = 0; j0 < 4; ++j0)
        r4dif(xr[j0], xi[j0], xr[j0 + 4], xi[j0 + 4], xr[j0 + 8], xi[j0 + 8],
              xr[j0 + 12], xi[j0 + 12], (o + 16 * j0) << 4, tw);
#pragma unroll
    for (int g = 0; g < 4; ++g)
        r4dif(xr[4 * g], xi[4 * g], xr[4 * g + 1], xi[4 * g + 1], xr[4 * g + 2],
              xi[4 * g + 2], xr[4 * g + 3], xi[4 * g + 3], o << 6, tw);
}
__device__ __forceinline__ void fftB_inv(float* xr, float* xi, int o, const float2* __restrict__ tw) {
#pragma unroll
    for (int g = 0; g < 4; ++g)
        r4dit(xr[4 * g], xi[4 * g], xr[4 * g + 1], xi[4 * g + 1], xr[4 * g + 2],
              xi[4 * g + 2], xr[4 * g + 3], xi[4 * g + 3], o << 6, tw);
#pragma unroll
    for (int j0 = 0; j0 < 4; ++j0)
        r4dit(xr[j0], xi[j0], xr[j0 + 4], xi[j0 + 4], xr[j0 + 8], xi[j0 + 8],
              xr[j0 + 12], xi[j0 + 12], (o + 16 * j0) << 4, tw);
}
// ---- phase C (stages 4,5): thread t owns X[j]=a[16t+j] ----------------------
__device__ __forceinline__ void fftC_fwd(float* xr, float* xi, const float2* __restrict__ tw) {
#pragma unroll
    for (int j0 = 0; j0 < 4; ++j0)
        r4dif(xr[j0], xi[j0], xr[j0 + 4], xi[j0 + 4], xr[j0 + 8], xi[j0 + 8],
              xr[j0 + 12], xi[j0 + 12], j0 << 8, tw);
#pragma unroll
    for (int g = 0; g < 4; ++g)
        r4dif_nt(xr[4 * g], xi[4 * g], xr[4 * g + 1], xi[4 * g + 1], xr[4 * g + 2],
                 xi[4 * g + 2], xr[4 * g + 3], xi[4 * g + 3]);
}
__device__ __forceinline__ void fftC_inv(float* xr, float* xi, const float2* __restrict__ tw) {
#pragma unroll
    for (int g = 0; g < 4; ++g)
        r4dit_nt(xr[4 * g], xi[4 * g], xr[4 * g + 1], xi[4 * g + 1], xr[4 * g + 2],
                 xi[4 * g + 2], xr[4 * g + 3], xi[4 * g + 3]);
#pragma unroll
    for (int j0 = 0; j0 < 4; ++j0)
        r4dit(xr[j0], xi[j0], xr[j0 + 4], xi[j0 + 4], xr[j0 + 8], xi[j0 + 8],
              xr[j0 + 12], xi[j0 + 12], j0 << 8, tw);
}

// ---- batched 64-pt radix-4 over rows, LDS layout idx = row*66 + col ---------
template <int CONJ>
__device__ inline void fft64_rows(float* xr, float* xi, int tid,
                                  const float2* __restrict__ tw) {
    for (int st = 0; st < 3; ++st) {
        int q = 1 << (4 - 2 * st);
        __syncthreads();
        for (int it = 0; it < 4; ++it) {
            int w = tid + (it << 8);
            int lc = w & 63, bc = w >> 6;
            int p = bc & (q - 1);
            int basev = ((bc & ~(q - 1)) << 2) | p;
            int i0 = basev * 66 + lc, i1 = i0 + q * 66, i2 = i1 + q * 66, i3 = i2 + q * 66;
            float x0r = xr[i0], x0i = xi[i0], x1r = xr[i1], x1i = xi[i1];
            float x2r = xr[i2], x2i = xi[i2], x3r = xr[i3], x3i = xi[i3];
            float a0r = x0r + x2r, a0i = x0i + x2i;
            float a1r = x0r - x2r, a1i = x0i - x2i;
            float a2r = x1r + x3r, a2i = x1i + x3i;
            float a3r = x1r - x3r, a3i = x1i - x3i;
            float y0r = a0r + a2r, y0i = a0i + a2i;
            float y2r = a0r - a2r, y2i = a0i - a2i;
            float y1r, y1i, y3r, y3i;
            if (!CONJ) {
                y1r = a1r + a3i; y1i = a1i - a3r;
                y3r = a1r - a3i; y3i = a1i + a3r;
            } else {
                y1r = a1r - a3i; y1i = a1i + a3r;
                y3r = a1r + a3i; y3i = a1i - a3r;
            }
            int e = (p << (2 * st)) * 64;
            float2 w1 = tw[e], w2 = tw[2 * e], w3 = tw[3 * e];
            float w1y = CONJ ? -w1.y : w1.y;
            float w2y = CONJ ? -w2.y : w2.y;
            float w3y = CONJ ? -w3.y : w3.y;
            xr[i0] = y0r; xi[i0] = y0i;
            xr[i1] = y1r * w1.x - y1i * w1y; xi[i1] = y1r * w1y + y1i * w1.x;
            xr[i2] = y2r * w2.x - y2i * w2y; xi[i2] = y2r * w2y + y2i * w2.x;
            xr[i3] = y3r * w3.x - y3i * w3y; xi[i3] = y3r * w3y + y3i * w3.x;
        }
    }
    __syncthreads();
}

// ------- batched 64-pt radix-4 FFT over rows in [row*64+col] layout ----------
__device__ inline void fft64_b(float* xr, float* xi, int tid,
                               const float2* __restrict__ tw) {
    for (int st = 0; st < 3; ++st) {
        int q = 1 << (4 - 2 * st);
        __syncthreads();
        for (int it = 0; it < 4; ++it) {
            int b = tid + (it << 8);
            int fc = b & 63;
            int bc = b >> 6;
            int p = bc & (q - 1);
            int basev = ((bc & ~(q - 1)) << 2) | p;
            int i0 = basev * 64 + fc, i1 = i0 + q * 64, i2 = i1 + q * 64, i3 = i2 + q * 64;
            float x0r = xr[i0], x0i = xi[i0], x1r = xr[i1], x1i = xi[i1];
            float x2r = xr[i2], x2i = xi[i2], x3r = xr[i3], x3i = xi[i3];
            float a0r = x0r + x2r, a0i = x0i + x2i;
            float a1r = x0r - x2r, a1i = x0i - x2i;
            float a2r = x1r + x3r, a2i = x1i + x3i;
            float a3r = x1r - x3r, a3i = x1i - x3i;
            float y0r = a0r + a2r, y0i = a0i + a2i;
            float y2r = a0r - a2r, y2i = a0i - a2i;
            float y1r = a1r + a3i, y1i = a1i - a3r;
            float y3r = a1r - a3i, y3i = a1i + a3r;
            int e = (p << (2 * st)) * 64;
            float2 w1 = tw[e], w2 = tw[2 * e], w3 = tw[3 * e];
            xr[i0] = y0r; xi[i0] = y0i;
            xr[i1] = y1r * w1.x - y1i * w1.y; xi[i1] = y1r * w1.y + y1i * w1.x;
            xr[i2] = y2r * w2.x - y2i * w2.y; xi[i2] = y2r * w2.y + y2i * w2.x;
            xr[i3] = y3r * w3.x - y3i * w3.y; xi[i3] = y3r * w3.y + y3i * w3.x;
        }
    }
    __syncthreads();
}

// ---------------- fp32 -> bf16 convert (vectorized) --------------------------
__global__ __launch_bounds__(256) void k_cvt(const float* __restrict__ in,
                                             bf16* __restrict__ out, int n) {
    int i = (blockIdx.x * 256 + threadIdx.x) * 4;
    if (i >= n) return;
    float4 v = *(const float4*)(in + i);
    bf16 tmp[4];
    tmp[0] = __float2bfloat16(v.x);
    tmp[1] = __float2bfloat16(v.y);
    tmp[2] = __float2bfloat16(v.z);
    tmp[3] = __float2bfloat16(v.w);
    *(ushort4*)(out + i) = *(ushort4*)tmp;
}

// ---------------- 3 weight converts in one dispatch --------------------------
__global__ __launch_bounds__(256) void k_cvtw(const float* __restrict__ W1,
                                              const float* __restrict__ W2,
                                              const float* __restrict__ W3,
                                              bf16* __restrict__ dst, int n) {
    const float* src = (blockIdx.y == 0) ? W1 : (blockIdx.y == 1) ? W2 : W3;
    int i = (blockIdx.x * 256 + threadIdx.x) * 4;
    if (i >= n) return;
    float4 v = *(const float4*)(src + i);
    bf16* out = dst + (size_t)blockIdx.y * n + i;
    bf16 tmp[4];
    tmp[0] = __float2bfloat16(v.x);
    tmp[1] = __float2bfloat16(v.y);
    tmp[2] = __float2bfloat16(v.z);
    tmp[3] = __float2bfloat16(v.w);
    *(ushort4*)out = *(ushort4*)tmp;
}

// ---------------- fp32 transpose: out[c*R+r] = in[r*C+c], 64x64 tiles --------
__global__ __launch_bounds__(256) void k_tf32(const float* __restrict__ in,
                                              float* __restrict__ out,
                                              int R, int C, long inB, long outB) {
    __shared__ float tile[64][65];
    in += (size_t)blockIdx.z * inB;
    out += (size_t)blockIdx.z * outB;
    int r0 = blockIdx.y * 64, c0 = blockIdx.x * 64;
    int t = threadIdx.x;
    int tx4 = (t & 15) * 4, ty = t >> 4;
#pragma unroll
    for (int k = 0; k < 4; ++k) {
        int r = ty + 16 * k;
        float4 v = *(const float4*)&in[(size_t)(r0 + r) * C + c0 + tx4];
        tile[r][tx4 + 0] = v.x; tile[r][tx4 + 1] = v.y;
        tile[r][tx4 + 2] = v.z; tile[r][tx4 + 3] = v.w;
    }
    __syncthreads();
#pragma unroll
    for (int k = 0; k < 4; ++k) {
        int c = ty + 16 * k;
        float4 w;
        w.x = tile[tx4 + 0][c]; w.y = tile[tx4 + 1][c];
        w.z = tile[tx4 + 2][c]; w.w = tile[tx4 + 3][c];
        *(float4*)&out[(size_t)(c0 + c) * R + r0 + tx4] = w;
    }
}

// ------ bf16 MFMA GEMM, BK=64, XOR-swizzled LDS, XCD-chunked block swizzle ---
template <int OUTB>
__global__ __launch_bounds__(256) void k_gemm_mfma(const bf16* __restrict__ A,
                                                   const bf16* __restrict__ Wt,
                                                   const float* __restrict__ bias,
                                                   float* __restrict__ C,
                                                   bf16* __restrict__ Cb,
                                                   int M, int N, int K) {
    __shared__ bf16 As[128 * 64];
    __shared__ bf16 Bs[128 * 64];
    int tid = threadIdx.x;
    int lane = tid & 63, w = tid >> 6;
    int wr = w >> 1, wc = w & 1;

    int nwg = gridDim.x * gridDim.y;
    int flat = blockIdx.y * gridDim.x + blockIdx.x;
    int cpx = nwg >> 3;
    int swz = (flat & 7) * cpx + (flat >> 3);
    int bx = (swz % gridDim.x) * 128;
    int by = (swz / gridDim.x) * 128;

    f32x4 zz = {0.0f, 0.0f, 0.0f, 0.0f};
    f32x4 acc[4][4];
#pragma unroll
    for (int m = 0; m < 4; ++m)
#pragma unroll
        for (int n = 0; n < 4; ++n) acc[m][n] = zz;

    int koff = (lane >> 4) * 8;
    int rsub = lane & 15;

    for (int k0 = 0; k0 < K; k0 += 64) {
#pragma unroll
        for (int i = 0; i < 4; ++i) {
            int c = tid + i * 256;
            int row = c >> 3;
            int kb = (c & 7) * 8;
            int kbs = kb ^ ((row & 7) << 3);
            gload_lds16(A + (size_t)(by + row) * K + k0 + kbs, &As[c * 8]);
            gload_lds16(Wt + (size_t)(bx + row) * K + k0 + kbs, &Bs[c * 8]);
        }
        __syncthreads();
#pragma unroll
        for (int half = 0; half < 2; ++half) {
            int ko = koff + half * 32;
            bf16x8 af[4], bfv[4];
#pragma unroll
            for (int m = 0; m < 4; ++m) {
                int R = wr * 64 + m * 16 + rsub;
                af[m] = *(const bf16x8*)&As[R * 64 + (ko ^ ((R & 7) << 3))];
            }
#pragma unroll
            for (int n = 0; n < 4; ++n) {
                int R = wc * 64 + n * 16 + rsub;
                bfv[n] = *(const bf16x8*)&Bs[R * 64 + (ko ^ ((R & 7) << 3))];
            }
#pragma unroll
            for (int m = 0; m < 4; ++m)
#pragma unroll
                for (int n = 0; n < 4; ++n)
                    acc[m][n] = __builtin_amdgcn_mfma_f32_16x16x32_bf16(af[m], bfv[n], acc[m][n], 0, 0, 0);
        }
        __syncthreads();
    }

    int cq = (lane >> 4) * 4;
    int cr = lane & 15;
#pragma unroll
    for (int m = 0; m < 4; ++m) {
        int row0 = by + wr * 64 + m * 16 + cq;
#pragma unroll
        for (int n = 0; n < 4; ++n) {
            int col = bx + wc * 64 + n * 16 + cr;
            float bv = bias[col];
#pragma unroll
            for (int j = 0; j < 4; ++j) {
                float v = acc[m][n][j] + bv;
                if constexpr (OUTB)
                    Cb[(size_t)(row0 + j) * N + col] = __float2bfloat16(v);
                else
                    C[(size_t)(row0 + j) * N + col] = v;
            }
        }
    }
}

// -------- PSF softmax + FULL K4096 (causal + uniform anticausal) + fwd FFT ---
__global__ __launch_bounds__(256) void k_build_khat(const float* __restrict__ psfT,
                                                    f16x2* __restrict__ Khat,
                                                    const float2* __restrict__ tw) {
    __shared__ f16x2 fl[LDSN];
    __shared__ float red[256];
    int u = blockIdx.x, h = blockIdx.y, tid = threadIdx.x;
    const float* col = psfT + ((size_t)(h * D_ + u)) * L_;
    int p = tid;

    float v[8];
#pragma unroll
    for (int j = 0; j < 8; ++j) v[j] = col[p + 256 * j];

    float lm = v[0];
#pragma unroll
    for (int j = 1; j < 8; ++j) lm = fmaxf(lm, v[j]);
    red[tid] = lm; __syncthreads();
    for (int off = 128; off > 0; off >>= 1) {
        if (tid < off) red[tid] = fmaxf(red[tid], red[tid + off]);
        __syncthreads();
    }
    float M = fmaxf(red[0], 0.0f);
    __syncthreads();

    float e[8];
    float ls = 0.0f;
#pragma unroll
    for (int j = 0; j < 8; ++j) { e[j] = expf(v[j] - M); ls += e[j]; }
    red[tid] = ls; __syncthreads();
    for (int off = 128; off > 0; off >>= 1) {
        if (tid < off) red[tid] += red[tid + off];
        __syncthreads();
    }
    float Z = red[0] + (float)(L_ - 1) * expf(-M);
    float invZ = 1.0f / Z;
    float cval = expf(-M) * invZ;

    float xr[16], xi[16];
#pragma unroll
    for (int j = 0; j < 16; ++j) {
        int i = p + 256 * j;
        xr[j] = (j < 8) ? e[j] * invZ : ((i == 2048) ? 0.0f : cval);
        xi[j] = 0.0f;
    }
    __syncthreads();

    fftA_fwd(xr, xi, p, tw);
#pragma unroll
    for (int j = 0; j < 16; ++j) fl[SL(p + 256 * j)] = pk2(xr[j], xi[j]);
    __syncthreads();
    {
        int bb = tid >> 4, o = tid & 15;
#pragma unroll
        for (int j = 0; j < 16; ++j) {
            f16x2 hh = fl[SL(bb * 256 + o + 16 * j)];
            xr[j] = (float)hh.x; xi[j] = (float)hh.y;
        }
        fftB_fwd(xr, xi, o, tw);
#pragma unroll
        for (int j = 0; j < 16; ++j)
            fl[SL(bb * 256 + o + 16 * j)] = pk2(xr[j], xi[j]);
    }
    __syncthreads();
#pragma unroll
    for (int j = 0; j < 16; ++j) {
        f16x2 hh = fl[SL(16 * tid + j)];
        xr[j] = (float)hh.x; xi[j] = (float)hh.y;
    }
    fftC_fwd(xr, xi, tw);

    float sc = 1.0f / (float)NFFT;
    f16x2* outp = Khat + ((size_t)h * D_ + u) * NFFT + 16 * tid;
#pragma unroll
    for (int j = 0; j < 16; ++j) outp[j] = pk2(xr[j] * sc, xi[j] * sc);
}

// --- in-place FFT64 over u of Khat (natural-k order out, +1/64 scale) --------
__global__ __launch_bounds__(256) void k_khat_dfft(f16x2* __restrict__ Khat,
                                                   const float2* __restrict__ tw) {
    __shared__ float Xre[4096];
    __shared__ float Xim[4096];
    int f0 = blockIdx.x * 64, h = blockIdx.y, tid = threadIdx.x;
    f16x2* kb = Khat + (size_t)h * D_ * NFFT;
    for (int i = tid; i < 4096; i += 256) {
        int uu = i >> 6, fc = i & 63;
        f16x2 v = kb[(size_t)uu * NFFT + f0 + fc];
        Xre[i] = (float)v.x; Xim[i] = (float)v.y;
    }
    fft64_b(Xre, Xim, tid, tw);
    float sc = 1.0f / 64.0f;
    for (int i = tid; i < 4096; i += 256) {
        int s = i >> 6, fc = i & 63;
        kb[(size_t)drev64(s) * NFFT + f0 + fc] = pk2(Xre[i] * sc, Xim[i] * sc);
    }
}

// ------ A: v-FFT64 in time domain: preb[b][l][e] -> Xv[b][h][k=0..32][l] -----
__global__ __launch_bounds__(256) void k_vfft(const bf16* __restrict__ preb,
                                              f16x2* __restrict__ Xv,
                                              const float2* __restrict__ tw) {
    __shared__ float Xre[64 * 66];
    __shared__ float Xim[64 * 66];
    int l0 = blockIdx.x * 64, h = blockIdx.y, b = blockIdx.z;
    int tid = threadIdx.x;
    const bf16* src = preb + ((size_t)(b * L_ + l0)) * E_ + h * 64;
#pragma unroll
    for (int it = 0; it < 2; ++it) {
        int c = tid + it * 256;
        int lc = c >> 3, v8 = (c & 7) * 8;
        bf16x8 xv8 = *(const bf16x8*)(src + (size_t)lc * E_ + v8);
#pragma unroll
        for (int j = 0; j < 8; ++j) {
            Xre[(v8 + j) * 66 + lc] = bfu2f((unsigned short)xv8[j]);
            Xim[(v8 + j) * 66 + lc] = 0.0f;
        }
    }
    fft64_rows<0>(Xre, Xim, tid, tw);
    for (int i = tid; i < 33 * 64; i += 256) {
        int k = i >> 6, lc = i & 63;
        int s = drev64(k);
        Xv[((size_t)(b * H_ + h) * 33 + k) * L_ + l0 + lc] =
            pk2(Xre[s * 66 + lc], Xim[s * 66 + lc]);
    }
}

// ------ B: fused seq conv per (k,h,b): FFT4096 -> cmul Khat -> IFFT4096 ------
__global__ __launch_bounds__(256) void k_seqconv(f16x2* __restrict__ Xv,
                                                 const f16x2* __restrict__ Khat,
                                                 const float2* __restrict__ tw) {
    __shared__ f16x2 fl[LDSN];
    int k = blockIdx.x, h = blockIdx.y, b = blockIdx.z;
    int tid = threadIdx.x, p = tid;
    f16x2* col = Xv + ((size_t)(b * H_ + h) * 33 + k) * L_;

    // prefetch Khat for this column (independent of everything else)
    const f16x2* khp = Khat + ((size_t)h * 64 + k) * NFFT + 16 * tid;
    f16x2 kk[16];
#pragma unroll
    for (int j = 0; j < 16; ++j) kk[j] = khp[j];

    float xr[16], xi[16];
#pragma unroll
    for (int j = 0; j < 16; ++j) {
        if (j < 8) {
            f16x2 z = col[p + 256 * j];
            xr[j] = (float)z.x; xi[j] = (float)z.y;
        } else { xr[j] = 0.0f; xi[j] = 0.0f; }
    }
    fftA_fwd(xr, xi, p, tw);
#pragma unroll
    for (int j = 0; j < 16; ++j) fl[SL(p + 256 * j)] = pk2(xr[j], xi[j]);
    __syncthreads();
    {
        int bb = tid >> 4, o = tid & 15;
#pragma unroll
        for (int j = 0; j < 16; ++j) {
            f16x2 hh = fl[SL(bb * 256 + o + 16 * j)];
            xr[j] = (float)hh.x; xi[j] = (float)hh.y;
        }
        fftB_fwd(xr, xi, o, tw);
#pragma unroll
        for (int j = 0; j < 16; ++j)
            fl[SL(bb * 256 + o + 16 * j)] = pk2(xr[j], xi[j]);
    }
    __syncthreads();
    {
#pragma unroll
        for (int j = 0; j < 16; ++j) {
            f16x2 hh = fl[SL(16 * tid + j)];
            xr[j] = (float)hh.x; xi[j] = (float)hh.y;
        }
        fftC_fwd(xr, xi, tw);
#pragma unroll
        for (int j = 0; j < 16; ++j) {
            float kr = (float)kk[j].x, ki = (float)kk[j].y;
            float ar = xr[j], ai = xi[j];
            xr[j] = ar * kr - ai * ki;
            xi[j] = ar * ki + ai * kr;
        }
        fftC_inv(xr, xi, tw);
#pragma unroll
        for (int j = 0; j < 16; ++j) fl[SL(16 * tid + j)] = pk2(xr[j], xi[j]);
    }
    __syncthreads();
    {
        int bb = tid >> 4, o = tid & 15;
#pragma unroll
        for (int j = 0; j < 16; ++j) {
            f16x2 hh = fl[SL(bb * 256 + o + 16 * j)];
            xr[j] = (float)hh.x; xi[j] = (float)hh.y;
        }
        fftB_inv(xr, xi, o, tw);
#pragma unroll
        for (int j = 0; j < 16; ++j)
            fl[SL(bb * 256 + o + 16 * j)] = pk2(xr[j], xi[j]);
    }
    __syncthreads();
#pragma unroll
    for (int j = 0; j < 16; ++j) {
        f16x2 hh = fl[SL(p + 256 * j)];
        xr[j] = (float)hh.x; xi[j] = (float)hh.y;
    }
    fftA_inv(xr, xi, p, tw);
#pragma unroll
    for (int j = 0; j < 8; ++j)  // only n<2048 needed
        col[p + 256 * j] = pk2(xr[j], xi[j]);
}

// ------ C: inverse v-FFT64 (Hermitian) + GELU -> actb[b][l][e] bf16 ----------
__global__ __launch_bounds__(256) void k_vifft(const f16x2* __restrict__ Xv,
                                               bf16* __restrict__ actb,
                                               const float2* __restrict__ tw) {
    __shared__ float Xre[64 * 66];
    __shared__ float Xim[64 * 66];
    int l0 = blockIdx.x * 64, h = blockIdx.y, b = blockIdx.z;
    int tid = threadIdx.x;
    for (int i = tid; i < 33 * 64; i += 256) {
        int k = i >> 6, lc = i & 63;
        f16x2 z = Xv[((size_t)(b * H_ + h) * 33 + k) * L_ + l0 + lc];
        Xre[k * 66 + lc] = (float)z.x; Xim[k * 66 + lc] = (float)z.y;
    }
    __syncthreads();
    for (int i = tid; i < 31 * 64; i += 256) {
        int k = 33 + (i >> 6), lc = i & 63;
        Xre[k * 66 + lc] =  Xre[(64 - k) * 66 + lc];
        Xim[k * 66 + lc] = -Xim[(64 - k) * 66 + lc];
    }
    fft64_rows<1>(Xre, Xim, tid, tw);
    bf16* dst = actb + ((size_t)(b * L_ + l0)) * E_ + h * 64;
#pragma unroll
    for (int it = 0; it < 2; ++it) {
        int c = tid + it * 256;
        int lc = c >> 3, m8 = (c & 7) * 8;
        unsigned short o[8];
#pragma unroll
        for (int j = 0; j < 8; ++j) {
            float x = Xre[drev64(m8 + j) * 66 + lc];
            float g = 0.5f * x * (1.0f + erff(x * 0.70710678118654752f));
            bf16 bb = __float2bfloat16(g);
            o[j] = *(unsigned short*)&bb;
        }
        *(ushort4*)(dst + (size_t)lc * E_ + m8)     = make_ushort4(o[0], o[1], o[2], o[3]);
        *(ushort4*)(dst + (size_t)lc * E_ + m8 + 4) = make_ushort4(o[4], o[5], o[6], o[7]);
    }
}

// ---------------- sparse seq-mix: build per-row (col,val) lists --------------
__global__ __launch_bounds__(256) void k_sparse_build(const float* __restrict__ Sp,
                                                      int* __restrict__ nnz,
                                                      int* __restrict__ idxs,
                                                      float* __restrict__ vals) {
    __shared__ int cnt;
    int l = blockIdx.x, tid = threadIdx.x;
    if (tid == 0) cnt = 0;
    __syncthreads();
    const float* row = Sp + (size_t)l * L_;
    for (int s = tid; s <= l; s += 256) {
        float v = row[s];
        if (v != 0.0f) {
            int slot = atomicAdd(&cnt, 1);
            if (slot < CAP) { idxs[l * CAP + slot] = s; vals[l * CAP + slot] = v; }
        }
    }
    __syncthreads();
    if (tid == 0) nnz[l] = min(cnt, CAP);
}

// -- fused: row = accbb(bf16) + sparse gather + emb; LayerNorm -> outp (fp32) --
__global__ __launch_bounds__(256) void k_spmm_ln(const int* __restrict__ nnz,
                                                 const int* __restrict__ idxs,
                                                 const float* __restrict__ vals,
                                                 const bf16* __restrict__ P,
                                                 const bf16* __restrict__ accbb,
                                                 const float* __restrict__ emb,
                                                 const float* __restrict__ gamma,
                                                 const float* __restrict__ beta,
                                                 float* __restrict__ outp) {
    __shared__ int sidx[CAP];
    __shared__ float sval[CAP];
    __shared__ float red[256];
    int l = blockIdx.x, b = blockIdx.y, tid = threadIdx.x;
    int n = nnz[l];
    for (int j = tid; j < n; j += 256) {
        sidx[j] = idxs[l * CAP + j];
        sval[j] = vals[l * CAP + j];
    }
    __syncthreads();
    size_t off = (size_t)tid * 4;
    size_t rowbase = ((size_t)(b * L_ + l)) * E_;
    ushort4 a4 = *(const ushort4*)(accbb + rowbase + off);
    float4 e4 = *(const float4*)(emb + rowbase + off);
    float x0 = bfu2f(a4.x) + e4.x;
    float x1 = bfu2f(a4.y) + e4.y;
    float x2 = bfu2f(a4.z) + e4.z;
    float x3 = bfu2f(a4.w) + e4.w;
    const bf16* Pb = P + (size_t)b * L_ * E_;
    for (int j = 0; j < n; ++j) {
        float v = sval[j];
        ushort4 p = *(const ushort4*)(Pb + (size_t)sidx[j] * E_ + off);
        x0 += v * bfu2f(p.x); x1 += v * bfu2f(p.y);
        x2 += v * bfu2f(p.z); x3 += v * bfu2f(p.w);
    }
    // mean
    red[tid] = x0 + x1 + x2 + x3; __syncthreads();
    for (int o2 = 128; o2 > 0; o2 >>= 1) {
        if (tid < o2) red[tid] += red[tid + o2];
        __syncthreads();
    }
    float mu = red[0] * (1.0f / E_);
    __syncthreads();
    float d0 = x0 - mu, d1 = x1 - mu, d2 = x2 - mu, d3 = x3 - mu;
    red[tid] = d0 * d0 + d1 * d1 + d2 * d2 + d3 * d3; __syncthreads();
    for (int o2 = 128; o2 > 0; o2 >>= 1) {
        if (tid < o2) red[tid] += red[tid + o2];
        __syncthreads();
    }
    float inv = rsqrtf(red[0] * (1.0f / E_) + 1e-12f);
    float4 g4 = *(const float4*)(gamma + off);
    float4 b4 = *(const float4*)(beta + off);
    float4 o4;
    o4.x = d0 * inv * g4.x + b4.x;
    o4.y = d1 * inv * g4.y + b4.y;
    o4.z = d2 * inv * g4.z + b4.z;
    o4.w = d3 * inv * g4.w + b4.w;
    *(float4*)(outp + rowbase + off) = o4;
}

extern "C" void kernel_launch(void* const* d_in, const int* in_sizes, int n_in,
                              void* d_out, int out_size, void* d_ws, size_t ws_size,
                              hipStream_t stream) {
    const float* emb    = (const float*)d_in[0];
    const float* W1     = (const float*)d_in[1];
    const float* b1     = (const float*)d_in[2];
    const float* W2     = (const float*)d_in[3];
    const float* b2     = (const float*)d_in[4];
    const float* psfs   = (const float*)d_in[5];
    const float* W3     = (const float*)d_in[6];
    const float* b3     = (const float*)d_in[7];
    const float* sparse = (const float*)d_in[8];
    const float* gamma  = (const float*)d_in[9];
    const float* beta   = (const float*)d_in[10];
    float* outp = (float*)d_out;

    const size_t BLE  = (size_t)B_ * L_ * E_;
    const size_t EE   = (size_t)E_ * E_;
    const size_t KSZ  = (size_t)H_ * D_ * NFFT;        // f16x2 elems
    const size_t XVSZ = (size_t)B_ * H_ * 33 * L_;     // f16x2 elems

    bf16*   accbb      = (bf16*)d_ws;                  // 16.8 MB
    bf16*   pre_sparse = accbb + BLE;                  // 16.8 MB
    f16x2*  Khat       = (f16x2*)(pre_sparse + BLE);   // 16.8 MB
    f16x2*  Xv         = Khat + KSZ;                   // 17.3 MB
    bf16*   preb       = (bf16*)(Xv + XVSZ);           // 16.8 MB
    bf16*   actb       = preb + BLE;                   // 16.8 MB
    bf16*   W1b        = actb + BLE;                   // 3x 2.1 MB
    bf16*   W2b        = W1b + EE;
    bf16*   W3b        = W2b + EE;
    float2* twd        = (float2*)(W3b + EE);          // 32 KB
    // overlays on Xv (dead before k_vfft / after k_vifft):
    float*  psfT       = (float*)Xv;
    int*    s_nnz      = (int*)Xv;
    int*    s_idx      = s_nnz + L_;
    float*  s_val      = (float*)(s_idx + (size_t)L_ * CAP);

    k_twiddle<<<16, 256, 0, stream>>>(twd);
    k_cvt<<<(int)(BLE / 4 / 256), 256, 0, stream>>>(emb, actb, (int)BLE);
    k_cvtw<<<dim3((int)(EE / 4 / 256), 3), 256, 0, stream>>>(W1, W2, W3, W1b, (int)EE);

    // preb = bf16(emb @ W1^T + b1) ; pre_sparse = bf16(preb @ W2^T + b2)
    k_gemm_mfma<1><<<dim3(E_ / 128, (B_ * L_) / 128), 256, 0, stream>>>(
        actb, W1b, b1, nullptr, preb, B_ * L_, E_, E_);
    k_gemm_mfma<1><<<dim3(E_ / 128, (B_ * L_) / 128), 256, 0, stream>>>(
        preb, W2b, b2, nullptr, pre_sparse, B_ * L_, E_, E_);

    // psfT[h][u][t<2048] = psfs[h][t][u]
    k_tf32<<<dim3(1, L_ / 64, H_), 256, 0, stream>>>(
        psfs, psfT, L_, D_, (long)(2 * L_ - 1) * D_, (long)D_ * L_);

    // PSF softmax + full K4096 + fwd seq-FFT; d-FFT of kernel spectrum
    k_build_khat<<<dim3(D_, H_), 256, 0, stream>>>(psfT, Khat, twd);
    k_khat_dfft<<<dim3(NFFT / 64, H_), 256, 0, stream>>>(Khat, twd);

    // conv: v-FFT -> fused per-(k,h,b) seq conv (in place) -> inverse v-FFT
    k_vfft<<<dim3(L_ / 64, H_, B_), 256, 0, stream>>>(preb, Xv, twd);
    k_seqconv<<<dim3(33, H_, B_), 256, 0, stream>>>(Xv, Khat, twd);
    k_vifft<<<dim3(L_ / 64, H_, B_), 256, 0, stream>>>(Xv, actb, twd);

    // accbb = bf16(conv @ W3^T + b3)
    k_gemm_mfma<1><<<dim3(E_ / 128, (B_ * L_) / 128), 256, 0, stream>>>(
        actb, W3b, b3, nullptr, accbb, B_ * L_, E_, E_);

    // fused: out = LayerNorm(accbb + tril(sparse)@pre_sparse + emb)
    k_sparse_build<<<L_, 256, 0, stream>>>(sparse, s_nnz, s_idx, s_val);
    k_spmm_ln<<<dim3(L_, B_), 256, 0, stream>>>(
        s_nnz, s_idx, s_val, pre_sparse, accbb, emb, gamma, beta, outp);
}